// Round 1
// baseline (396.567 us; speedup 1.0000x reference)
//
#include <hip/hip_runtime.h>

#define BN_EPS 1e-5f
#define ATT_SCALE 0.125f   // 64^-0.5

// ---------------- K0: fold BN into pointwise weights ----------------
// wq_eff[512][256], bq_eff[512], wkv_eff[1024][256], bkv_eff[1024]
__global__ __launch_bounds__(256) void prep_weights_kernel(
    const float* __restrict__ qg, const float* __restrict__ qb,
    const float* __restrict__ qm, const float* __restrict__ qv,
    const float* __restrict__ qw,
    const float* __restrict__ kg, const float* __restrict__ kb,
    const float* __restrict__ km, const float* __restrict__ kvv,
    const float* __restrict__ kw,
    float* __restrict__ wq_eff, float* __restrict__ bq_eff,
    float* __restrict__ wkv_eff, float* __restrict__ bkv_eff)
{
    int o = blockIdx.x;       // 0..1535  (512 q rows, then 1024 kv rows)
    int c = threadIdx.x;      // 0..255
    const float *g, *b, *m, *v, *w;
    float *we, *be;
    if (o < 512) {
        g = qg; b = qb; m = qm; v = qv;
        w = qw + (size_t)o * 256; we = wq_eff + (size_t)o * 256; be = bq_eff + o;
    } else {
        int ro = o - 512;
        g = kg; b = kb; m = km; v = kvv;
        w = kw + (size_t)ro * 256; we = wkv_eff + (size_t)ro * 256; be = bkv_eff + ro;
    }
    float s  = g[c] * rsqrtf(v[c] + BN_EPS);
    float t  = b[c] - m[c] * s;
    float wv = w[c];
    we[c] = wv * s;
    float partial = wv * t;
    #pragma unroll
    for (int off = 32; off > 0; off >>= 1)
        partial += __shfl_down(partial, off, 64);
    __shared__ float red[4];
    if ((c & 63) == 0) red[c >> 6] = partial;
    __syncthreads();
    if (c == 0) *be = red[0] + red[1] + red[2] + red[3];
}

// ---------------- K1: depthwise 3x3, stride1 (q) + stride2 (kv) ----------------
// grid (256 ch, 16 img). Input plane in LDS with zero halo.
__global__ __launch_bounds__(256) void dw_conv_kernel(
    const float* __restrict__ x, const float* __restrict__ y,
    const float* __restrict__ qdw, const float* __restrict__ kvdw,
    float* __restrict__ dwq, float* __restrict__ dwkv)
{
    int ch = blockIdx.x;
    int img = blockIdx.y;
    const float* in = (img < 8)
        ? x + ((size_t)img * 256 + ch) * 1024
        : y + ((size_t)(img - 8) * 256 + ch) * 1024;
    __shared__ float p[34][34];
    int t = threadIdx.x;
    for (int i = t; i < 34 * 34; i += 256) ((float*)p)[i] = 0.f;
    __syncthreads();
    #pragma unroll
    for (int r = 0; r < 4; ++r) {
        int row = r * 8 + (t >> 5), col = t & 31;
        p[row + 1][col + 1] = in[row * 32 + col];
    }
    __syncthreads();
    float wq[9], wk[9];
    #pragma unroll
    for (int i = 0; i < 9; ++i) { wq[i] = qdw[ch * 9 + i]; wk[i] = kvdw[ch * 9 + i]; }

    float* oq = dwq + ((size_t)img * 256 + ch) * 1024;
    #pragma unroll
    for (int r = 0; r < 4; ++r) {
        int pos = r * 256 + t;
        int rr = pos >> 5, cc = pos & 31;
        float acc = 0.f;
        #pragma unroll
        for (int dr = 0; dr < 3; ++dr)
            #pragma unroll
            for (int dc = 0; dc < 3; ++dc)
                acc += wq[dr * 3 + dc] * p[rr + dr][cc + dc];
        oq[pos] = acc;
    }
    float* ok = dwkv + ((size_t)img * 256 + ch) * 256;
    {
        int rr = (t >> 4) * 2, cc = (t & 15) * 2;
        float acc = 0.f;
        #pragma unroll
        for (int dr = 0; dr < 3; ++dr)
            #pragma unroll
            for (int dc = 0; dc < 3; ++dc)
                acc += wk[dr * 3 + dc] * p[rr + dr][cc + dc];
        ok[t] = acc;
    }
}

// ---------------- generic batched GEMM: C_img = A @ B_img + bias ----------------
// A [M][K] shared across imgs; B [K][N], C [M][N] per img.
// grid (N/64, M/64, 16), 256 threads, 4x4 acc per thread, K-chunks of 16.
#define LSTR 68
__global__ __launch_bounds__(256) void gemm_bias_kernel(
    const float* __restrict__ A, const float* __restrict__ B,
    float* __restrict__ C, const float* __restrict__ bias,
    int M, int K, int N)
{
    int img = blockIdx.z;
    const float* Bi = B + (size_t)img * K * N;
    float* Ci = C + (size_t)img * M * N;
    int n0 = blockIdx.x * 64, m0 = blockIdx.y * 64;
    __shared__ float As[16][LSTR];
    __shared__ float Bs[16][LSTR];
    int t = threadIdx.x;
    int tx = t & 15, ty = t >> 4;
    int tx4 = tx * 4, ty4 = ty * 4;
    float acc[4][4] = {};
    for (int k0 = 0; k0 < K; k0 += 16) {
        {   // A tile -> As[k][m] (transposed)
            int m = t >> 2, k = (t & 3) * 4;
            float4 a = *(const float4*)(A + (size_t)(m0 + m) * K + k0 + k);
            As[k + 0][m] = a.x; As[k + 1][m] = a.y; As[k + 2][m] = a.z; As[k + 3][m] = a.w;
        }
        {   // B tile -> Bs[k][n]
            int k = t >> 4, n = (t & 15) * 4;
            *(float4*)(&Bs[k][n]) = *(const float4*)(Bi + (size_t)(k0 + k) * N + n0 + n);
        }
        __syncthreads();
        #pragma unroll
        for (int kk = 0; kk < 16; ++kk) {
            float4 a = *(const float4*)(&As[kk][ty4]);
            float4 b = *(const float4*)(&Bs[kk][tx4]);
            acc[0][0] += a.x * b.x; acc[0][1] += a.x * b.y; acc[0][2] += a.x * b.z; acc[0][3] += a.x * b.w;
            acc[1][0] += a.y * b.x; acc[1][1] += a.y * b.y; acc[1][2] += a.y * b.z; acc[1][3] += a.y * b.w;
            acc[2][0] += a.z * b.x; acc[2][1] += a.z * b.y; acc[2][2] += a.z * b.z; acc[2][3] += a.z * b.w;
            acc[3][0] += a.w * b.x; acc[3][1] += a.w * b.y; acc[3][2] += a.w * b.z; acc[3][3] += a.w * b.w;
        }
        __syncthreads();
    }
    #pragma unroll
    for (int ii = 0; ii < 4; ++ii) {
        int m = m0 + ty4 + ii;
        float bv = bias[m];
        float4 o;
        o.x = acc[ii][0] + bv; o.y = acc[ii][1] + bv; o.z = acc[ii][2] + bv; o.w = acc[ii][3] + bv;
        *(float4*)(Ci + (size_t)m * N + n0 + tx4) = o;
    }
}

// ---------------- attention: per (img, head, 64-query chunk) ----------------
// q [16][512][1024], kv [16][1024][256] (k rows 0..511, v rows 512..1023)
// att [16][512][1024]. partner img = img ^ 8. Full S row-block in registers.
__global__ __launch_bounds__(256) void attn_kernel(
    const float* __restrict__ q, const float* __restrict__ kv,
    float* __restrict__ att)
{
    int ic = blockIdx.x;        // 16 chunks of 64 queries
    int h  = blockIdx.y;        // 8 heads
    int img = blockIdx.z;       // 16 images
    int partner = img ^ 8;
    const float* qp = q  + ((size_t)img * 512 + h * 64) * 1024 + ic * 64;
    const float* kp = kv + ((size_t)partner * 1024 + h * 64) * 256;
    const float* vp = kv + ((size_t)partner * 1024 + 512 + h * 64) * 256;
    float* op = att + ((size_t)img * 512 + h * 64) * 1024 + ic * 64;

    __shared__ float smA[64][LSTR];  // phase1: qs[d][i]*SCALE ; phase2: vs[j][d]
    __shared__ float smB[64][LSTR];  // phase1: ks[d][j]       ; phase2: ps[j][i]

    int t = threadIdx.x;
    int tj = t & 15, ti = t >> 4;
    int tj4 = tj * 4, ti4 = ti * 4;

    // load q tile (scaled)
    #pragma unroll
    for (int r = 0; r < 4; ++r) {
        int d = r * 16 + ti;
        float4 a = *(const float4*)(qp + (size_t)d * 1024 + tj4);
        float4 sa;
        sa.x = a.x * ATT_SCALE; sa.y = a.y * ATT_SCALE; sa.z = a.z * ATT_SCALE; sa.w = a.w * ATT_SCALE;
        *(float4*)(&smA[d][tj4]) = sa;
    }

    float s[4][16];
    #pragma unroll
    for (int i = 0; i < 4; ++i)
        #pragma unroll
        for (int j = 0; j < 16; ++j) s[i][j] = 0.f;

    // ---- phase 1: S = (q*scale)^T k, 4 chunks of 64 j ----
    for (int jc = 0; jc < 4; ++jc) {
        __syncthreads();
        #pragma unroll
        for (int r = 0; r < 4; ++r) {
            int d = r * 16 + ti;
            *(float4*)(&smB[d][tj4]) = *(const float4*)(kp + (size_t)d * 256 + jc * 64 + tj4);
        }
        __syncthreads();
        int jb = jc * 4;
        for (int d = 0; d < 64; ++d) {
            float4 a = *(const float4*)(&smA[d][ti4]);  // q rows i = ti4..+3
            float4 b = *(const float4*)(&smB[d][tj4]);  // k cols j = jc*64+tj4..+3
            s[0][jb+0]+=a.x*b.x; s[0][jb+1]+=a.x*b.y; s[0][jb+2]+=a.x*b.z; s[0][jb+3]+=a.x*b.w;
            s[1][jb+0]+=a.y*b.x; s[1][jb+1]+=a.y*b.y; s[1][jb+2]+=a.y*b.z; s[1][jb+3]+=a.y*b.w;
            s[2][jb+0]+=a.z*b.x; s[2][jb+1]+=a.z*b.y; s[2][jb+2]+=a.z*b.z; s[2][jb+3]+=a.z*b.w;
            s[3][jb+0]+=a.w*b.x; s[3][jb+1]+=a.w*b.y; s[3][jb+2]+=a.w*b.z; s[3][jb+3]+=a.w*b.w;
        }
    }

    // ---- softmax over j (256 cols: 16 local x 16 lanes tj) ----
    #pragma unroll
    for (int rr = 0; rr < 4; ++rr) {
        float mx = s[rr][0];
        #pragma unroll
        for (int w = 1; w < 16; ++w) mx = fmaxf(mx, s[rr][w]);
        #pragma unroll
        for (int off = 1; off < 16; off <<= 1) mx = fmaxf(mx, __shfl_xor(mx, off, 16));
        float sum = 0.f;
        #pragma unroll
        for (int w = 0; w < 16; ++w) { float e = __expf(s[rr][w] - mx); s[rr][w] = e; sum += e; }
        #pragma unroll
        for (int off = 1; off < 16; off <<= 1) sum += __shfl_xor(sum, off, 16);
        float inv = 1.f / sum;
        #pragma unroll
        for (int w = 0; w < 16; ++w) s[rr][w] *= inv;
    }

    // ---- phase 2: O[d][i] = sum_j P[i][j] V[d][j] ----
    float o[4][4] = {};
    for (int jc = 0; jc < 4; ++jc) {
        __syncthreads();
        int jb = jc * 4;
        #pragma unroll
        for (int jj = 0; jj < 4; ++jj) {   // ps[j][i]
            float4 pv;
            pv.x = s[0][jb+jj]; pv.y = s[1][jb+jj]; pv.z = s[2][jb+jj]; pv.w = s[3][jb+jj];
            *(float4*)(&smB[tj4 + jj][ti4]) = pv;
        }
        #pragma unroll
        for (int r = 0; r < 4; ++r) {      // vs[j][d] (transposed load)
            int d = r * 16 + ti;
            float4 vv = *(const float4*)(vp + (size_t)d * 256 + jc * 64 + tj4);
            smA[tj4 + 0][d] = vv.x; smA[tj4 + 1][d] = vv.y;
            smA[tj4 + 2][d] = vv.z; smA[tj4 + 3][d] = vv.w;
        }
        __syncthreads();
        for (int j = 0; j < 64; ++j) {
            float4 v4 = *(const float4*)(&smA[j][ti4]);  // v, d = ti4..+3
            float4 p4 = *(const float4*)(&smB[j][tj4]);  // p, i = tj4..+3
            o[0][0]+=v4.x*p4.x; o[0][1]+=v4.x*p4.y; o[0][2]+=v4.x*p4.z; o[0][3]+=v4.x*p4.w;
            o[1][0]+=v4.y*p4.x; o[1][1]+=v4.y*p4.y; o[1][2]+=v4.y*p4.z; o[1][3]+=v4.y*p4.w;
            o[2][0]+=v4.z*p4.x; o[2][1]+=v4.z*p4.y; o[2][2]+=v4.z*p4.z; o[2][3]+=v4.z*p4.w;
            o[3][0]+=v4.w*p4.x; o[3][1]+=v4.w*p4.y; o[3][2]+=v4.w*p4.z; o[3][3]+=v4.w*p4.w;
        }
    }
    #pragma unroll
    for (int dd = 0; dd < 4; ++dd) {
        float4 ov; ov.x = o[dd][0]; ov.y = o[dd][1]; ov.z = o[dd][2]; ov.w = o[dd][3];
        *(float4*)(op + (size_t)(ti4 + dd) * 1024 + tj4) = ov;
    }
}

// ---------------- launch ----------------
extern "C" void kernel_launch(void* const* d_in, const int* in_sizes, int n_in,
                              void* d_out, int out_size, void* d_ws, size_t ws_size,
                              hipStream_t stream) {
    const float* x    = (const float*)d_in[0];
    const float* y    = (const float*)d_in[1];
    const float* qdw  = (const float*)d_in[2];
    const float* qg   = (const float*)d_in[3];
    const float* qb   = (const float*)d_in[4];
    const float* qm   = (const float*)d_in[5];
    const float* qv   = (const float*)d_in[6];
    const float* qpw  = (const float*)d_in[7];
    const float* kvdw = (const float*)d_in[8];
    const float* kg   = (const float*)d_in[9];
    const float* kb   = (const float*)d_in[10];
    const float* km   = (const float*)d_in[11];
    const float* kvv  = (const float*)d_in[12];
    const float* kvpw = (const float*)d_in[13];
    const float* outw = (const float*)d_in[14];
    const float* outb = (const float*)d_in[15];

    float* ws = (float*)d_ws;
    // ws layout (floats); att aliases the dead dwkv region.
    float* wq_eff  = ws;                       // 131072
    float* bq_eff  = ws + 131072;              // 512
    float* wkv_eff = ws + 131584;              // 262144
    float* bkv_eff = ws + 393728;              // 1024
    float* qbuf    = ws + 394752;              // 8388608  [16][512][1024]
    float* kvbuf   = ws + 8783360;             // 4194304  [16][1024][256]
    float* dwkv    = ws + 12977664;            // 1048576  [16][256][256]
    float* attbuf  = ws + 12977664;            // 8388608  [16][512][1024] (aliases dwkv)
    // total: 21,366,272 floats = 85.5 MB
    float* dwq = (float*)d_out;                // 4194304 [16][256][1024] scratch, dead before final write

    prep_weights_kernel<<<1536, 256, 0, stream>>>(
        qg, qb, qm, qv, qpw, kg, kb, km, kvv, kvpw,
        wq_eff, bq_eff, wkv_eff, bkv_eff);

    dw_conv_kernel<<<dim3(256, 16), 256, 0, stream>>>(x, y, qdw, kvdw, dwq, dwkv);

    // q = wq_eff[512x256] @ dwq[256x1024] + bq
    gemm_bias_kernel<<<dim3(16, 8, 16), 256, 0, stream>>>(
        wq_eff, dwq, qbuf, bq_eff, 512, 256, 1024);
    // kv = wkv_eff[1024x256] @ dwkv[256x256] + bkv
    gemm_bias_kernel<<<dim3(4, 16, 16), 256, 0, stream>>>(
        wkv_eff, dwkv, kvbuf, bkv_eff, 1024, 256, 256);

    attn_kernel<<<dim3(16, 8, 16), 256, 0, stream>>>(qbuf, kvbuf, attbuf);

    // out = outw[256x512] @ att[512x1024] + outb  -> d_out
    gemm_bias_kernel<<<dim3(16, 4, 16), 256, 0, stream>>>(
        outw, attbuf, (float*)d_out, outb, 256, 512, 1024);
}

// Round 2
// 291.757 us; speedup vs baseline: 1.3592x; 1.3592x over previous
//
#include <hip/hip_runtime.h>

#define BN_EPS 1e-5f
#define ATT_SCALE 0.125f   // 64^-0.5

typedef _Float16 half_t;
typedef _Float16 half8 __attribute__((ext_vector_type(8)));
typedef _Float16 half4 __attribute__((ext_vector_type(4)));
typedef float f32x4 __attribute__((ext_vector_type(4)));

// async global->LDS, 16B per lane; LDS dest = wave-uniform base + lane*16
__device__ __forceinline__ void gll16(const void* g, void* l) {
    __builtin_amdgcn_global_load_lds((const __attribute__((address_space(1))) void*)g,
                                     (__attribute__((address_space(3))) void*)l, 16, 0, 0);
}

// ---------------- prep: fold BN, split weights to f16 hi|lo ----------------
// wq' [512][512] (hi 0..255 | lo 256..511), wkv' [1024][512], wout' [256][1024]
__global__ __launch_bounds__(256) void prep_kernel(
    const float* __restrict__ qg, const float* __restrict__ qb,
    const float* __restrict__ qm, const float* __restrict__ qv,
    const float* __restrict__ qpw,
    const float* __restrict__ kg, const float* __restrict__ kbt,
    const float* __restrict__ km, const float* __restrict__ kvv,
    const float* __restrict__ kvpw,
    const float* __restrict__ outw,
    half_t* __restrict__ wq, half_t* __restrict__ wkv, half_t* __restrict__ wout,
    float* __restrict__ bq, float* __restrict__ bkv)
{
    int o = blockIdx.x, c = threadIdx.x;
    if (o >= 1536) {   // out_w rows: no BN, just split
        int ro = o - 1536;
        #pragma unroll
        for (int ci = 0; ci < 2; ++ci) {
            int cc = ci * 256 + c;
            float wv = outw[(size_t)ro * 512 + cc];
            half_t hh = (half_t)wv;
            wout[(size_t)ro * 1024 + cc]       = hh;
            wout[(size_t)ro * 1024 + 512 + cc] = (half_t)(wv - (float)hh);
        }
        return;
    }
    const float *g, *b, *m, *v, *w; half_t* we; float* be;
    if (o < 512) {
        g = qg; b = qb; m = qm; v = qv;
        w = qpw + (size_t)o * 256; we = wq + (size_t)o * 512; be = bq + o;
    } else {
        int ro = o - 512;
        g = kg; b = kbt; m = km; v = kvv;
        w = kvpw + (size_t)ro * 256; we = wkv + (size_t)ro * 512; be = bkv + ro;
    }
    float s  = g[c] * rsqrtf(v[c] + BN_EPS);
    float tt = b[c] - m[c] * s;
    float wv = w[c];
    float wsv = wv * s;
    half_t hh = (half_t)wsv;
    we[c]       = hh;
    we[256 + c] = (half_t)(wsv - (float)hh);
    float partial = wv * tt;
    #pragma unroll
    for (int off = 32; off > 0; off >>= 1)
        partial += __shfl_down(partial, off, 64);
    __shared__ float red[4];
    if ((c & 63) == 0) red[c >> 6] = partial;
    __syncthreads();
    if (c == 0) *be = red[0] + red[1] + red[2] + red[3];
}

// ---------------- depthwise 3x3, stride1 (q) + stride2 (kv), fp32 ----------------
__global__ __launch_bounds__(256) void dw_conv_kernel(
    const float* __restrict__ x, const float* __restrict__ y,
    const float* __restrict__ qdw, const float* __restrict__ kvdw,
    float* __restrict__ dwq, float* __restrict__ dwkv)
{
    int ch = blockIdx.x;
    int img = blockIdx.y;
    const float* in = (img < 8)
        ? x + ((size_t)img * 256 + ch) * 1024
        : y + ((size_t)(img - 8) * 256 + ch) * 1024;
    __shared__ float p[34][34];
    int t = threadIdx.x;
    for (int i = t; i < 34 * 34; i += 256) ((float*)p)[i] = 0.f;
    __syncthreads();
    #pragma unroll
    for (int r = 0; r < 4; ++r) {
        int row = r * 8 + (t >> 5), col = t & 31;
        p[row + 1][col + 1] = in[row * 32 + col];
    }
    __syncthreads();
    float wq9[9], wk9[9];
    #pragma unroll
    for (int i = 0; i < 9; ++i) { wq9[i] = qdw[ch * 9 + i]; wk9[i] = kvdw[ch * 9 + i]; }

    float* oq = dwq + ((size_t)img * 256 + ch) * 1024;
    #pragma unroll
    for (int r = 0; r < 4; ++r) {
        int pos = r * 256 + t;
        int rr = pos >> 5, cc = pos & 31;
        float acc = 0.f;
        #pragma unroll
        for (int dr = 0; dr < 3; ++dr)
            #pragma unroll
            for (int dc = 0; dc < 3; ++dc)
                acc += wq9[dr * 3 + dc] * p[rr + dr][cc + dc];
        oq[pos] = acc;
    }
    float* ok = dwkv + ((size_t)img * 256 + ch) * 256;
    {
        int rr = (t >> 4) * 2, cc = (t & 15) * 2;
        float acc = 0.f;
        #pragma unroll
        for (int dr = 0; dr < 3; ++dr)
            #pragma unroll
            for (int dc = 0; dc < 3; ++dc)
                acc += wk9[dr * 3 + dc] * p[rr + dr][cc + dc];
        ok[t] = acc;
    }
}

// ---------------- transpose + f16 split: in fp32 [R][C] -> out f16 [C][2R] ----------------
__global__ __launch_bounds__(256) void pack_bt_kernel(
    const float* __restrict__ in, half_t* __restrict__ out, int R, int C)
{
    __shared__ float tile[64][65];
    int img = blockIdx.z;
    int c0 = blockIdx.y * 64, p0 = blockIdx.x * 64;
    int t = threadIdx.x;
    const float* ip = in + ((size_t)img * R + c0) * C + p0;
    #pragma unroll
    for (int rr = 0; rr < 16; ++rr) {
        int row = rr * 4 + (t >> 6);
        tile[row][t & 63] = ip[(size_t)row * C + (t & 63)];
    }
    __syncthreads();
    half_t* op = out + ((size_t)img * C + p0) * (2 * R) + c0;
    #pragma unroll
    for (int ww = 0; ww < 16; ++ww) {
        int px = ww * 4 + (t >> 6);
        float v = tile[t & 63][px];
        half_t hh = (half_t)v;
        op[(size_t)px * (2 * R) + (t & 63)]     = hh;
        op[(size_t)px * (2 * R) + R + (t & 63)] = (half_t)(v - (float)hh);
    }
}

// ---------------- split-f16 MFMA GEMM ----------------
// C[m][n] = sum_k A[m][k] * B^T[n][k], emulated fp32: 3 phases hi*hi + hi*lo + lo*hi.
// A [M][2K] f16 (hi|lo), B [N][2K] f16 (hi|lo). Tile TM=WGM*MT*16, TN=WGN*NT*16.
// MODE 0 (QK): out f16 [(img*8+h)*NPX + n][128]: hi at d, lo at 64+d; d,h from m; (acc+bias[m])*scale
// MODE 1 (V):  out f16 [(img*8+h)*64 + d][512]: hi at j=m, lo at 256+m; d,h from n; acc+bias[n]
// MODE 2 (F32): out fp32 [img*256 + m][NPX] = acc + bias[m]
template<int MT, int NT, int WGM, int WGN, int MODE>
__global__ __launch_bounds__(256) void gemm_split(
    const half_t* __restrict__ A, const half_t* __restrict__ B,
    void* __restrict__ outBuf, const float* __restrict__ bias,
    int K, int NPX, long aImgStride, long bImgStride, float scale)
{
    constexpr int TM = WGM * MT * 16, TN = WGN * NT * 16;
    __shared__ __align__(16) char lds[(TM + TN) * 64];
    char* ldsA = lds;
    char* ldsB = lds + TM * 64;

    int t = threadIdx.x;
    int w = t >> 6, lane = t & 63, quad = lane >> 4, l15 = lane & 15;
    int wm = w % WGM, wn = w / WGM;
    int img = blockIdx.z;
    int n0 = blockIdx.x * TN, m0 = blockIdx.y * TM;
    const half_t* Ab = A + (size_t)img * aImgStride + (size_t)m0 * (2 * K);
    const half_t* Bb = B + (size_t)img * bImgStride + (size_t)n0 * (2 * K);

    f32x4 acc[MT][NT] = {};

    for (int ph = 0; ph < 3; ++ph) {
        int aoff = (ph == 2) ? K : 0;
        int boff = (ph == 1) ? K : 0;
        for (int kc = 0; kc < K; kc += 32) {
            __syncthreads();
            #pragma unroll
            for (int ii = 0; ii < TM / 64; ++ii) {
                int u = ii * 256 + t;
                int mt = u >> 6, q = (u >> 4) & 3, r = u & 15;
                gll16(Ab + (size_t)(mt * 16 + r) * (2 * K) + aoff + kc + q * 8,
                      ldsA + (u & ~63) * 16);
            }
            #pragma unroll
            for (int ii = 0; ii < TN / 64; ++ii) {
                int u = ii * 256 + t;
                int nt = u >> 6, q = (u >> 4) & 3, r = u & 15;
                gll16(Bb + (size_t)(nt * 16 + r) * (2 * K) + boff + kc + q * 8,
                      ldsB + (u & ~63) * 16);
            }
            __syncthreads();
            half8 af[MT], bf[NT];
            #pragma unroll
            for (int mi = 0; mi < MT; ++mi)
                af[mi] = *(half8*)(ldsA + (wm * MT + mi) * 1024 + lane * 16);
            #pragma unroll
            for (int ni = 0; ni < NT; ++ni)
                bf[ni] = *(half8*)(ldsB + (wn * NT + ni) * 1024 + lane * 16);
            #pragma unroll
            for (int mi = 0; mi < MT; ++mi)
                #pragma unroll
                for (int ni = 0; ni < NT; ++ni)
                    acc[mi][ni] = __builtin_amdgcn_mfma_f32_16x16x32_f16(
                        af[mi], bf[ni], acc[mi][ni], 0, 0, 0);
        }
    }

    // epilogue (D layout: col = lane&15, row = quad*4 + reg)
    #pragma unroll
    for (int mi = 0; mi < MT; ++mi) {
        int mrow0 = m0 + wm * MT * 16 + mi * 16 + quad * 4;
        #pragma unroll
        for (int ni = 0; ni < NT; ++ni) {
            int col = n0 + wn * NT * 16 + ni * 16 + l15;
            f32x4 a = acc[mi][ni];
            if (MODE == 0) {
                int h = mrow0 >> 6, d0 = mrow0 & 63;
                half_t* op = (half_t*)outBuf + ((size_t)(img * 8 + h) * NPX + col) * 128 + d0;
                half4 hv, lv;
                #pragma unroll
                for (int r = 0; r < 4; ++r) {
                    float vv = (a[r] + bias[mrow0 + r]) * scale;
                    half_t hh = (half_t)vv;
                    hv[r] = hh; lv[r] = (half_t)(vv - (float)hh);
                }
                *(half4*)op = hv;
                *(half4*)(op + 64) = lv;
            } else if (MODE == 1) {
                int h = col >> 6, d = col & 63;
                half_t* op = (half_t*)outBuf + ((size_t)(img * 8 + h) * 64 + d) * 512 + mrow0;
                float bv = bias[col];
                half4 hv, lv;
                #pragma unroll
                for (int r = 0; r < 4; ++r) {
                    float vv = a[r] + bv;
                    half_t hh = (half_t)vv;
                    hv[r] = hh; lv[r] = (half_t)(vv - (float)hh);
                }
                *(half4*)op = hv;
                *(half4*)(op + 256) = lv;
            } else {
                float* op = (float*)outBuf + (size_t)img * 256 * NPX;
                #pragma unroll
                for (int r = 0; r < 4; ++r)
                    op[(size_t)(mrow0 + r) * NPX + col] = a[r] + bias[mrow0 + r];
            }
        }
    }
}

// ---------------- attention: split-f16 MFMA, full S in accumulators ----------------
// q' [img*8+h][1024 i][128], k' [img*8+h][256 j][128], v' [img*8+h][64 d][512]
// att' [img][1024 i][1024]: hi at c=h*64+d, lo at 512+c. partner = img^8.
__global__ __launch_bounds__(256) void attn_split(
    const half_t* __restrict__ qb, const half_t* __restrict__ kb,
    const half_t* __restrict__ vb, half_t* __restrict__ att)
{
    __shared__ __align__(16) char lds[4096 + 16384 + 8192 + 2 * 9216];
    char* stA = lds;                           // q tile  [4 mt][4 q][16 r]*16B
    char* stB = lds + 4096;                    // k tile  [16 nt][4 q][16 r]*16B
    char* stV = lds + 20480;                   // v tile  [4 nt][2 kcs][4 q][16 r]*16B
    half_t* pHi = (half_t*)(lds + 28672);      // [64 i][72] (stride 72 -> 16B-aligned rows)
    half_t* pLo = (half_t*)(lds + 37888);

    int ic = blockIdx.x, h = blockIdx.y, img = blockIdx.z;
    int partner = img ^ 8;
    int t = threadIdx.x, w = t >> 6, lane = t & 63, quad = lane >> 4, l15 = lane & 15;
    const half_t* qp = qb + ((size_t)(img * 8 + h) * 1024 + ic * 64) * 128;
    const half_t* kp = kb + (size_t)(partner * 8 + h) * 256 * 128;
    const half_t* vp = vb + (size_t)(partner * 8 + h) * 64 * 512;

    // ---- phase 1: S[64 i][256 j], 3 split-phases x 2 k-chunks ----
    f32x4 sacc[16] = {};
    for (int ph = 0; ph < 3; ++ph) {
        int aoff = (ph == 2) ? 64 : 0;
        int boff = (ph == 1) ? 64 : 0;
        for (int kc = 0; kc < 64; kc += 32) {
            __syncthreads();
            {
                int u = t, mt = u >> 6, q = (u >> 4) & 3, r = u & 15;
                gll16(qp + (size_t)(mt * 16 + r) * 128 + aoff + kc + q * 8,
                      stA + (u & ~63) * 16);
            }
            #pragma unroll
            for (int ii = 0; ii < 4; ++ii) {
                int u = ii * 256 + t;
                int nt = u >> 6, q = (u >> 4) & 3, r = u & 15;
                gll16(kp + (size_t)(nt * 16 + r) * 128 + boff + kc + q * 8,
                      stB + (u & ~63) * 16);
            }
            __syncthreads();
            half8 a = *(half8*)(stA + w * 1024 + lane * 16);
            #pragma unroll
            for (int nt = 0; nt < 16; ++nt) {
                half8 b = *(half8*)(stB + nt * 1024 + lane * 16);
                sacc[nt] = __builtin_amdgcn_mfma_f32_16x16x32_f16(a, b, sacc[nt], 0, 0, 0);
            }
        }
    }

    // ---- softmax over j (rows i = w*16 + quad*4 + reg; cols j = nt*16 + l15) ----
    #pragma unroll
    for (int r = 0; r < 4; ++r) {
        float mx = sacc[0][r];
        #pragma unroll
        for (int nt = 1; nt < 16; ++nt) mx = fmaxf(mx, sacc[nt][r]);
        #pragma unroll
        for (int off = 1; off < 16; off <<= 1) mx = fmaxf(mx, __shfl_xor(mx, off, 64));
        float sum = 0.f;
        #pragma unroll
        for (int nt = 0; nt < 16; ++nt) {
            float e = __expf(sacc[nt][r] - mx);
            sacc[nt][r] = e; sum += e;
        }
        #pragma unroll
        for (int off = 1; off < 16; off <<= 1) sum += __shfl_xor(sum, off, 64);
        float inv = 1.f / sum;
        #pragma unroll
        for (int nt = 0; nt < 16; ++nt) sacc[nt][r] *= inv;
    }

    // ---- phase 2: O[64 i][64 d] += P[:, jc*64..+64] * V^T, per j-chunk ----
    f32x4 oacc[4] = {};
    for (int jc = 0; jc < 4; ++jc) {
        // write P chunk (hi/lo) — each wave writes only its own 16 rows
        #pragma unroll
        for (int ni = 0; ni < 4; ++ni) {
            #pragma unroll
            for (int r = 0; r < 4; ++r) {
                float pv = sacc[jc * 4 + ni][r];
                half_t hh = (half_t)pv;
                int iLoc = w * 16 + quad * 4 + r, jl = ni * 16 + l15;
                pHi[iLoc * 72 + jl] = hh;
                pLo[iLoc * 72 + jl] = (half_t)(pv - (float)hh);
            }
        }
        for (int ph = 0; ph < 3; ++ph) {
            int vcol = (ph == 1) ? 256 : 0;
            const half_t* psrc = (ph == 2) ? pLo : pHi;
            __syncthreads();
            #pragma unroll
            for (int ii = 0; ii < 2; ++ii) {
                int u = ii * 256 + t;
                int nt = u >> 7, kcs = (u >> 6) & 1, q = (u >> 4) & 3, r = u & 15;
                gll16(vp + (size_t)(nt * 16 + r) * 512 + vcol + jc * 64 + kcs * 32 + q * 8,
                      stV + (u & ~63) * 16);
            }
            __syncthreads();
            #pragma unroll
            for (int kcs = 0; kcs < 2; ++kcs) {
                half8 a = *(half8*)(psrc + (w * 16 + l15) * 72 + kcs * 32 + quad * 8);
                #pragma unroll
                for (int nt = 0; nt < 4; ++nt) {
                    half8 b = *(half8*)(stV + nt * 2048 + kcs * 1024 + lane * 16);
                    oacc[nt] = __builtin_amdgcn_mfma_f32_16x16x32_f16(a, b, oacc[nt], 0, 0, 0);
                }
            }
        }
    }

    // ---- write O as f16 hi/lo in out-proj B' layout [px][1024] ----
    #pragma unroll
    for (int nt = 0; nt < 4; ++nt) {
        int d = nt * 16 + l15, c = h * 64 + d;
        #pragma unroll
        for (int r = 0; r < 4; ++r) {
            int i = ic * 64 + w * 16 + quad * 4 + r;
            float vv = oacc[nt][r];
            half_t hh = (half_t)vv;
            size_t base = ((size_t)img * 1024 + i) * 1024 + c;
            att[base]       = hh;
            att[base + 512] = (half_t)(vv - (float)hh);
        }
    }
}

// ---------------- launch ----------------
extern "C" void kernel_launch(void* const* d_in, const int* in_sizes, int n_in,
                              void* d_out, int out_size, void* d_ws, size_t ws_size,
                              hipStream_t stream) {
    const float* x    = (const float*)d_in[0];
    const float* y    = (const float*)d_in[1];
    const float* qdw  = (const float*)d_in[2];
    const float* qg   = (const float*)d_in[3];
    const float* qbb  = (const float*)d_in[4];
    const float* qm   = (const float*)d_in[5];
    const float* qv   = (const float*)d_in[6];
    const float* qpw  = (const float*)d_in[7];
    const float* kvdw = (const float*)d_in[8];
    const float* kg   = (const float*)d_in[9];
    const float* kb_  = (const float*)d_in[10];
    const float* km   = (const float*)d_in[11];
    const float* kvv  = (const float*)d_in[12];
    const float* kvpw = (const float*)d_in[13];
    const float* outw = (const float*)d_in[14];
    const float* outb = (const float*)d_in[15];

    char* ws = (char*)d_ws;
    // byte offsets (16B aligned)
    half_t* wq   = (half_t*)(ws);              //  512*512*2  = 524288
    half_t* wkv  = (half_t*)(ws + 524288);     // 1024*512*2  = 1048576
    half_t* wout = (half_t*)(ws + 1572864);    //  256*1024*2 = 524288
    float*  bq   = (float*) (ws + 2097152);    //  2048
    float*  bkv  = (float*) (ws + 2099200);    //  4096
    half_t* qB   = (half_t*)(ws + 2103296);    // 16*1024*512*2 = 16777216
    half_t* kvB  = (half_t*)(ws + 18880512);   // 16*256*512*2  = 4194304
    float*  dwkv = (float*) (ws + 23074816);   // 16*256*256*4  = 4194304
    // att' aliases qB+kvB+dwkv (all dead by attention time) + 8.4MB fresh
    half_t* attp = (half_t*)(ws + 2103296);    // 16*1024*1024*2 = 33554432 -> ends 35657728
    half_t* qpr  = (half_t*)(ws + 35657728);   // 16*8*1024*128*2 = 33554432
    half_t* kpr  = (half_t*)(ws + 69212160);   // 16*8*256*128*2  = 8388608
    half_t* vpr  = (half_t*)(ws + 77600768);   // 16*8*64*512*2   = 8388608
    // total 85,989,376 B
    float* dwq = (float*)d_out;                // fp32 [16][256][1024] scratch, dead before final write

    prep_kernel<<<1792, 256, 0, stream>>>(
        qg, qbb, qm, qv, qpw, kg, kb_, km, kvv, kvpw, outw,
        wq, wkv, wout, bq, bkv);

    dw_conv_kernel<<<dim3(256, 16), 256, 0, stream>>>(x, y, qdw, kvdw, dwq, dwkv);

    // dwq [256][1024] -> qB [1024][512]; dwkv [256][256] -> kvB [256][512]
    pack_bt_kernel<<<dim3(16, 4, 16), 256, 0, stream>>>(dwq, qB, 256, 1024);
    pack_bt_kernel<<<dim3(4, 4, 16), 256, 0, stream>>>(dwkv, kvB, 256, 256);

    // q' = (wq @ dwq + bq) * SCALE   [M=512, K=256, N=1024] -> MODE_QK layout
    gemm_split<4, 4, 2, 2, 0><<<dim3(8, 4, 16), 256, 0, stream>>>(
        wq, qB, qpr, bq, 256, 1024, 0L, 1024L * 512, ATT_SCALE);
    // k' = wkv[0:512] @ dwkv + bkv[0:512]   [M=512, K=256, N=256]
    gemm_split<2, 4, 2, 2, 0><<<dim3(2, 8, 16), 256, 0, stream>>>(
        wkv, kvB, kpr, bkv, 256, 256, 0L, 256L * 512, 1.0f);
    // v' = (wkv[512:1024] @ dwkv + bkv[512:])^T  [M=256 j, K=256, N=512 c] -> MODE_V
    gemm_split<2, 4, 2, 2, 1><<<dim3(4, 4, 16), 256, 0, stream>>>(
        kvB, wkv + 512 * 512, vpr, bkv + 512, 256, 512, 256L * 512, 0L, 1.0f);

    attn_split<<<dim3(16, 8, 16), 256, 0, stream>>>(qpr, kpr, vpr, attp);

    // out = wout @ att + outb  [M=256, K=512, N=1024] -> fp32 d_out
    gemm_split<2, 4, 2, 2, 2><<<dim3(8, 4, 16), 256, 0, stream>>>(
        wout, attp, d_out, outb, 512, 1024, 0L, 1024L * 1024, 1.0f);
}

// Round 3
// 285.981 us; speedup vs baseline: 1.3867x; 1.0202x over previous
//
#include <hip/hip_runtime.h>

#define BN_EPS 1e-5f
#define ATT_SCALE 0.125f   // 64^-0.5

typedef _Float16 half_t;
typedef _Float16 half8 __attribute__((ext_vector_type(8)));
typedef _Float16 half4 __attribute__((ext_vector_type(4)));
typedef float f32x4 __attribute__((ext_vector_type(4)));

// async global->LDS, 16B per lane; LDS dest = wave-uniform base + lane*16
__device__ __forceinline__ void gll16(const void* g, void* l) {
    __builtin_amdgcn_global_load_lds((const __attribute__((address_space(1))) void*)g,
                                     (__attribute__((address_space(3))) void*)l, 16, 0, 0);
}

// ---------------- prep: fold BN, split weights to f16 hi|lo ----------------
__global__ __launch_bounds__(256) void prep_kernel(
    const float* __restrict__ qg, const float* __restrict__ qb,
    const float* __restrict__ qm, const float* __restrict__ qv,
    const float* __restrict__ qpw,
    const float* __restrict__ kg, const float* __restrict__ kbt,
    const float* __restrict__ km, const float* __restrict__ kvv,
    const float* __restrict__ kvpw,
    const float* __restrict__ outw,
    half_t* __restrict__ wq, half_t* __restrict__ wkv, half_t* __restrict__ wout,
    float* __restrict__ bq, float* __restrict__ bkv)
{
    int o = blockIdx.x, c = threadIdx.x;
    if (o >= 1536) {   // out_w rows: no BN, just split
        int ro = o - 1536;
        #pragma unroll
        for (int ci = 0; ci < 2; ++ci) {
            int cc = ci * 256 + c;
            float wv = outw[(size_t)ro * 512 + cc];
            half_t hh = (half_t)wv;
            wout[(size_t)ro * 1024 + cc]       = hh;
            wout[(size_t)ro * 1024 + 512 + cc] = (half_t)(wv - (float)hh);
        }
        return;
    }
    const float *g, *b, *m, *v, *w; half_t* we; float* be;
    if (o < 512) {
        g = qg; b = qb; m = qm; v = qv;
        w = qpw + (size_t)o * 256; we = wq + (size_t)o * 512; be = bq + o;
    } else {
        int ro = o - 512;
        g = kg; b = kbt; m = km; v = kvv;
        w = kvpw + (size_t)ro * 256; we = wkv + (size_t)ro * 512; be = bkv + ro;
    }
    float s  = g[c] * rsqrtf(v[c] + BN_EPS);
    float tt = b[c] - m[c] * s;
    float wv = w[c];
    float wsv = wv * s;
    half_t hh = (half_t)wsv;
    we[c]       = hh;
    we[256 + c] = (half_t)(wsv - (float)hh);
    float partial = wv * tt;
    #pragma unroll
    for (int off = 32; off > 0; off >>= 1)
        partial += __shfl_down(partial, off, 64);
    __shared__ float red[4];
    if ((c & 63) == 0) red[c >> 6] = partial;
    __syncthreads();
    if (c == 0) *be = red[0] + red[1] + red[2] + red[3];
}

// ---------------- fused depthwise 3x3 (stride1 + stride2) + f16 split-pack ----------------
// Writes GEMM-B layouts directly:
//   qB  [img][1024 p][512: ch hi 0..255 | ch lo 256..511]
//   kvB [img][ 256 p][512: hi | lo]
// grid (16 row-pairs, 16 img), 256 thr. Lane = channel -> 128B coalesced stores.
__global__ __launch_bounds__(256) void dw_pack_kernel(
    const float* __restrict__ x, const float* __restrict__ y,
    const float* __restrict__ qdw, const float* __restrict__ kvdw,
    half_t* __restrict__ qB, half_t* __restrict__ kvB)
{
    int rp = blockIdx.x;    // output rows 2rp, 2rp+1
    int img = blockIdx.y;
    const float* in = (img < 8) ? x + (size_t)img * 256 * 1024
                                : y + (size_t)(img - 8) * 256 * 1024;
    __shared__ float sin[64 * 129];   // [ch 64][4 rows * 32 + 1 pad] -> conflict-free ch-lanes
    int t = threadIdx.x;
    int ch = t & 63, cg = t >> 6;     // cg == wave id
    int r0 = 2 * rp - 1;
    for (int cc = 0; cc < 4; ++cc) {
        __syncthreads();
        #pragma unroll
        for (int ii = 0; ii < 8; ++ii) {
            int u = ii * 256 + t;            // float4 unit
            int sch = u >> 5, row = (u >> 3) & 3, seg = u & 7;
            int gr = r0 + row;
            float4 v4 = {0.f, 0.f, 0.f, 0.f};
            if (gr >= 0 && gr < 32)
                v4 = *(const float4*)(in + (size_t)(cc * 64 + sch) * 1024 + gr * 32 + seg * 4);
            float* d = &sin[sch * 129 + row * 32 + seg * 4];
            d[0] = v4.x; d[1] = v4.y; d[2] = v4.z; d[3] = v4.w;
        }
        __syncthreads();
        int gch = cc * 64 + ch;
        float wq9[9], wk9[9];
        #pragma unroll
        for (int i = 0; i < 9; ++i) { wq9[i] = qdw[gch * 9 + i]; wk9[i] = kvdw[gch * 9 + i]; }
        const float* base = &sin[ch * 129];
        // q (stride 1): rows 2rp..2rp+1, cols cg*8..+8
        #pragma unroll
        for (int r = 0; r < 2; ++r) {
            #pragma unroll
            for (int c8 = 0; c8 < 8; ++c8) {
                int c = cg * 8 + c8;
                float acc = 0.f;
                #pragma unroll
                for (int dr = 0; dr < 3; ++dr) {
                    const float* rowp = base + (r + dr) * 32;
                    #pragma unroll
                    for (int dc = 0; dc < 3; ++dc) {
                        int cx = c + dc - 1;
                        float pv = (cx >= 0 && cx < 32) ? rowp[cx] : 0.f;
                        acc += wq9[dr * 3 + dc] * pv;
                    }
                }
                half_t hh = (half_t)acc;
                size_t p = (size_t)img * 1024 + (2 * rp + r) * 32 + c;
                qB[p * 512 + gch]       = hh;
                qB[p * 512 + 256 + gch] = (half_t)(acc - (float)hh);
            }
        }
        // kv (stride 2): row rp, cols cg*4..+4
        #pragma unroll
        for (int c4 = 0; c4 < 4; ++c4) {
            int c2 = cg * 4 + c4;
            float acc = 0.f;
            #pragma unroll
            for (int dr = 0; dr < 3; ++dr) {
                const float* rowp = base + dr * 32;
                #pragma unroll
                for (int dc = 0; dc < 3; ++dc) {
                    int cx = 2 * c2 + dc - 1;
                    float pv = (cx >= 0 && cx < 32) ? rowp[cx] : 0.f;
                    acc += wk9[dr * 3 + dc] * pv;
                }
            }
            half_t hh = (half_t)acc;
            size_t p = (size_t)img * 256 + rp * 16 + c2;
            kvB[p * 512 + gch]       = hh;
            kvB[p * 512 + 256 + gch] = (half_t)(acc - (float)hh);
        }
    }
}

// ---------------- split-f16 MFMA GEMM (3 phases: hi*hi + hi*lo + lo*hi) ----------------
// A [M][2K] f16 (hi|lo), B [N][2K] f16 (hi|lo), C[m][n] = sum_k A*B^T.
// MODE 0 (QK): out f16 [(img*8+h)*NPX + n][128]: hi at d, lo 64+d; (acc+bias[m])*scale
// MODE 1 (V):  out f16 [(img*8+h)*64 + d][512]: hi at j=m, lo 256+m; acc+bias[n]
// MODE 2 (F32): out fp32 [img*256 + m][NPX] = acc + bias[m]
template<int MT, int NT, int WGM, int WGN, int MODE>
__global__ __launch_bounds__(256) void gemm_split(
    const half_t* __restrict__ A, const half_t* __restrict__ B,
    void* __restrict__ outBuf, const float* __restrict__ bias,
    int K, int NPX, long aImgStride, long bImgStride, float scale)
{
    constexpr int TM = WGM * MT * 16, TN = WGN * NT * 16;
    __shared__ __align__(16) char lds[(TM + TN) * 64];
    char* ldsA = lds;
    char* ldsB = lds + TM * 64;

    int t = threadIdx.x;
    int w = t >> 6, lane = t & 63, quad = lane >> 4, l15 = lane & 15;
    int wm = w % WGM, wn = w / WGM;
    int img = blockIdx.z;
    int n0 = blockIdx.x * TN, m0 = blockIdx.y * TM;
    const half_t* Ab = A + (size_t)img * aImgStride + (size_t)m0 * (2 * K);
    const half_t* Bb = B + (size_t)img * bImgStride + (size_t)n0 * (2 * K);

    f32x4 acc[MT][NT] = {};

    for (int ph = 0; ph < 3; ++ph) {
        int aoff = (ph == 2) ? K : 0;
        int boff = (ph == 1) ? K : 0;
        for (int kc = 0; kc < K; kc += 32) {
            __syncthreads();
            #pragma unroll
            for (int ii = 0; ii < TM / 64; ++ii) {
                int u = ii * 256 + t;
                int mt = u >> 6, q = (u >> 4) & 3, r = u & 15;
                gll16(Ab + (size_t)(mt * 16 + r) * (2 * K) + aoff + kc + q * 8,
                      ldsA + (u & ~63) * 16);
            }
            #pragma unroll
            for (int ii = 0; ii < TN / 64; ++ii) {
                int u = ii * 256 + t;
                int nt = u >> 6, q = (u >> 4) & 3, r = u & 15;
                gll16(Bb + (size_t)(nt * 16 + r) * (2 * K) + boff + kc + q * 8,
                      ldsB + (u & ~63) * 16);
            }
            __syncthreads();
            half8 af[MT], bf[NT];
            #pragma unroll
            for (int mi = 0; mi < MT; ++mi)
                af[mi] = *(half8*)(ldsA + (wm * MT + mi) * 1024 + lane * 16);
            #pragma unroll
            for (int ni = 0; ni < NT; ++ni)
                bf[ni] = *(half8*)(ldsB + (wn * NT + ni) * 1024 + lane * 16);
            #pragma unroll
            for (int mi = 0; mi < MT; ++mi)
                #pragma unroll
                for (int ni = 0; ni < NT; ++ni)
                    acc[mi][ni] = __builtin_amdgcn_mfma_f32_16x16x32_f16(
                        af[mi], bf[ni], acc[mi][ni], 0, 0, 0);
        }
    }

    // epilogue (D layout: col = lane&15, row = quad*4 + reg)
    #pragma unroll
    for (int mi = 0; mi < MT; ++mi) {
        int mrow0 = m0 + wm * MT * 16 + mi * 16 + quad * 4;
        #pragma unroll
        for (int ni = 0; ni < NT; ++ni) {
            int col = n0 + wn * NT * 16 + ni * 16 + l15;
            f32x4 a = acc[mi][ni];
            if (MODE == 0) {
                int h = mrow0 >> 6, d0 = mrow0 & 63;
                half_t* op = (half_t*)outBuf + ((size_t)(img * 8 + h) * NPX + col) * 128 + d0;
                half4 hv, lv;
                #pragma unroll
                for (int r = 0; r < 4; ++r) {
                    float vv = (a[r] + bias[mrow0 + r]) * scale;
                    half_t hh = (half_t)vv;
                    hv[r] = hh; lv[r] = (half_t)(vv - (float)hh);
                }
                *(half4*)op = hv;
                *(half4*)(op + 64) = lv;
            } else if (MODE == 1) {
                int h = col >> 6, d = col & 63;
                half_t* op = (half_t*)outBuf + ((size_t)(img * 8 + h) * 64 + d) * 512 + mrow0;
                float bv = bias[col];
                half4 hv, lv;
                #pragma unroll
                for (int r = 0; r < 4; ++r) {
                    float vv = a[r] + bv;
                    half_t hh = (half_t)vv;
                    hv[r] = hh; lv[r] = (half_t)(vv - (float)hh);
                }
                *(half4*)op = hv;
                *(half4*)(op + 256) = lv;
            } else {
                float* op = (float*)outBuf + (size_t)img * 256 * NPX;
                #pragma unroll
                for (int r = 0; r < 4; ++r)
                    op[(size_t)(mrow0 + r) * NPX + col] = a[r] + bias[mrow0 + r];
            }
        }
    }
}

// ---------------- attention: 128 queries/block, K resident in LDS ----------------
// q' [(img*8+h)*1024 + i][128: d hi | d lo] (scale pre-folded)
// k' [(img*8+h)*256 + j][128], v' [(img*8+h)*64 + d][512: j hi | j lo]
// att' [img][1024 i][1024: c hi | 512 + c lo], c = h*64+d. partner = img^8.
__global__ __launch_bounds__(256, 2) void attn_fused(
    const half_t* __restrict__ qb, const half_t* __restrict__ kb,
    const half_t* __restrict__ vb, half_t* __restrict__ att)
{
    __shared__ __align__(16) char lds[65536];
    // phase1: K_hi @0 (32KB), K_lo @32768 (32KB)
    // phase2: V @0 (16KB), per-wave P @32768 + w*9216 ([hi 4608][lo 4608], stride 72 halfs)
    // epilogue: O stage @0 ([128 i][132 halfs] = 33792B)
    int ic = blockIdx.x, h = blockIdx.y, img = blockIdx.z;
    int partner = img ^ 8;
    int t = threadIdx.x, w = t >> 6, lane = t & 63, quad = lane >> 4, l15 = lane & 15;
    const half_t* qp = qb + ((size_t)(img * 8 + h) * 1024 + ic * 128) * 128;
    const half_t* kp = kb + (size_t)(partner * 8 + h) * 256 * 128;
    const half_t* vp = vb + (size_t)(partner * 8 + h) * 64 * 512;

    // ---- stage K_hi, barrier, then prefetch K_lo (drained by the ph0->ph1 barrier) ----
    #pragma unroll
    for (int ii = 0; ii < 8; ++ii) {
        int u = ii * 256 + t;
        int nt = u >> 7, kcs = (u >> 6) & 1, q = (u >> 4) & 3, r = u & 15;
        gll16(kp + (size_t)(nt * 16 + r) * 128 + kcs * 32 + q * 8, lds + (u & ~63) * 16);
    }
    __syncthreads();
    #pragma unroll
    for (int ii = 0; ii < 8; ++ii) {
        int u = ii * 256 + t;
        int nt = u >> 7, kcs = (u >> 6) & 1, q = (u >> 4) & 3, r = u & 15;
        gll16(kp + (size_t)(nt * 16 + r) * 128 + 64 + kcs * 32 + q * 8,
              lds + 32768 + (u & ~63) * 16);
    }

    // ---- phase 1: S[128 i][256 j] ----
    f32x4 sacc[2][16] = {};
    for (int ph = 0; ph < 3; ++ph) {
        if (ph == 1) __syncthreads();              // K_lo ready (vmcnt drained)
        int aoff = (ph == 2) ? 64 : 0;
        const char* kl = (ph == 1) ? lds + 32768 : lds;
        #pragma unroll
        for (int kcs = 0; kcs < 2; ++kcs) {
            half8 af0 = *(const half8*)(qp + (size_t)(w * 32 + l15) * 128 + aoff + kcs * 32 + quad * 8);
            half8 af1 = *(const half8*)(qp + (size_t)(w * 32 + 16 + l15) * 128 + aoff + kcs * 32 + quad * 8);
            #pragma unroll
            for (int nt = 0; nt < 16; ++nt) {
                half8 bf = *(const half8*)(kl + (nt * 2 + kcs) * 1024 + lane * 16);
                sacc[0][nt] = __builtin_amdgcn_mfma_f32_16x16x32_f16(af0, bf, sacc[0][nt], 0, 0, 0);
                sacc[1][nt] = __builtin_amdgcn_mfma_f32_16x16x32_f16(af1, bf, sacc[1][nt], 0, 0, 0);
            }
        }
    }

    // ---- softmax over j (rows: mi*16 + quad*4 + r; cols: nt*16 + l15) ----
    #pragma unroll
    for (int mi = 0; mi < 2; ++mi)
        #pragma unroll
        for (int r = 0; r < 4; ++r) {
            float mx = sacc[mi][0][r];
            #pragma unroll
            for (int nt = 1; nt < 16; ++nt) mx = fmaxf(mx, sacc[mi][nt][r]);
            #pragma unroll
            for (int off = 1; off < 16; off <<= 1) mx = fmaxf(mx, __shfl_xor(mx, off, 64));
            float sum = 0.f;
            #pragma unroll
            for (int nt = 0; nt < 16; ++nt) {
                float e = __expf(sacc[mi][nt][r] - mx);
                sacc[mi][nt][r] = e; sum += e;
            }
            #pragma unroll
            for (int off = 1; off < 16; off <<= 1) sum += __shfl_xor(sum, off, 64);
            float inv = 1.f / sum;
            #pragma unroll
            for (int nt = 0; nt < 16; ++nt) sacc[mi][nt][r] *= inv;
        }

    // ---- phase 2: O[128 i][64 d] ----
    char* Pw = lds + 32768 + w * 9216;
    f32x4 oacc[2][4] = {};
    for (int jc = 0; jc < 4; ++jc) {
        // write P chunk (per-wave private region; read back after barrier)
        #pragma unroll
        for (int mi = 0; mi < 2; ++mi)
            #pragma unroll
            for (int n4 = 0; n4 < 4; ++n4)
                #pragma unroll
                for (int r = 0; r < 4; ++r) {
                    float pv = sacc[mi][jc * 4 + n4][r];
                    half_t hh = (half_t)pv;
                    int row = mi * 16 + quad * 4 + r, col = n4 * 16 + l15;
                    *(half_t*)(Pw + (row * 72 + col) * 2) = hh;
                    *(half_t*)(Pw + 4608 + (row * 72 + col) * 2) = (half_t)(pv - (float)hh);
                }
        __syncthreads();   // all waves done with previous V chunk (and K LDS at jc=0)
        #pragma unroll
        for (int ii = 0; ii < 4; ++ii) {
            int u = ii * 256 + t;
            int part = u >> 9, nt = (u >> 7) & 3, kcs = (u >> 6) & 1, q = (u >> 4) & 3, r = u & 15;
            gll16(vp + (size_t)(nt * 16 + r) * 512 + part * 256 + jc * 64 + kcs * 32 + q * 8,
                  lds + (u & ~63) * 16);
        }
        __syncthreads();   // V chunk ready (also publishes P)
        for (int ph = 0; ph < 3; ++ph) {
            int ppart = (ph == 2) ? 4608 : 0;
            int vpart = (ph == 1) ? 8192 : 0;
            #pragma unroll
            for (int kcs = 0; kcs < 2; ++kcs) {
                half8 af0 = *(const half8*)(Pw + ppart + ((l15) * 72 + kcs * 32 + quad * 8) * 2);
                half8 af1 = *(const half8*)(Pw + ppart + ((16 + l15) * 72 + kcs * 32 + quad * 8) * 2);
                #pragma unroll
                for (int nt = 0; nt < 4; ++nt) {
                    half8 bf = *(const half8*)(lds + vpart + (nt * 2 + kcs) * 1024 + lane * 16);
                    oacc[0][nt] = __builtin_amdgcn_mfma_f32_16x16x32_f16(af0, bf, oacc[0][nt], 0, 0, 0);
                    oacc[1][nt] = __builtin_amdgcn_mfma_f32_16x16x32_f16(af1, bf, oacc[1][nt], 0, 0, 0);
                }
            }
        }
    }

    // ---- epilogue: stage O (hi|lo) in LDS, coalesced 16B stores ----
    __syncthreads();
    #pragma unroll
    for (int mi = 0; mi < 2; ++mi)
        #pragma unroll
        for (int nt = 0; nt < 4; ++nt)
            #pragma unroll
            for (int r = 0; r < 4; ++r) {
                float vv = oacc[mi][nt][r];
                half_t hh = (half_t)vv;
                int row = w * 32 + mi * 16 + quad * 4 + r, col = nt * 16 + l15;
                *(half_t*)(lds + (row * 132 + col) * 2) = hh;
                *(half_t*)(lds + (row * 132 + 64 + col) * 2) = (half_t)(vv - (float)hh);
            }
    __syncthreads();
    #pragma unroll
    for (int ii = 0; ii < 8; ++ii) {
        int u = ii * 256 + t;
        int i = u >> 4, seg = (u >> 3) & 1, p8 = u & 7;
        half8 val = *(const half8*)(lds + (i * 132 + seg * 64 + p8 * 8) * 2);
        *(half8*)(att + ((size_t)img * 1024 + ic * 128 + i) * 1024 + seg * 512 + h * 64 + p8 * 8) = val;
    }
}

// ---------------- launch ----------------
extern "C" void kernel_launch(void* const* d_in, const int* in_sizes, int n_in,
                              void* d_out, int out_size, void* d_ws, size_t ws_size,
                              hipStream_t stream) {
    const float* x    = (const float*)d_in[0];
    const float* y    = (const float*)d_in[1];
    const float* qdw  = (const float*)d_in[2];
    const float* qg   = (const float*)d_in[3];
    const float* qbb  = (const float*)d_in[4];
    const float* qm   = (const float*)d_in[5];
    const float* qv   = (const float*)d_in[6];
    const float* qpw  = (const float*)d_in[7];
    const float* kvdw = (const float*)d_in[8];
    const float* kg   = (const float*)d_in[9];
    const float* kb_  = (const float*)d_in[10];
    const float* km   = (const float*)d_in[11];
    const float* kvv  = (const float*)d_in[12];
    const float* kvpw = (const float*)d_in[13];
    const float* outw = (const float*)d_in[14];
    const float* outb = (const float*)d_in[15];

    char* ws = (char*)d_ws;
    half_t* wq   = (half_t*)(ws);              //  512*512*2  = 524288
    half_t* wkv  = (half_t*)(ws + 524288);     // 1024*512*2  = 1048576
    half_t* wout = (half_t*)(ws + 1572864);    //  256*1024*2 = 524288
    float*  bq   = (float*) (ws + 2097152);
    float*  bkv  = (float*) (ws + 2099200);
    half_t* qpr  = (half_t*)(ws + 2103296);    // 16*8*1024*128*2 = 33554432
    half_t* kpr  = (half_t*)(ws + 35657728);   // 16*8*256*128*2  = 8388608
    half_t* vpr  = (half_t*)(ws + 44046336);   // 16*8*64*512*2   = 8388608
    half_t* qB   = (half_t*)(ws + 52434944);   // 16*1024*512*2   = 16777216
    half_t* kvB  = (half_t*)(ws + 69212160);   // 16*256*512*2    = 4194304
    half_t* attp = (half_t*)(ws + 52434944);   // aliases qB+kvB (dead by attn time): 33554432 -> 85989376
    // total 85,989,376 B

    prep_kernel<<<1792, 256, 0, stream>>>(
        qg, qbb, qm, qv, qpw, kg, kb_, km, kvv, kvpw, outw,
        wq, wkv, wout, bq, bkv);

    dw_pack_kernel<<<dim3(16, 16), 256, 0, stream>>>(x, y, qdw, kvdw, qB, kvB);

    // q' = (wq @ dwq + bq) * SCALE   [M=512, K=256, N=1024] -> MODE0
    gemm_split<4, 4, 2, 2, 0><<<dim3(8, 4, 16), 256, 0, stream>>>(
        wq, qB, qpr, bq, 256, 1024, 0L, 1024L * 512, ATT_SCALE);
    // k' = wkv[0:512] @ dwkv + bkv[0:512]   [M=512, K=256, N=256] -> MODE0
    gemm_split<2, 4, 2, 2, 0><<<dim3(2, 8, 16), 256, 0, stream>>>(
        wkv, kvB, kpr, bkv, 256, 256, 0L, 256L * 512, 1.0f);
    // v' = (wkv[512:] @ dwkv + bkv[512:])^T  [M=256 j, K=256, N=512 c] -> MODE1
    gemm_split<2, 4, 2, 2, 1><<<dim3(4, 4, 16), 256, 0, stream>>>(
        kvB, wkv + 512 * 512, vpr, bkv + 512, 256, 512, 256L * 512, 0L, 1.0f);

    attn_fused<<<dim3(8, 8, 16), 256, 0, stream>>>(qpr, kpr, vpr, attp);

    // out = wout @ att + outb  [M=256, K=512, N=1024] -> fp32 d_out
    gemm_split<4, 4, 2, 2, 2><<<dim3(8, 2, 16), 256, 0, stream>>>(
        wout, attp, d_out, outb, 512, 1024, 0L, 1024L * 1024, 1.0f);
}

// Round 4
// 252.399 us; speedup vs baseline: 1.5712x; 1.1331x over previous
//
#include <hip/hip_runtime.h>

#define BN_EPS 1e-5f
#define ATT_SCALE 0.125f   // 64^-0.5

typedef _Float16 half_t;
typedef _Float16 half8 __attribute__((ext_vector_type(8)));
typedef _Float16 half4 __attribute__((ext_vector_type(4)));
typedef float f32x4 __attribute__((ext_vector_type(4)));

// async global->LDS, 16B per lane; LDS dest = wave-uniform base + lane*16
__device__ __forceinline__ void gll16(const void* g, void* l) {
    __builtin_amdgcn_global_load_lds((const __attribute__((address_space(1))) void*)g,
                                     (__attribute__((address_space(3))) void*)l, 16, 0, 0);
}

// ================= fused prep (BN-fold + weight split) + dw-conv pack =================
__device__ void prep_body(
    int o, int c,
    const float* qg, const float* qb, const float* qm, const float* qv, const float* qpw,
    const float* kg, const float* kbt, const float* km, const float* kvv, const float* kvpw,
    const float* outw,
    half_t* wq, half_t* wkv, half_t* wout, float* bq, float* bkv, float* red)
{
    if (o >= 1536) {   // out_w rows: no BN, just split
        int ro = o - 1536;
        #pragma unroll
        for (int ci = 0; ci < 2; ++ci) {
            int cc = ci * 256 + c;
            float wv = outw[(size_t)ro * 512 + cc];
            half_t hh = (half_t)wv;
            wout[(size_t)ro * 1024 + cc]       = hh;
            wout[(size_t)ro * 1024 + 512 + cc] = (half_t)(wv - (float)hh);
        }
        return;
    }
    const float *g, *b, *m, *v, *w; half_t* we; float* be;
    if (o < 512) {
        g = qg; b = qb; m = qm; v = qv;
        w = qpw + (size_t)o * 256; we = wq + (size_t)o * 512; be = bq + o;
    } else {
        int ro = o - 512;
        g = kg; b = kbt; m = km; v = kvv;
        w = kvpw + (size_t)ro * 256; we = wkv + (size_t)ro * 512; be = bkv + ro;
    }
    float s  = g[c] * rsqrtf(v[c] + BN_EPS);
    float tt = b[c] - m[c] * s;
    float wv = w[c];
    float wsv = wv * s;
    half_t hh = (half_t)wsv;
    we[c]       = hh;
    we[256 + c] = (half_t)(wsv - (float)hh);
    float partial = wv * tt;
    #pragma unroll
    for (int off = 32; off > 0; off >>= 1)
        partial += __shfl_down(partial, off, 64);
    if ((c & 63) == 0) red[c >> 6] = partial;
    __syncthreads();
    if (c == 0) *be = red[0] + red[1] + red[2] + red[3];
}

__device__ void dw_body(
    int rp, int img, float* sin,
    const float* x, const float* y,
    const float* qdw, const float* kvdw,
    half_t* qB, half_t* kvB)
{
    const float* in = (img < 8) ? x + (size_t)img * 256 * 1024
                                : y + (size_t)(img - 8) * 256 * 1024;
    int t = threadIdx.x;
    int ch = t & 63, cg = t >> 6;
    int r0 = 2 * rp - 1;
    for (int cc = 0; cc < 4; ++cc) {
        __syncthreads();
        #pragma unroll
        for (int ii = 0; ii < 8; ++ii) {
            int u = ii * 256 + t;            // float4 unit
            int sch = u >> 5, row = (u >> 3) & 3, seg = u & 7;
            int gr = r0 + row;
            float4 v4 = {0.f, 0.f, 0.f, 0.f};
            if (gr >= 0 && gr < 32)
                v4 = *(const float4*)(in + (size_t)(cc * 64 + sch) * 1024 + gr * 32 + seg * 4);
            float* d = &sin[sch * 129 + row * 32 + seg * 4];
            d[0] = v4.x; d[1] = v4.y; d[2] = v4.z; d[3] = v4.w;
        }
        __syncthreads();
        int gch = cc * 64 + ch;
        float wq9[9], wk9[9];
        #pragma unroll
        for (int i = 0; i < 9; ++i) { wq9[i] = qdw[gch * 9 + i]; wk9[i] = kvdw[gch * 9 + i]; }
        const float* base = &sin[ch * 129];
        #pragma unroll
        for (int r = 0; r < 2; ++r) {
            #pragma unroll
            for (int c8 = 0; c8 < 8; ++c8) {
                int c = cg * 8 + c8;
                float acc = 0.f;
                #pragma unroll
                for (int dr = 0; dr < 3; ++dr) {
                    const float* rowp = base + (r + dr) * 32;
                    #pragma unroll
                    for (int dc = 0; dc < 3; ++dc) {
                        int cx = c + dc - 1;
                        float pv = (cx >= 0 && cx < 32) ? rowp[cx] : 0.f;
                        acc += wq9[dr * 3 + dc] * pv;
                    }
                }
                half_t hh = (half_t)acc;
                size_t p = (size_t)img * 1024 + (2 * rp + r) * 32 + c;
                qB[p * 512 + gch]       = hh;
                qB[p * 512 + 256 + gch] = (half_t)(acc - (float)hh);
            }
        }
        #pragma unroll
        for (int c4 = 0; c4 < 4; ++c4) {
            int c2 = cg * 4 + c4;
            float acc = 0.f;
            #pragma unroll
            for (int dr = 0; dr < 3; ++dr) {
                const float* rowp = base + dr * 32;
                #pragma unroll
                for (int dc = 0; dc < 3; ++dc) {
                    int cx = 2 * c2 + dc - 1;
                    float pv = (cx >= 0 && cx < 32) ? rowp[cx] : 0.f;
                    acc += wk9[dr * 3 + dc] * pv;
                }
            }
            half_t hh = (half_t)acc;
            size_t p = (size_t)img * 256 + rp * 16 + c2;
            kvB[p * 512 + gch]       = hh;
            kvB[p * 512 + 256 + gch] = (half_t)(acc - (float)hh);
        }
    }
}

__global__ __launch_bounds__(256) void prep_dw_kernel(
    const float* __restrict__ x, const float* __restrict__ y,
    const float* __restrict__ qdw, const float* __restrict__ kvdw,
    const float* __restrict__ qg, const float* __restrict__ qb,
    const float* __restrict__ qm, const float* __restrict__ qv,
    const float* __restrict__ qpw,
    const float* __restrict__ kg, const float* __restrict__ kbt,
    const float* __restrict__ km, const float* __restrict__ kvv,
    const float* __restrict__ kvpw,
    const float* __restrict__ outw,
    half_t* __restrict__ wq, half_t* __restrict__ wkv, half_t* __restrict__ wout,
    float* __restrict__ bq, float* __restrict__ bkv,
    half_t* __restrict__ qB, half_t* __restrict__ kvB)
{
    __shared__ __align__(16) float smem[64 * 129];
    int bx = blockIdx.x;
    if (bx < 256)
        dw_body(bx & 15, bx >> 4, smem, x, y, qdw, kvdw, qB, kvB);
    else
        prep_body(bx - 256, threadIdx.x, qg, qb, qm, qv, qpw,
                  kg, kbt, km, kvv, kvpw, outw, wq, wkv, wout, bq, bkv, smem);
}

// ================= split-f16 MFMA GEMM worker =================
// Per k-chunk: stage A_hi,A_lo,B_hi,B_lo once; 3 products (hh, hl, lh) per fragment.
// A [M][2K] hi|lo, B [N][2K] hi|lo; C = sum_k A*B^T. Ab/Bb pre-offset by m0/n0 (+img).
// MODE 0 (QK): f16 out [(img*8+h)*NPX + n][128]: hi d0, lo 64+d0; (acc+bias[m])*scale
// MODE 1 (V):  f16 out [(img*8+h)*64 + d][512]: hi at m, lo 256+m; acc+bias[n]
// MODE 2 (F32): fp32 out [img*256 + m][NPX] = acc + bias[m]
template<int MT, int NT, int WGM, int WGN, int MODE>
__device__ __forceinline__ void gemm_worker(
    char* lds, const half_t* Ab, const half_t* Bb,
    void* outBuf, const float* bias,
    int K, int NPX, int img, int m0, int n0, float scale)
{
    constexpr int TM = WGM * MT * 16, TN = WGN * NT * 16;
    char* Ah = lds;
    char* Al = lds + TM * 64;
    char* Bh = lds + TM * 128;
    char* Bl = lds + TM * 128 + TN * 64;
    int t = threadIdx.x, w = t >> 6, lane = t & 63, quad = lane >> 4, l15 = lane & 15;
    int wm = w % WGM, wn = w / WGM;
    f32x4 acc[MT][NT] = {};

    for (int kc = 0; kc < K; kc += 32) {
        __syncthreads();
        #pragma unroll
        for (int ii = 0; ii < TM / 64; ++ii) {
            int u = ii * 256 + t;
            int mt = u >> 6, q = (u >> 4) & 3, r = u & 15;
            const half_t* g = Ab + (size_t)(mt * 16 + r) * (2 * K) + kc + q * 8;
            gll16(g,     Ah + (u & ~63) * 16);
            gll16(g + K, Al + (u & ~63) * 16);
        }
        #pragma unroll
        for (int ii = 0; ii < TN / 64; ++ii) {
            int u = ii * 256 + t;
            int nt = u >> 6, q = (u >> 4) & 3, r = u & 15;
            const half_t* g = Bb + (size_t)(nt * 16 + r) * (2 * K) + kc + q * 8;
            gll16(g,     Bh + (u & ~63) * 16);
            gll16(g + K, Bl + (u & ~63) * 16);
        }
        __syncthreads();
        half8 afh[MT], afl[MT];
        #pragma unroll
        for (int mi = 0; mi < MT; ++mi) {
            afh[mi] = *(half8*)(Ah + (wm * MT + mi) * 1024 + lane * 16);
            afl[mi] = *(half8*)(Al + (wm * MT + mi) * 1024 + lane * 16);
        }
        #pragma unroll
        for (int ni = 0; ni < NT; ++ni) {
            half8 bh = *(half8*)(Bh + (wn * NT + ni) * 1024 + lane * 16);
            half8 bl = *(half8*)(Bl + (wn * NT + ni) * 1024 + lane * 16);
            #pragma unroll
            for (int mi = 0; mi < MT; ++mi) {
                acc[mi][ni] = __builtin_amdgcn_mfma_f32_16x16x32_f16(afh[mi], bh, acc[mi][ni], 0, 0, 0);
                acc[mi][ni] = __builtin_amdgcn_mfma_f32_16x16x32_f16(afh[mi], bl, acc[mi][ni], 0, 0, 0);
                acc[mi][ni] = __builtin_amdgcn_mfma_f32_16x16x32_f16(afl[mi], bh, acc[mi][ni], 0, 0, 0);
            }
        }
    }

    // epilogue (D layout: col = lane&15, row = quad*4 + reg)
    #pragma unroll
    for (int mi = 0; mi < MT; ++mi) {
        int mrow0 = m0 + wm * MT * 16 + mi * 16 + quad * 4;
        #pragma unroll
        for (int ni = 0; ni < NT; ++ni) {
            int col = n0 + wn * NT * 16 + ni * 16 + l15;
            f32x4 a = acc[mi][ni];
            if (MODE == 0) {
                int h = mrow0 >> 6, d0 = mrow0 & 63;
                half_t* op = (half_t*)outBuf + ((size_t)(img * 8 + h) * NPX + col) * 128 + d0;
                half4 hv, lv;
                #pragma unroll
                for (int r = 0; r < 4; ++r) {
                    float vv = (a[r] + bias[mrow0 + r]) * scale;
                    half_t hh = (half_t)vv;
                    hv[r] = hh; lv[r] = (half_t)(vv - (float)hh);
                }
                *(half4*)op = hv;
                *(half4*)(op + 64) = lv;
            } else if (MODE == 1) {
                int h = col >> 6, d = col & 63;
                half_t* op = (half_t*)outBuf + ((size_t)(img * 8 + h) * 64 + d) * 512 + mrow0;
                float bv = bias[col];
                half4 hv, lv;
                #pragma unroll
                for (int r = 0; r < 4; ++r) {
                    float vv = a[r] + bv;
                    half_t hh = (half_t)vv;
                    hv[r] = hh; lv[r] = (half_t)(vv - (float)hh);
                }
                *(half4*)op = hv;
                *(half4*)(op + 256) = lv;
            } else {
                float* op = (float*)outBuf + (size_t)img * 256 * NPX;
                #pragma unroll
                for (int r = 0; r < 4; ++r)
                    op[(size_t)(mrow0 + r) * NPX + col] = a[r] + bias[mrow0 + r];
            }
        }
    }
}

// ---- fused q/k/v projection dispatch: 48 tiles/img (32 q + 8 k + 8 v) ----
__global__ __launch_bounds__(256) void qkv_kernel(
    const half_t* __restrict__ wq, const half_t* __restrict__ wkv,
    const half_t* __restrict__ qB, const half_t* __restrict__ kvB,
    const float* __restrict__ bq, const float* __restrict__ bkv,
    half_t* __restrict__ qpr, half_t* __restrict__ kpr, half_t* __restrict__ vpr)
{
    __shared__ __align__(16) char lds[32768];
    int tile = blockIdx.x, img = blockIdx.z;
    if (tile < 32) {        // q': (wq @ dwq + bq)*SCALE  M=512 N=1024 K=256
        int m0 = (tile >> 3) * 128, n0 = (tile & 7) * 128;
        gemm_worker<4, 4, 2, 2, 0>(lds,
            wq + (size_t)m0 * 512,
            qB + (size_t)img * (1024 * 512) + (size_t)n0 * 512,
            qpr, bq, 256, 1024, img, m0, n0, ATT_SCALE);
    } else if (tile < 40) { // k': wkv[0:512] @ dwkv + bkv  M=512 N=256 K=256
        int tt = tile - 32;
        int m0 = (tt >> 1) * 128, n0 = (tt & 1) * 128;
        gemm_worker<4, 4, 2, 2, 0>(lds,
            wkv + (size_t)m0 * 512,
            kvB + (size_t)img * (256 * 512) + (size_t)n0 * 512,
            kpr, bkv, 256, 256, img, m0, n0, 1.0f);
    } else {                // v': (wkv[512:] @ dwkv + bkv)^T  M=256(j) N=512(c) K=256
        int tt = tile - 40;
        int m0 = (tt >> 2) * 128, n0 = (tt & 3) * 128;
        gemm_worker<4, 4, 2, 2, 1>(lds,
            kvB + (size_t)img * (256 * 512) + (size_t)m0 * 512,
            wkv + (size_t)(512 + n0) * 512,
            vpr, bkv + 512, 256, 512, img, m0, n0, 1.0f);
    }
}

// ---- out-proj: 64x128 tiles, 32 tiles/img ----
__global__ __launch_bounds__(256) void out_kernel(
    const half_t* __restrict__ wout, const half_t* __restrict__ attp,
    const float* __restrict__ outb, float* __restrict__ out)
{
    __shared__ __align__(16) char lds[24576];
    int tile = blockIdx.x, img = blockIdx.z;
    int m0 = (tile >> 3) * 64, n0 = (tile & 7) * 128;
    gemm_worker<4, 2, 1, 4, 2>(lds,
        wout + (size_t)m0 * 1024,
        attp + (size_t)img * (1024 * 1024) + (size_t)n0 * 1024,
        out, outb, 512, 1024, img, m0, n0, 1.0f);
}

// ================= attention: 128 queries/block, single-barrier phase 1 =================
// q' [(img*8+h)*1024 + i][128: d hi | d lo] (scale pre-folded)
// k' [(img*8+h)*256 + j][128], v' [(img*8+h)*64 + d][512: j hi | j lo]
// att' [img][1024 i][1024: c hi | 512 + c lo], c = h*64+d. partner = img^8.
__global__ __launch_bounds__(256) void attn_fused(
    const half_t* __restrict__ qb, const half_t* __restrict__ kb,
    const half_t* __restrict__ vb, half_t* __restrict__ att)
{
    __shared__ __align__(16) char lds[65536];
    // phase1: K_hi @0 (32KB), K_lo @32768 (32KB)
    // phase2: V @0 (16KB), P @16384 + w*9216 ([hi 4608][lo 4608]) -> ends 53248
    // epilogue: O stage @0 ([128][132] halfs = 33792B)
    int ic = blockIdx.x, h = blockIdx.y, img = blockIdx.z;
    int partner = img ^ 8;
    int t = threadIdx.x, w = t >> 6, lane = t & 63, quad = lane >> 4, l15 = lane & 15;
    const half_t* qp = qb + ((size_t)(img * 8 + h) * 1024 + ic * 128) * 128;
    const half_t* kp = kb + (size_t)(partner * 8 + h) * 256 * 128;
    const half_t* vp = vb + (size_t)(partner * 8 + h) * 64 * 512;

    // preload Q_hi frags (rows w*32 + mi*16 + l15)
    half8 qh[2][2];
    #pragma unroll
    for (int mi = 0; mi < 2; ++mi)
        #pragma unroll
        for (int kcs = 0; kcs < 2; ++kcs)
            qh[mi][kcs] = *(const half8*)(qp + (size_t)(w * 32 + mi * 16 + l15) * 128 + kcs * 32 + quad * 8);

    // stage K_hi + K_lo (one barrier)
    #pragma unroll
    for (int ii = 0; ii < 8; ++ii) {
        int u = ii * 256 + t;
        int nt = u >> 7, kcs = (u >> 6) & 1, q = (u >> 4) & 3, r = u & 15;
        const half_t* g = kp + (size_t)(nt * 16 + r) * 128 + kcs * 32 + q * 8;
        gll16(g,      lds + (u & ~63) * 16);
        gll16(g + 64, lds + 32768 + (u & ~63) * 16);
    }
    __syncthreads();

    // ---- phase 1: S[128 i][256 j] ----
    f32x4 sacc[2][16] = {};
    // pass A: Qh*Kh + Qh*Kl  (128 MFMAs/wave)
    #pragma unroll
    for (int kcs = 0; kcs < 2; ++kcs)
        #pragma unroll
        for (int nt = 0; nt < 16; ++nt) {
            half8 bh = *(const half8*)(lds + (nt * 2 + kcs) * 1024 + lane * 16);
            half8 bl = *(const half8*)(lds + 32768 + (nt * 2 + kcs) * 1024 + lane * 16);
            #pragma unroll
            for (int mi = 0; mi < 2; ++mi) {
                sacc[mi][nt] = __builtin_amdgcn_mfma_f32_16x16x32_f16(qh[mi][kcs], bh, sacc[mi][nt], 0, 0, 0);
                sacc[mi][nt] = __builtin_amdgcn_mfma_f32_16x16x32_f16(qh[mi][kcs], bl, sacc[mi][nt], 0, 0, 0);
            }
        }
    // load Q_lo (replaces qh pressure-wise only after use; small overlap)
    half8 ql[2][2];
    #pragma unroll
    for (int mi = 0; mi < 2; ++mi)
        #pragma unroll
        for (int kcs = 0; kcs < 2; ++kcs)
            ql[mi][kcs] = *(const half8*)(qp + (size_t)(w * 32 + mi * 16 + l15) * 128 + 64 + kcs * 32 + quad * 8);
    // pass B: Ql*Kh  (64 MFMAs/wave)
    #pragma unroll
    for (int kcs = 0; kcs < 2; ++kcs)
        #pragma unroll
        for (int nt = 0; nt < 16; ++nt) {
            half8 bh = *(const half8*)(lds + (nt * 2 + kcs) * 1024 + lane * 16);
            #pragma unroll
            for (int mi = 0; mi < 2; ++mi)
                sacc[mi][nt] = __builtin_amdgcn_mfma_f32_16x16x32_f16(ql[mi][kcs], bh, sacc[mi][nt], 0, 0, 0);
        }

    // ---- softmax over j (rows: mi*16 + quad*4 + r; cols: nt*16 + l15) ----
    #pragma unroll
    for (int mi = 0; mi < 2; ++mi)
        #pragma unroll
        for (int r = 0; r < 4; ++r) {
            float mx = sacc[mi][0][r];
            #pragma unroll
            for (int nt = 1; nt < 16; ++nt) mx = fmaxf(mx, sacc[mi][nt][r]);
            #pragma unroll
            for (int off = 1; off < 16; off <<= 1) mx = fmaxf(mx, __shfl_xor(mx, off, 64));
            float sum = 0.f;
            #pragma unroll
            for (int nt = 0; nt < 16; ++nt) {
                float e = __expf(sacc[mi][nt][r] - mx);
                sacc[mi][nt][r] = e; sum += e;
            }
            #pragma unroll
            for (int off = 1; off < 16; off <<= 1) sum += __shfl_xor(sum, off, 64);
            float inv = 1.f / sum;
            #pragma unroll
            for (int nt = 0; nt < 16; ++nt) sacc[mi][nt][r] *= inv;
        }
    __syncthreads();   // all waves done reading K LDS before P overwrites it

    // ---- phase 2: O[128 i][64 d] ----
    char* Pw = lds + 16384 + w * 9216;
    f32x4 oacc[2][4] = {};
    for (int jc = 0; jc < 4; ++jc) {
        #pragma unroll
        for (int mi = 0; mi < 2; ++mi)
            #pragma unroll
            for (int n4 = 0; n4 < 4; ++n4)
                #pragma unroll
                for (int r = 0; r < 4; ++r) {
                    float pv = sacc[mi][jc * 4 + n4][r];
                    half_t hh = (half_t)pv;
                    int row = mi * 16 + quad * 4 + r, col = n4 * 16 + l15;
                    *(half_t*)(Pw + (row * 72 + col) * 2) = hh;
                    *(half_t*)(Pw + 4608 + (row * 72 + col) * 2) = (half_t)(pv - (float)hh);
                }
        __syncthreads();   // previous V chunk consumed by all waves
        #pragma unroll
        for (int ii = 0; ii < 4; ++ii) {
            int u = ii * 256 + t;
            int part = u >> 9, nt = (u >> 7) & 3, kcs = (u >> 6) & 1, q = (u >> 4) & 3, r = u & 15;
            gll16(vp + (size_t)(nt * 16 + r) * 512 + part * 256 + jc * 64 + kcs * 32 + q * 8,
                  lds + (u & ~63) * 16);
        }
        __syncthreads();   // V ready (P also published, though per-wave private)
        #pragma unroll
        for (int kcs = 0; kcs < 2; ++kcs) {
            half8 ph0 = *(const half8*)(Pw + ((l15) * 72 + kcs * 32 + quad * 8) * 2);
            half8 ph1 = *(const half8*)(Pw + ((16 + l15) * 72 + kcs * 32 + quad * 8) * 2);
            half8 pl0 = *(const half8*)(Pw + 4608 + ((l15) * 72 + kcs * 32 + quad * 8) * 2);
            half8 pl1 = *(const half8*)(Pw + 4608 + ((16 + l15) * 72 + kcs * 32 + quad * 8) * 2);
            #pragma unroll
            for (int nt = 0; nt < 4; ++nt) {
                half8 vh = *(const half8*)(lds + (nt * 2 + kcs) * 1024 + lane * 16);
                half8 vl = *(const half8*)(lds + 8192 + (nt * 2 + kcs) * 1024 + lane * 16);
                oacc[0][nt] = __builtin_amdgcn_mfma_f32_16x16x32_f16(ph0, vh, oacc[0][nt], 0, 0, 0);
                oacc[0][nt] = __builtin_amdgcn_mfma_f32_16x16x32_f16(ph0, vl, oacc[0][nt], 0, 0, 0);
                oacc[0][nt] = __builtin_amdgcn_mfma_f32_16x16x32_f16(pl0, vh, oacc[0][nt], 0, 0, 0);
                oacc[1][nt] = __builtin_amdgcn_mfma_f32_16x16x32_f16(ph1, vh, oacc[1][nt], 0, 0, 0);
                oacc[1][nt] = __builtin_amdgcn_mfma_f32_16x16x32_f16(ph1, vl, oacc[1][nt], 0, 0, 0);
                oacc[1][nt] = __builtin_amdgcn_mfma_f32_16x16x32_f16(pl1, vh, oacc[1][nt], 0, 0, 0);
            }
        }
    }

    // ---- epilogue: stage O (hi|lo) in LDS, coalesced 16B stores ----
    __syncthreads();
    #pragma unroll
    for (int mi = 0; mi < 2; ++mi)
        #pragma unroll
        for (int nt = 0; nt < 4; ++nt)
            #pragma unroll
            for (int r = 0; r < 4; ++r) {
                float vv = oacc[mi][nt][r];
                half_t hh = (half_t)vv;
                int row = w * 32 + mi * 16 + quad * 4 + r, col = nt * 16 + l15;
                *(half_t*)(lds + (row * 132 + col) * 2) = hh;
                *(half_t*)(lds + (row * 132 + 64 + col) * 2) = (half_t)(vv - (float)hh);
            }
    __syncthreads();
    #pragma unroll
    for (int ii = 0; ii < 8; ++ii) {
        int u = ii * 256 + t;
        int i = u >> 4, seg = (u >> 3) & 1, p8 = u & 7;
        half8 val = *(const half8*)(lds + (i * 132 + seg * 64 + p8 * 8) * 2);
        *(half8*)(att + ((size_t)img * 1024 + ic * 128 + i) * 1024 + seg * 512 + h * 64 + p8 * 8) = val;
    }
}

// ================= launch =================
extern "C" void kernel_launch(void* const* d_in, const int* in_sizes, int n_in,
                              void* d_out, int out_size, void* d_ws, size_t ws_size,
                              hipStream_t stream) {
    const float* x    = (const float*)d_in[0];
    const float* y    = (const float*)d_in[1];
    const float* qdw  = (const float*)d_in[2];
    const float* qg   = (const float*)d_in[3];
    const float* qbb  = (const float*)d_in[4];
    const float* qm   = (const float*)d_in[5];
    const float* qv   = (const float*)d_in[6];
    const float* qpw  = (const float*)d_in[7];
    const float* kvdw = (const float*)d_in[8];
    const float* kg   = (const float*)d_in[9];
    const float* kb_  = (const float*)d_in[10];
    const float* km   = (const float*)d_in[11];
    const float* kvv  = (const float*)d_in[12];
    const float* kvpw = (const float*)d_in[13];
    const float* outw = (const float*)d_in[14];
    const float* outb = (const float*)d_in[15];

    char* ws = (char*)d_ws;
    half_t* wq   = (half_t*)(ws);              //  512*512*2  = 524288
    half_t* wkv  = (half_t*)(ws + 524288);     // 1024*512*2  = 1048576
    half_t* wout = (half_t*)(ws + 1572864);    //  256*1024*2 = 524288
    float*  bq   = (float*) (ws + 2097152);
    float*  bkv  = (float*) (ws + 2099200);
    half_t* qpr  = (half_t*)(ws + 2103296);    // 16*8*1024*128*2 = 33554432
    half_t* kpr  = (half_t*)(ws + 35657728);   // 16*8*256*128*2  = 8388608
    half_t* vpr  = (half_t*)(ws + 44046336);   // 16*8*64*512*2   = 8388608
    half_t* qB   = (half_t*)(ws + 52434944);   // 16*1024*512*2   = 16777216
    half_t* kvB  = (half_t*)(ws + 69212160);   // 16*256*512*2    = 4194304
    half_t* attp = (half_t*)(ws + 52434944);   // aliases qB+kvB (dead by attn time): 33554432
    // total 85,989,376 B

    prep_dw_kernel<<<2048, 256, 0, stream>>>(
        x, y, qdw, kvdw, qg, qbb, qm, qv, qpw, kg, kb_, km, kvv, kvpw, outw,
        wq, wkv, wout, bq, bkv, qB, kvB);

    qkv_kernel<<<dim3(48, 1, 16), 256, 0, stream>>>(
        wq, wkv, qB, kvB, bq, bkv, qpr, kpr, vpr);

    attn_fused<<<dim3(8, 8, 16), 256, 0, stream>>>(qpr, kpr, vpr, attp);

    out_kernel<<<dim3(32, 1, 16), 256, 0, stream>>>(wout, attp, outb, (float*)d_out);
}

// Round 5
// 249.107 us; speedup vs baseline: 1.5920x; 1.0132x over previous
//
#include <hip/hip_runtime.h>

#define BN_EPS 1e-5f
#define ATT_SCALE 0.125f   // 64^-0.5

typedef _Float16 half_t;
typedef _Float16 half8 __attribute__((ext_vector_type(8)));
typedef _Float16 half4 __attribute__((ext_vector_type(4)));
typedef float f32x4 __attribute__((ext_vector_type(4)));

// async global->LDS, 16B per lane; LDS dest = wave-uniform base + lane*16
__device__ __forceinline__ void gll16(const void* g, void* l) {
    __builtin_amdgcn_global_load_lds((const __attribute__((address_space(1))) void*)g,
                                     (__attribute__((address_space(3))) void*)l, 16, 0, 0);
}

// ================= fused prep (BN-fold + weight split) + dw-conv pack =================
__device__ void prep_body(
    int o, int c,
    const float* qg, const float* qb, const float* qm, const float* qv, const float* qpw,
    const float* kg, const float* kbt, const float* km, const float* kvv, const float* kvpw,
    const float* outw,
    half_t* wq, half_t* wkv, half_t* wout, float* bq, float* bkv, float* red)
{
    if (o >= 1536) {   // out_w rows: no BN, just split
        int ro = o - 1536;
        #pragma unroll
        for (int ci = 0; ci < 2; ++ci) {
            int cc = ci * 256 + c;
            float wv = outw[(size_t)ro * 512 + cc];
            half_t hh = (half_t)wv;
            wout[(size_t)ro * 1024 + cc]       = hh;
            wout[(size_t)ro * 1024 + 512 + cc] = (half_t)(wv - (float)hh);
        }
        return;
    }
    const float *g, *b, *m, *v, *w; half_t* we; float* be;
    if (o < 512) {
        g = qg; b = qb; m = qm; v = qv;
        w = qpw + (size_t)o * 256; we = wq + (size_t)o * 512; be = bq + o;
    } else {
        int ro = o - 512;
        g = kg; b = kbt; m = km; v = kvv;
        w = kvpw + (size_t)ro * 256; we = wkv + (size_t)ro * 512; be = bkv + ro;
    }
    float s  = g[c] * rsqrtf(v[c] + BN_EPS);
    float tt = b[c] - m[c] * s;
    float wv = w[c];
    float wsv = wv * s;
    half_t hh = (half_t)wsv;
    we[c]       = hh;
    we[256 + c] = (half_t)(wsv - (float)hh);
    float partial = wv * tt;
    #pragma unroll
    for (int off = 32; off > 0; off >>= 1)
        partial += __shfl_down(partial, off, 64);
    if ((c & 63) == 0) red[c >> 6] = partial;
    __syncthreads();
    if (c == 0) *be = red[0] + red[1] + red[2] + red[3];
}

__device__ void dw_body(
    int rp, int img, float* sin,
    const float* x, const float* y,
    const float* qdw, const float* kvdw,
    half_t* qB, half_t* kvB)
{
    const float* in = (img < 8) ? x + (size_t)img * 256 * 1024
                                : y + (size_t)(img - 8) * 256 * 1024;
    int t = threadIdx.x;
    int ch = t & 63, cg = t >> 6;
    int r0 = 2 * rp - 1;
    for (int cc = 0; cc < 4; ++cc) {
        __syncthreads();
        #pragma unroll
        for (int ii = 0; ii < 8; ++ii) {
            int u = ii * 256 + t;            // float4 unit
            int sch = u >> 5, row = (u >> 3) & 3, seg = u & 7;
            int gr = r0 + row;
            float4 v4 = {0.f, 0.f, 0.f, 0.f};
            if (gr >= 0 && gr < 32)
                v4 = *(const float4*)(in + (size_t)(cc * 64 + sch) * 1024 + gr * 32 + seg * 4);
            float* d = &sin[sch * 129 + row * 32 + seg * 4];
            d[0] = v4.x; d[1] = v4.y; d[2] = v4.z; d[3] = v4.w;
        }
        __syncthreads();
        int gch = cc * 64 + ch;
        float wq9[9], wk9[9];
        #pragma unroll
        for (int i = 0; i < 9; ++i) { wq9[i] = qdw[gch * 9 + i]; wk9[i] = kvdw[gch * 9 + i]; }
        const float* base = &sin[ch * 129];
        #pragma unroll
        for (int r = 0; r < 2; ++r) {
            #pragma unroll
            for (int c8 = 0; c8 < 8; ++c8) {
                int c = cg * 8 + c8;
                float acc = 0.f;
                #pragma unroll
                for (int dr = 0; dr < 3; ++dr) {
                    const float* rowp = base + (r + dr) * 32;
                    #pragma unroll
                    for (int dc = 0; dc < 3; ++dc) {
                        int cx = c + dc - 1;
                        float pv = (cx >= 0 && cx < 32) ? rowp[cx] : 0.f;
                        acc += wq9[dr * 3 + dc] * pv;
                    }
                }
                half_t hh = (half_t)acc;
                size_t p = (size_t)img * 1024 + (2 * rp + r) * 32 + c;
                qB[p * 512 + gch]       = hh;
                qB[p * 512 + 256 + gch] = (half_t)(acc - (float)hh);
            }
        }
        #pragma unroll
        for (int c4 = 0; c4 < 4; ++c4) {
            int c2 = cg * 4 + c4;
            float acc = 0.f;
            #pragma unroll
            for (int dr = 0; dr < 3; ++dr) {
                const float* rowp = base + dr * 32;
                #pragma unroll
                for (int dc = 0; dc < 3; ++dc) {
                    int cx = 2 * c2 + dc - 1;
                    float pv = (cx >= 0 && cx < 32) ? rowp[cx] : 0.f;
                    acc += wk9[dr * 3 + dc] * pv;
                }
            }
            half_t hh = (half_t)acc;
            size_t p = (size_t)img * 256 + rp * 16 + c2;
            kvB[p * 512 + gch]       = hh;
            kvB[p * 512 + 256 + gch] = (half_t)(acc - (float)hh);
        }
    }
}

__global__ __launch_bounds__(256) void prep_dw_kernel(
    const float* __restrict__ x, const float* __restrict__ y,
    const float* __restrict__ qdw, const float* __restrict__ kvdw,
    const float* __restrict__ qg, const float* __restrict__ qb,
    const float* __restrict__ qm, const float* __restrict__ qv,
    const float* __restrict__ qpw,
    const float* __restrict__ kg, const float* __restrict__ kbt,
    const float* __restrict__ km, const float* __restrict__ kvv,
    const float* __restrict__ kvpw,
    const float* __restrict__ outw,
    half_t* __restrict__ wq, half_t* __restrict__ wkv, half_t* __restrict__ wout,
    float* __restrict__ bq, float* __restrict__ bkv,
    half_t* __restrict__ qB, half_t* __restrict__ kvB)
{
    __shared__ __align__(16) float smem[64 * 129];
    int bx = blockIdx.x;
    if (bx < 256)
        dw_body(bx & 15, bx >> 4, smem, x, y, qdw, kvdw, qB, kvB);
    else
        prep_body(bx - 256, threadIdx.x, qg, qb, qm, qv, qpw,
                  kg, kbt, km, kvv, kvpw, outw, wq, wkv, wout, bq, bkv, smem);
}

// ================= split-f16 MFMA GEMM worker =================
// Per k-chunk: stage A_hi,A_lo,B_hi,B_lo once; 3 products (hh, hl, lh) per fragment.
// A [M][2K] hi|lo, B [N][2K] hi|lo; C = sum_k A*B^T. Ab/Bb pre-offset by m0/n0 (+img).
// MODE 0 (QK): f16 out [(img*8+h)*NPX + n][128]: hi d0, lo 64+d0; (acc+bias[m])*scale
// MODE 1 (V):  f16 out [(img*8+h)*64 + d][512]: hi at m, lo 256+m; acc+bias[n]
// MODE 2 (F32): fp32 out [img*256 + m][NPX] = acc + bias[m]
template<int MT, int NT, int WGM, int WGN, int MODE>
__device__ __forceinline__ void gemm_worker(
    char* lds, const half_t* Ab, const half_t* Bb,
    void* outBuf, const float* bias,
    int K, int NPX, int img, int m0, int n0, float scale)
{
    constexpr int TM = WGM * MT * 16, TN = WGN * NT * 16;
    char* Ah = lds;
    char* Al = lds + TM * 64;
    char* Bh = lds + TM * 128;
    char* Bl = lds + TM * 128 + TN * 64;
    int t = threadIdx.x, w = t >> 6, lane = t & 63, quad = lane >> 4, l15 = lane & 15;
    int wm = w % WGM, wn = w / WGM;
    f32x4 acc[MT][NT] = {};

    for (int kc = 0; kc < K; kc += 32) {
        __syncthreads();
        #pragma unroll
        for (int ii = 0; ii < TM / 64; ++ii) {
            int u = ii * 256 + t;
            int mt = u >> 6, q = (u >> 4) & 3, r = u & 15;
            const half_t* g = Ab + (size_t)(mt * 16 + r) * (2 * K) + kc + q * 8;
            gll16(g,     Ah + (u & ~63) * 16);
            gll16(g + K, Al + (u & ~63) * 16);
        }
        #pragma unroll
        for (int ii = 0; ii < TN / 64; ++ii) {
            int u = ii * 256 + t;
            int nt = u >> 6, q = (u >> 4) & 3, r = u & 15;
            const half_t* g = Bb + (size_t)(nt * 16 + r) * (2 * K) + kc + q * 8;
            gll16(g,     Bh + (u & ~63) * 16);
            gll16(g + K, Bl + (u & ~63) * 16);
        }
        __syncthreads();
        half8 afh[MT], afl[MT];
        #pragma unroll
        for (int mi = 0; mi < MT; ++mi) {
            afh[mi] = *(half8*)(Ah + (wm * MT + mi) * 1024 + lane * 16);
            afl[mi] = *(half8*)(Al + (wm * MT + mi) * 1024 + lane * 16);
        }
        #pragma unroll
        for (int ni = 0; ni < NT; ++ni) {
            half8 bh = *(half8*)(Bh + (wn * NT + ni) * 1024 + lane * 16);
            half8 bl = *(half8*)(Bl + (wn * NT + ni) * 1024 + lane * 16);
            #pragma unroll
            for (int mi = 0; mi < MT; ++mi) {
                acc[mi][ni] = __builtin_amdgcn_mfma_f32_16x16x32_f16(afh[mi], bh, acc[mi][ni], 0, 0, 0);
                acc[mi][ni] = __builtin_amdgcn_mfma_f32_16x16x32_f16(afh[mi], bl, acc[mi][ni], 0, 0, 0);
                acc[mi][ni] = __builtin_amdgcn_mfma_f32_16x16x32_f16(afl[mi], bh, acc[mi][ni], 0, 0, 0);
            }
        }
    }

    // epilogue (D layout: col = lane&15, row = quad*4 + reg)
    #pragma unroll
    for (int mi = 0; mi < MT; ++mi) {
        int mrow0 = m0 + wm * MT * 16 + mi * 16 + quad * 4;
        #pragma unroll
        for (int ni = 0; ni < NT; ++ni) {
            int col = n0 + wn * NT * 16 + ni * 16 + l15;
            f32x4 a = acc[mi][ni];
            if (MODE == 0) {
                int h = mrow0 >> 6, d0 = mrow0 & 63;
                half_t* op = (half_t*)outBuf + ((size_t)(img * 8 + h) * NPX + col) * 128 + d0;
                half4 hv, lv;
                #pragma unroll
                for (int r = 0; r < 4; ++r) {
                    float vv = (a[r] + bias[mrow0 + r]) * scale;
                    half_t hh = (half_t)vv;
                    hv[r] = hh; lv[r] = (half_t)(vv - (float)hh);
                }
                *(half4*)op = hv;
                *(half4*)(op + 64) = lv;
            } else if (MODE == 1) {
                int h = col >> 6, d = col & 63;
                half_t* op = (half_t*)outBuf + ((size_t)(img * 8 + h) * 64 + d) * 512 + mrow0;
                float bv = bias[col];
                half4 hv, lv;
                #pragma unroll
                for (int r = 0; r < 4; ++r) {
                    float vv = a[r] + bv;
                    half_t hh = (half_t)vv;
                    hv[r] = hh; lv[r] = (half_t)(vv - (float)hh);
                }
                *(half4*)op = hv;
                *(half4*)(op + 256) = lv;
            } else {
                float* op = (float*)outBuf + (size_t)img * 256 * NPX;
                #pragma unroll
                for (int r = 0; r < 4; ++r)
                    op[(size_t)(mrow0 + r) * NPX + col] = a[r] + bias[mrow0 + r];
            }
        }
    }
}

// ---- fused q/k/v projection dispatch: 96 64x128 tiles/img (64 q + 16 k + 16 v) ----
__global__ __launch_bounds__(256) void qkv_kernel(
    const half_t* __restrict__ wq, const half_t* __restrict__ wkv,
    const half_t* __restrict__ qB, const half_t* __restrict__ kvB,
    const float* __restrict__ bq, const float* __restrict__ bkv,
    half_t* __restrict__ qpr, half_t* __restrict__ kpr, half_t* __restrict__ vpr)
{
    __shared__ __align__(16) char lds[24576];
    int tile = blockIdx.x, img = blockIdx.z;
    if (tile < 64) {        // q': (wq @ dwq + bq)*SCALE  M=512 N=1024 K=256
        int m0 = (tile >> 3) * 64, n0 = (tile & 7) * 128;
        gemm_worker<2, 4, 2, 2, 0>(lds,
            wq + (size_t)m0 * 512,
            qB + (size_t)img * (1024 * 512) + (size_t)n0 * 512,
            qpr, bq, 256, 1024, img, m0, n0, ATT_SCALE);
    } else if (tile < 80) { // k': wkv[0:512] @ dwkv + bkv  M=512 N=256 K=256
        int tt = tile - 64;
        int m0 = (tt >> 1) * 64, n0 = (tt & 1) * 128;
        gemm_worker<2, 4, 2, 2, 0>(lds,
            wkv + (size_t)m0 * 512,
            kvB + (size_t)img * (256 * 512) + (size_t)n0 * 512,
            kpr, bkv, 256, 256, img, m0, n0, 1.0f);
    } else {                // v': (wkv[512:] @ dwkv + bkv)^T  M=256(j) N=512(c) K=256
        int tt = tile - 80;
        int m0 = (tt >> 2) * 64, n0 = (tt & 3) * 128;
        gemm_worker<2, 4, 2, 2, 1>(lds,
            kvB + (size_t)img * (256 * 512) + (size_t)m0 * 512,
            wkv + (size_t)(512 + n0) * 512,
            vpr, bkv + 512, 256, 512, img, m0, n0, 1.0f);
    }
}

// ---- out-proj: 64x64 tiles, 64 tiles/img ----
__global__ __launch_bounds__(256) void out_kernel(
    const half_t* __restrict__ wout, const half_t* __restrict__ attp,
    const float* __restrict__ outb, float* __restrict__ out)
{
    __shared__ __align__(16) char lds[16384];
    int tile = blockIdx.x, img = blockIdx.z;
    int m0 = (tile >> 4) * 64, n0 = (tile & 15) * 64;
    gemm_worker<2, 2, 2, 2, 2>(lds,
        wout + (size_t)m0 * 1024,
        attp + (size_t)img * (1024 * 1024) + (size_t)n0 * 1024,
        out, outb, 512, 1024, img, m0, n0, 1.0f);
}

// ================= attention: 512 threads (8 waves), 128 queries/block =================
// Each wave owns 16 query rows -> sacc[16] = 64 VGPRs (occupancy!).
// q' [(img*8+h)*1024 + i][128: d hi | d lo] (scale pre-folded)
// k' [(img*8+h)*256 + j][128], v' [(img*8+h)*64 + d][512: j hi | j lo]
// att' [img][1024 i][1024: c hi | 512 + c lo], c = h*64+d. partner = img^8.
__global__ __launch_bounds__(512, 4) void attn_fused(
    const half_t* __restrict__ qb, const half_t* __restrict__ kb,
    const half_t* __restrict__ vb, half_t* __restrict__ att)
{
    __shared__ __align__(16) char lds[65536];
    // phase1: K_hi @0 (32KB), K_lo @32768 (32KB)
    // phase2: V_hi @0 (8KB), V_lo @8192 (8KB), P @16384 + w*4608 ([hi 2304][lo 2304]) -> ends 53248
    // epilogue: O stage @0 ([128][132] halfs = 33792B)
    int ic = blockIdx.x, h = blockIdx.y, img = blockIdx.z;
    int partner = img ^ 8;
    int t = threadIdx.x, w = t >> 6, lane = t & 63, quad = lane >> 4, l15 = lane & 15;
    const half_t* qp = qb + ((size_t)(img * 8 + h) * 1024 + ic * 128) * 128;
    const half_t* kp = kb + (size_t)(partner * 8 + h) * 256 * 128;
    const half_t* vp = vb + (size_t)(partner * 8 + h) * 64 * 512;

    // Q frags for this wave's 16 rows (i = w*16 + l15)
    half8 qh[2], ql[2];
    #pragma unroll
    for (int kcs = 0; kcs < 2; ++kcs) {
        qh[kcs] = *(const half8*)(qp + (size_t)(w * 16 + l15) * 128 + kcs * 32 + quad * 8);
        ql[kcs] = *(const half8*)(qp + (size_t)(w * 16 + l15) * 128 + 64 + kcs * 32 + quad * 8);
    }

    // stage K_hi + K_lo (one barrier)
    #pragma unroll
    for (int ii = 0; ii < 4; ++ii) {
        int u = ii * 512 + t;
        const half_t* g = kp + (size_t)((u >> 7) * 16 + (u & 15)) * 128
                             + ((u >> 6) & 1) * 32 + ((u >> 4) & 3) * 8;
        gll16(g,      lds + (u & ~63) * 16);
        gll16(g + 64, lds + 32768 + (u & ~63) * 16);
    }
    __syncthreads();

    // ---- phase 1: S[16 i][256 j] per wave, 96 MFMAs ----
    f32x4 sacc[16] = {};
    #pragma unroll
    for (int kcs = 0; kcs < 2; ++kcs)
        #pragma unroll
        for (int nt = 0; nt < 16; ++nt) {
            half8 bh = *(const half8*)(lds + (nt * 2 + kcs) * 1024 + lane * 16);
            half8 bl = *(const half8*)(lds + 32768 + (nt * 2 + kcs) * 1024 + lane * 16);
            sacc[nt] = __builtin_amdgcn_mfma_f32_16x16x32_f16(qh[kcs], bh, sacc[nt], 0, 0, 0);
            sacc[nt] = __builtin_amdgcn_mfma_f32_16x16x32_f16(qh[kcs], bl, sacc[nt], 0, 0, 0);
            sacc[nt] = __builtin_amdgcn_mfma_f32_16x16x32_f16(ql[kcs], bh, sacc[nt], 0, 0, 0);
        }

    // ---- softmax over j (row = quad*4 + r; cols = nt*16 + l15) ----
    #pragma unroll
    for (int r = 0; r < 4; ++r) {
        float mx = sacc[0][r];
        #pragma unroll
        for (int nt = 1; nt < 16; ++nt) mx = fmaxf(mx, sacc[nt][r]);
        #pragma unroll
        for (int off = 1; off < 16; off <<= 1) mx = fmaxf(mx, __shfl_xor(mx, off, 64));
        float sum = 0.f;
        #pragma unroll
        for (int nt = 0; nt < 16; ++nt) {
            float e = __expf(sacc[nt][r] - mx);
            sacc[nt][r] = e; sum += e;
        }
        #pragma unroll
        for (int off = 1; off < 16; off <<= 1) sum += __shfl_xor(sum, off, 64);
        float inv = 1.f / sum;
        #pragma unroll
        for (int nt = 0; nt < 16; ++nt) sacc[nt][r] *= inv;
    }
    __syncthreads();   // all waves done reading K LDS before P overwrites it

    // ---- phase 2: O[16 i][64 d] per wave ----
    char* Pw = lds + 16384 + w * 4608;
    f32x4 oacc[4] = {};
    for (int jc = 0; jc < 4; ++jc) {
        #pragma unroll
        for (int n4 = 0; n4 < 4; ++n4)
            #pragma unroll
            for (int r = 0; r < 4; ++r) {
                float pv = sacc[jc * 4 + n4][r];
                half_t hh = (half_t)pv;
                int idx = ((quad * 4 + r) * 72 + n4 * 16 + l15) * 2;
                *(half_t*)(Pw + idx) = hh;
                *(half_t*)(Pw + 2304 + idx) = (half_t)(pv - (float)hh);
            }
        __syncthreads();   // previous V chunk consumed by all waves
        {
            const half_t* g = vp + (size_t)(((t >> 7) & 3) * 16 + (t & 15)) * 512
                                 + jc * 64 + ((t >> 6) & 1) * 32 + ((t >> 4) & 3) * 8;
            gll16(g,       lds + (t & ~63) * 16);
            gll16(g + 256, lds + 8192 + (t & ~63) * 16);
        }
        __syncthreads();   // V chunk ready
        #pragma unroll
        for (int kcs = 0; kcs < 2; ++kcs) {
            half8 ph = *(const half8*)(Pw + (l15 * 72 + kcs * 32 + quad * 8) * 2);
            half8 pl = *(const half8*)(Pw + 2304 + (l15 * 72 + kcs * 32 + quad * 8) * 2);
            #pragma unroll
            for (int nt = 0; nt < 4; ++nt) {
                half8 vh = *(const half8*)(lds + (nt * 2 + kcs) * 1024 + lane * 16);
                half8 vl = *(const half8*)(lds + 8192 + (nt * 2 + kcs) * 1024 + lane * 16);
                oacc[nt] = __builtin_amdgcn_mfma_f32_16x16x32_f16(ph, vh, oacc[nt], 0, 0, 0);
                oacc[nt] = __builtin_amdgcn_mfma_f32_16x16x32_f16(ph, vl, oacc[nt], 0, 0, 0);
                oacc[nt] = __builtin_amdgcn_mfma_f32_16x16x32_f16(pl, vh, oacc[nt], 0, 0, 0);
            }
        }
    }

    // ---- epilogue: stage O (hi|lo) in LDS, coalesced 16B stores ----
    __syncthreads();
    #pragma unroll
    for (int nt = 0; nt < 4; ++nt)
        #pragma unroll
        for (int r = 0; r < 4; ++r) {
            float vv = oacc[nt][r];
            half_t hh = (half_t)vv;
            int row = w * 16 + quad * 4 + r, col = nt * 16 + l15;
            *(half_t*)(lds + (row * 132 + col) * 2) = hh;
            *(half_t*)(lds + (row * 132 + 64 + col) * 2) = (half_t)(vv - (float)hh);
        }
    __syncthreads();
    #pragma unroll
    for (int ii = 0; ii < 4; ++ii) {
        int u = ii * 512 + t;
        int i = u >> 4, seg = (u >> 3) & 1, p8 = u & 7;
        half8 val = *(const half8*)(lds + (i * 132 + seg * 64 + p8 * 8) * 2);
        *(half8*)(att + ((size_t)img * 1024 + ic * 128 + i) * 1024 + seg * 512 + h * 64 + p8 * 8) = val;
    }
}

// ================= launch =================
extern "C" void kernel_launch(void* const* d_in, const int* in_sizes, int n_in,
                              void* d_out, int out_size, void* d_ws, size_t ws_size,
                              hipStream_t stream) {
    const float* x    = (const float*)d_in[0];
    const float* y    = (const float*)d_in[1];
    const float* qdw  = (const float*)d_in[2];
    const float* qg   = (const float*)d_in[3];
    const float* qbb  = (const float*)d_in[4];
    const float* qm   = (const float*)d_in[5];
    const float* qv   = (const float*)d_in[6];
    const float* qpw  = (const float*)d_in[7];
    const float* kvdw = (const float*)d_in[8];
    const float* kg   = (const float*)d_in[9];
    const float* kb_  = (const float*)d_in[10];
    const float* km   = (const float*)d_in[11];
    const float* kvv  = (const float*)d_in[12];
    const float* kvpw = (const float*)d_in[13];
    const float* outw = (const float*)d_in[14];
    const float* outb = (const float*)d_in[15];

    char* ws = (char*)d_ws;
    half_t* wq   = (half_t*)(ws);              //  512*512*2  = 524288
    half_t* wkv  = (half_t*)(ws + 524288);     // 1024*512*2  = 1048576
    half_t* wout = (half_t*)(ws + 1572864);    //  256*1024*2 = 524288
    float*  bq   = (float*) (ws + 2097152);
    float*  bkv  = (float*) (ws + 2099200);
    half_t* qpr  = (half_t*)(ws + 2103296);    // 16*8*1024*128*2 = 33554432
    half_t* kpr  = (half_t*)(ws + 35657728);   // 16*8*256*128*2  = 8388608
    half_t* vpr  = (half_t*)(ws + 44046336);   // 16*8*64*512*2   = 8388608
    half_t* qB   = (half_t*)(ws + 52434944);   // 16*1024*512*2   = 16777216
    half_t* kvB  = (half_t*)(ws + 69212160);   // 16*256*512*2    = 4194304
    half_t* attp = (half_t*)(ws + 52434944);   // aliases qB+kvB (dead by attn time): 33554432
    // total 85,989,376 B

    prep_dw_kernel<<<2048, 256, 0, stream>>>(
        x, y, qdw, kvdw, qg, qbb, qm, qv, qpw, kg, kb_, km, kvv, kvpw, outw,
        wq, wkv, wout, bq, bkv, qB, kvB);

    qkv_kernel<<<dim3(96, 1, 16), 256, 0, stream>>>(
        wq, wkv, qB, kvB, bq, bkv, qpr, kpr, vpr);

    attn_fused<<<dim3(8, 8, 16), 512, 0, stream>>>(qpr, kpr, vpr, attp);

    out_kernel<<<dim3(64, 1, 16), 256, 0, stream>>>(wout, attp, outb, (float*)d_out);
}

// Round 6
// 231.540 us; speedup vs baseline: 1.7127x; 1.0759x over previous
//
#include <hip/hip_runtime.h>

#define BN_EPS 1e-5f
#define ATT_SCALE 0.125f   // 64^-0.5

typedef _Float16 half_t;
typedef _Float16 half8 __attribute__((ext_vector_type(8)));
typedef _Float16 half4 __attribute__((ext_vector_type(4)));
typedef float f32x4 __attribute__((ext_vector_type(4)));

// async global->LDS, 16B per lane; LDS dest = wave-uniform base + lane*16
__device__ __forceinline__ void gll16(const void* g, void* l) {
    __builtin_amdgcn_global_load_lds((const __attribute__((address_space(1))) void*)g,
                                     (__attribute__((address_space(3))) void*)l, 16, 0, 0);
}

// ================= fused prep (BN-fold + weight split) + dw-conv pack =================
__device__ void prep_body(
    int o, int c,
    const float* qg, const float* qb, const float* qm, const float* qv, const float* qpw,
    const float* kg, const float* kbt, const float* km, const float* kvv, const float* kvpw,
    const float* outw,
    half_t* wq, half_t* wkv, half_t* wout, float* bq, float* bkv, float* red)
{
    if (o >= 1536) {   // out_w rows: no BN, just split
        int ro = o - 1536;
        #pragma unroll
        for (int ci = 0; ci < 2; ++ci) {
            int cc = ci * 256 + c;
            float wv = outw[(size_t)ro * 512 + cc];
            half_t hh = (half_t)wv;
            wout[(size_t)ro * 1024 + cc]       = hh;
            wout[(size_t)ro * 1024 + 512 + cc] = (half_t)(wv - (float)hh);
        }
        return;
    }
    const float *g, *b, *m, *v, *w; half_t* we; float* be;
    if (o < 512) {
        g = qg; b = qb; m = qm; v = qv;
        w = qpw + (size_t)o * 256; we = wq + (size_t)o * 512; be = bq + o;
    } else {
        int ro = o - 512;
        g = kg; b = kbt; m = km; v = kvv;
        w = kvpw + (size_t)ro * 256; we = wkv + (size_t)ro * 512; be = bkv + ro;
    }
    float s  = g[c] * rsqrtf(v[c] + BN_EPS);
    float tt = b[c] - m[c] * s;
    float wv = w[c];
    float wsv = wv * s;
    half_t hh = (half_t)wsv;
    we[c]       = hh;
    we[256 + c] = (half_t)(wsv - (float)hh);
    float partial = wv * tt;
    #pragma unroll
    for (int off = 32; off > 0; off >>= 1)
        partial += __shfl_down(partial, off, 64);
    if ((c & 63) == 0) red[c >> 6] = partial;
    __syncthreads();
    if (c == 0) *be = red[0] + red[1] + red[2] + red[3];
}

__device__ void dw_body(
    int rp, int img, float* sin,
    const float* x, const float* y,
    const float* qdw, const float* kvdw,
    half_t* qB, half_t* kvB)
{
    const float* in = (img < 8) ? x + (size_t)img * 256 * 1024
                                : y + (size_t)(img - 8) * 256 * 1024;
    int t = threadIdx.x;
    int ch = t & 63, cg = t >> 6;
    int r0 = 2 * rp - 1;
    for (int cc = 0; cc < 4; ++cc) {
        __syncthreads();
        #pragma unroll
        for (int ii = 0; ii < 8; ++ii) {
            int u = ii * 256 + t;            // float4 unit
            int sch = u >> 5, row = (u >> 3) & 3, seg = u & 7;
            int gr = r0 + row;
            float4 v4 = {0.f, 0.f, 0.f, 0.f};
            if (gr >= 0 && gr < 32)
                v4 = *(const float4*)(in + (size_t)(cc * 64 + sch) * 1024 + gr * 32 + seg * 4);
            float* d = &sin[sch * 129 + row * 32 + seg * 4];
            d[0] = v4.x; d[1] = v4.y; d[2] = v4.z; d[3] = v4.w;
        }
        __syncthreads();
        int gch = cc * 64 + ch;
        float wq9[9], wk9[9];
        #pragma unroll
        for (int i = 0; i < 9; ++i) { wq9[i] = qdw[gch * 9 + i]; wk9[i] = kvdw[gch * 9 + i]; }
        const float* base = &sin[ch * 129];
        #pragma unroll
        for (int r = 0; r < 2; ++r) {
            #pragma unroll
            for (int c8 = 0; c8 < 8; ++c8) {
                int c = cg * 8 + c8;
                float acc = 0.f;
                #pragma unroll
                for (int dr = 0; dr < 3; ++dr) {
                    const float* rowp = base + (r + dr) * 32;
                    #pragma unroll
                    for (int dc = 0; dc < 3; ++dc) {
                        int cx = c + dc - 1;
                        float pv = (cx >= 0 && cx < 32) ? rowp[cx] : 0.f;
                        acc += wq9[dr * 3 + dc] * pv;
                    }
                }
                half_t hh = (half_t)acc;
                size_t p = (size_t)img * 1024 + (2 * rp + r) * 32 + c;
                qB[p * 512 + gch]       = hh;
                qB[p * 512 + 256 + gch] = (half_t)(acc - (float)hh);
            }
        }
        #pragma unroll
        for (int c4 = 0; c4 < 4; ++c4) {
            int c2 = cg * 4 + c4;
            float acc = 0.f;
            #pragma unroll
            for (int dr = 0; dr < 3; ++dr) {
                const float* rowp = base + dr * 32;
                #pragma unroll
                for (int dc = 0; dc < 3; ++dc) {
                    int cx = 2 * c2 + dc - 1;
                    float pv = (cx >= 0 && cx < 32) ? rowp[cx] : 0.f;
                    acc += wk9[dr * 3 + dc] * pv;
                }
            }
            half_t hh = (half_t)acc;
            size_t p = (size_t)img * 256 + rp * 16 + c2;
            kvB[p * 512 + gch]       = hh;
            kvB[p * 512 + 256 + gch] = (half_t)(acc - (float)hh);
        }
    }
}

__global__ __launch_bounds__(256) void prep_dw_kernel(
    const float* __restrict__ x, const float* __restrict__ y,
    const float* __restrict__ qdw, const float* __restrict__ kvdw,
    const float* __restrict__ qg, const float* __restrict__ qb,
    const float* __restrict__ qm, const float* __restrict__ qv,
    const float* __restrict__ qpw,
    const float* __restrict__ kg, const float* __restrict__ kbt,
    const float* __restrict__ km, const float* __restrict__ kvv,
    const float* __restrict__ kvpw,
    const float* __restrict__ outw,
    half_t* __restrict__ wq, half_t* __restrict__ wkv, half_t* __restrict__ wout,
    float* __restrict__ bq, float* __restrict__ bkv,
    half_t* __restrict__ qB, half_t* __restrict__ kvB)
{
    __shared__ __align__(16) float smem[64 * 129];
    int bx = blockIdx.x;
    if (bx < 256)
        dw_body(bx & 15, bx >> 4, smem, x, y, qdw, kvdw, qB, kvB);
    else
        prep_body(bx - 256, threadIdx.x, qg, qb, qm, qv, qpw,
                  kg, kbt, km, kvv, kvpw, outw, wq, wkv, wout, bq, bkv, smem);
}

// ================= split-f16 MFMA GEMM worker =================
// Per k-chunk (KC = 32*KSTEPS): stage A_hi,A_lo,B_hi,B_lo once; 3 products per frag.
// A [M][2K] hi|lo, B [N][2K] hi|lo; C = sum_k A*B^T. Ab/Bb pre-offset by m0/n0 (+img).
// MODE 0 (QK): f16 out [(img*8+h)*NPX + n][128]: hi d0, lo 64+d0; (acc+bias[m])*scale
// MODE 1 (V):  f16 out [(img*8+h)*64 + d][512]: hi at m, lo 256+m; acc+bias[n]
//   (MODE 0/1 epilogue: LDS-transposed -> coalesced 16B stores)
// MODE 2 (F32): fp32 out [img*256 + m][NPX] = acc + bias[m]  (direct, lane-coalesced)
template<int MT, int NT, int WGM, int WGN, int KSTEPS, int MODE>
__device__ __forceinline__ void gemm_worker(
    char* lds, const half_t* Ab, const half_t* Bb,
    void* outBuf, const float* bias,
    int K, int NPX, int img, int m0, int n0, float scale)
{
    constexpr int TM = WGM * MT * 16, TN = WGN * NT * 16;
    constexpr int KC = 32 * KSTEPS;
    char* Ah = lds;
    char* Al = lds + TM * KC * 2;
    char* Bh = lds + TM * KC * 4;
    char* Bl = lds + TM * KC * 4 + TN * KC * 2;
    int t = threadIdx.x, w = t >> 6, lane = t & 63, quad = lane >> 4, l15 = lane & 15;
    int wm = w % WGM, wn = w / WGM;
    f32x4 acc[MT][NT] = {};

    for (int kc = 0; kc < K; kc += KC) {
        __syncthreads();
        #pragma unroll
        for (int ii = 0; ii < TM * KSTEPS / 64; ++ii) {
            int u = ii * 256 + t;
            int unit = u >> 6;                       // = mt*KSTEPS + ks
            int mt = unit / KSTEPS, ks = unit % KSTEPS;
            int q = (u >> 4) & 3, r = u & 15;
            const half_t* g = Ab + (size_t)(mt * 16 + r) * (2 * K) + kc + ks * 32 + q * 8;
            gll16(g,     Ah + (u & ~63) * 16);
            gll16(g + K, Al + (u & ~63) * 16);
        }
        #pragma unroll
        for (int ii = 0; ii < TN * KSTEPS / 64; ++ii) {
            int u = ii * 256 + t;
            int unit = u >> 6;
            int nt = unit / KSTEPS, ks = unit % KSTEPS;
            int q = (u >> 4) & 3, r = u & 15;
            const half_t* g = Bb + (size_t)(nt * 16 + r) * (2 * K) + kc + ks * 32 + q * 8;
            gll16(g,     Bh + (u & ~63) * 16);
            gll16(g + K, Bl + (u & ~63) * 16);
        }
        __syncthreads();
        #pragma unroll
        for (int ks = 0; ks < KSTEPS; ++ks) {
            half8 afh[MT], afl[MT];
            #pragma unroll
            for (int mi = 0; mi < MT; ++mi) {
                afh[mi] = *(half8*)(Ah + ((wm * MT + mi) * KSTEPS + ks) * 1024 + lane * 16);
                afl[mi] = *(half8*)(Al + ((wm * MT + mi) * KSTEPS + ks) * 1024 + lane * 16);
            }
            #pragma unroll
            for (int ni = 0; ni < NT; ++ni) {
                half8 bh = *(half8*)(Bh + ((wn * NT + ni) * KSTEPS + ks) * 1024 + lane * 16);
                half8 bl = *(half8*)(Bl + ((wn * NT + ni) * KSTEPS + ks) * 1024 + lane * 16);
                #pragma unroll
                for (int mi = 0; mi < MT; ++mi) {
                    acc[mi][ni] = __builtin_amdgcn_mfma_f32_16x16x32_f16(afh[mi], bh, acc[mi][ni], 0, 0, 0);
                    acc[mi][ni] = __builtin_amdgcn_mfma_f32_16x16x32_f16(afh[mi], bl, acc[mi][ni], 0, 0, 0);
                    acc[mi][ni] = __builtin_amdgcn_mfma_f32_16x16x32_f16(afl[mi], bh, acc[mi][ni], 0, 0, 0);
                }
            }
        }
    }

    if (MODE == 2) {
        // direct fp32 epilogue (already lane-coalesced: col = l15)
        #pragma unroll
        for (int mi = 0; mi < MT; ++mi) {
            int mrow0 = m0 + wm * MT * 16 + mi * 16 + quad * 4;
            #pragma unroll
            for (int ni = 0; ni < NT; ++ni) {
                int col = n0 + wn * NT * 16 + ni * 16 + l15;
                f32x4 a = acc[mi][ni];
                float* op = (float*)outBuf + (size_t)img * 256 * NPX;
                #pragma unroll
                for (int r = 0; r < 4; ++r)
                    op[(size_t)(mrow0 + r) * NPX + col] = a[r] + bias[mrow0 + r];
            }
        }
    } else {
        // LDS-transposed epilogue: process TM in 32-row quarters.
        // tbuf [TN][40 floats] (pad 40 -> float4-aligned rows, bounded conflicts)
        __syncthreads();
        float* tbuf = (float*)lds;
        constexpr int TP = 40;
        #pragma unroll
        for (int qtr = 0; qtr < TM / 32; ++qtr) {
            #pragma unroll
            for (int mi = 0; mi < MT; ++mi) {
                int rowblk = wm * MT * 16 + mi * 16;
                if (rowblk >= qtr * 32 && rowblk < qtr * 32 + 32) {
                    int mloc = rowblk - qtr * 32 + quad * 4;
                    #pragma unroll
                    for (int ni = 0; ni < NT; ++ni) {
                        int nloc = wn * NT * 16 + ni * 16 + l15;
                        #pragma unroll
                        for (int r = 0; r < 4; ++r) {
                            float vv = acc[mi][ni][r];
                            if (MODE == 0) vv = (vv + bias[m0 + rowblk + quad * 4 + r]) * scale;
                            else           vv = vv + bias[n0 + nloc];
                            tbuf[nloc * TP + mloc + r] = vv;
                        }
                    }
                }
            }
            __syncthreads();
            #pragma unroll
            for (int it = 0; it < (TN * 4) / 256; ++it) {
                int u = it * 256 + t;
                int n = u >> 2, mg = u & 3;
                float vv[8];
                *(float4*)&vv[0] = *(const float4*)&tbuf[n * TP + mg * 8];
                *(float4*)&vv[4] = *(const float4*)&tbuf[n * TP + mg * 8 + 4];
                half8 hv, lv;
                #pragma unroll
                for (int j = 0; j < 8; ++j) {
                    half_t hh = (half_t)vv[j];
                    hv[j] = hh; lv[j] = (half_t)(vv[j] - (float)hh);
                }
                int mglob = m0 + qtr * 32 + mg * 8;
                if (MODE == 0) {
                    int h = mglob >> 6, d0 = mglob & 63;
                    half_t* op = (half_t*)outBuf + ((size_t)(img * 8 + h) * NPX + n0 + n) * 128 + d0;
                    *(half8*)op = hv;
                    *(half8*)(op + 64) = lv;
                } else {
                    int nn = n0 + n, h = nn >> 6, d = nn & 63;
                    half_t* op = (half_t*)outBuf + ((size_t)(img * 8 + h) * 64 + d) * 512 + mglob;
                    *(half8*)op = hv;
                    *(half8*)(op + 256) = lv;
                }
            }
            __syncthreads();
        }
    }
}

// ---- fused q/k/v projection dispatch: 48 128x128 tiles/img (32 q + 8 k + 8 v) ----
__global__ __launch_bounds__(256) void qkv_kernel(
    const half_t* __restrict__ wq, const half_t* __restrict__ wkv,
    const half_t* __restrict__ qB, const half_t* __restrict__ kvB,
    const float* __restrict__ bq, const float* __restrict__ bkv,
    half_t* __restrict__ qpr, half_t* __restrict__ kpr, half_t* __restrict__ vpr)
{
    __shared__ __align__(16) char lds[32768];
    int tile = blockIdx.x, img = blockIdx.z;
    if (tile < 32) {        // q': (wq @ dwq + bq)*SCALE  M=512 N=1024 K=256
        int m0 = (tile >> 3) * 128, n0 = (tile & 7) * 128;
        gemm_worker<4, 4, 2, 2, 1, 0>(lds,
            wq + (size_t)m0 * 512,
            qB + (size_t)img * (1024 * 512) + (size_t)n0 * 512,
            qpr, bq, 256, 1024, img, m0, n0, ATT_SCALE);
    } else if (tile < 40) { // k': wkv[0:512] @ dwkv + bkv  M=512 N=256 K=256
        int tt = tile - 32;
        int m0 = (tt >> 1) * 128, n0 = (tt & 1) * 128;
        gemm_worker<4, 4, 2, 2, 1, 0>(lds,
            wkv + (size_t)m0 * 512,
            kvB + (size_t)img * (256 * 512) + (size_t)n0 * 512,
            kpr, bkv, 256, 256, img, m0, n0, 1.0f);
    } else {                // v': (wkv[512:] @ dwkv + bkv)^T  M=256(j) N=512(c) K=256
        int tt = tile - 40;
        int m0 = (tt >> 2) * 128, n0 = (tt & 3) * 128;
        gemm_worker<4, 4, 2, 2, 1, 1>(lds,
            kvB + (size_t)img * (256 * 512) + (size_t)m0 * 512,
            wkv + (size_t)(512 + n0) * 512,
            vpr, bkv + 512, 256, 512, img, m0, n0, 1.0f);
    }
}

// ---- out-proj: 64x128 tiles, KC=64 (KSTEPS=2), 32 tiles/img ----
__global__ __launch_bounds__(256) void out_kernel(
    const half_t* __restrict__ wout, const half_t* __restrict__ attp,
    const float* __restrict__ outb, float* __restrict__ out)
{
    __shared__ __align__(16) char lds[49152];
    int tile = blockIdx.x, img = blockIdx.z;
    int m0 = (tile >> 3) * 64, n0 = (tile & 7) * 128;
    gemm_worker<2, 4, 2, 2, 2, 2>(lds,
        wout + (size_t)m0 * 1024,
        attp + (size_t)img * (1024 * 1024) + (size_t)n0 * 1024,
        out, outb, 512, 1024, img, m0, n0, 1.0f);
}

// ================= attention: 512 threads (8 waves), 128 queries/block =================
// Each wave owns 16 query rows -> sacc[16] = 64 VGPRs (occupancy!).
// q' [(img*8+h)*1024 + i][128: d hi | d lo] (scale pre-folded)
// k' [(img*8+h)*256 + j][128], v' [(img*8+h)*64 + d][512: j hi | j lo]
// att' [img][1024 i][1024: c hi | 512 + c lo], c = h*64+d. partner = img^8.
__global__ __launch_bounds__(512, 4) void attn_fused(
    const half_t* __restrict__ qb, const half_t* __restrict__ kb,
    const half_t* __restrict__ vb, half_t* __restrict__ att)
{
    __shared__ __align__(16) char lds[65536];
    int ic = blockIdx.x, h = blockIdx.y, img = blockIdx.z;
    int partner = img ^ 8;
    int t = threadIdx.x, w = t >> 6, lane = t & 63, quad = lane >> 4, l15 = lane & 15;
    const half_t* qp = qb + ((size_t)(img * 8 + h) * 1024 + ic * 128) * 128;
    const half_t* kp = kb + (size_t)(partner * 8 + h) * 256 * 128;
    const half_t* vp = vb + (size_t)(partner * 8 + h) * 64 * 512;

    // Q frags for this wave's 16 rows (i = w*16 + l15)
    half8 qh[2], ql[2];
    #pragma unroll
    for (int kcs = 0; kcs < 2; ++kcs) {
        qh[kcs] = *(const half8*)(qp + (size_t)(w * 16 + l15) * 128 + kcs * 32 + quad * 8);
        ql[kcs] = *(const half8*)(qp + (size_t)(w * 16 + l15) * 128 + 64 + kcs * 32 + quad * 8);
    }

    // stage K_hi + K_lo (one barrier)
    #pragma unroll
    for (int ii = 0; ii < 4; ++ii) {
        int u = ii * 512 + t;
        const half_t* g = kp + (size_t)((u >> 7) * 16 + (u & 15)) * 128
                             + ((u >> 6) & 1) * 32 + ((u >> 4) & 3) * 8;
        gll16(g,      lds + (u & ~63) * 16);
        gll16(g + 64, lds + 32768 + (u & ~63) * 16);
    }
    __syncthreads();

    // ---- phase 1: S[16 i][256 j] per wave, 96 MFMAs ----
    f32x4 sacc[16] = {};
    #pragma unroll
    for (int kcs = 0; kcs < 2; ++kcs)
        #pragma unroll
        for (int nt = 0; nt < 16; ++nt) {
            half8 bh = *(const half8*)(lds + (nt * 2 + kcs) * 1024 + lane * 16);
            half8 bl = *(const half8*)(lds + 32768 + (nt * 2 + kcs) * 1024 + lane * 16);
            sacc[nt] = __builtin_amdgcn_mfma_f32_16x16x32_f16(qh[kcs], bh, sacc[nt], 0, 0, 0);
            sacc[nt] = __builtin_amdgcn_mfma_f32_16x16x32_f16(qh[kcs], bl, sacc[nt], 0, 0, 0);
            sacc[nt] = __builtin_amdgcn_mfma_f32_16x16x32_f16(ql[kcs], bh, sacc[nt], 0, 0, 0);
        }

    // ---- softmax over j (row = quad*4 + r; cols = nt*16 + l15) ----
    #pragma unroll
    for (int r = 0; r < 4; ++r) {
        float mx = sacc[0][r];
        #pragma unroll
        for (int nt = 1; nt < 16; ++nt) mx = fmaxf(mx, sacc[nt][r]);
        #pragma unroll
        for (int off = 1; off < 16; off <<= 1) mx = fmaxf(mx, __shfl_xor(mx, off, 64));
        float sum = 0.f;
        #pragma unroll
        for (int nt = 0; nt < 16; ++nt) {
            float e = __expf(sacc[nt][r] - mx);
            sacc[nt][r] = e; sum += e;
        }
        #pragma unroll
        for (int off = 1; off < 16; off <<= 1) sum += __shfl_xor(sum, off, 64);
        float inv = 1.f / sum;
        #pragma unroll
        for (int nt = 0; nt < 16; ++nt) sacc[nt][r] *= inv;
    }
    __syncthreads();   // all waves done reading K LDS before P overwrites it

    // ---- phase 2: O[16 i][64 d] per wave ----
    char* Pw = lds + 16384 + w * 4608;
    f32x4 oacc[4] = {};
    for (int jc = 0; jc < 4; ++jc) {
        #pragma unroll
        for (int n4 = 0; n4 < 4; ++n4)
            #pragma unroll
            for (int r = 0; r < 4; ++r) {
                float pv = sacc[jc * 4 + n4][r];
                half_t hh = (half_t)pv;
                int idx = ((quad * 4 + r) * 72 + n4 * 16 + l15) * 2;
                *(half_t*)(Pw + idx) = hh;
                *(half_t*)(Pw + 2304 + idx) = (half_t)(pv - (float)hh);
            }
        __syncthreads();   // previous V chunk consumed by all waves
        {
            const half_t* g = vp + (size_t)(((t >> 7) & 3) * 16 + (t & 15)) * 512
                                 + jc * 64 + ((t >> 6) & 1) * 32 + ((t >> 4) & 3) * 8;
            gll16(g,       lds + (t & ~63) * 16);
            gll16(g + 256, lds + 8192 + (t & ~63) * 16);
        }
        __syncthreads();   // V chunk ready
        #pragma unroll
        for (int kcs = 0; kcs < 2; ++kcs) {
            half8 ph = *(const half8*)(Pw + (l15 * 72 + kcs * 32 + quad * 8) * 2);
            half8 pl = *(const half8*)(Pw + 2304 + (l15 * 72 + kcs * 32 + quad * 8) * 2);
            #pragma unroll
            for (int nt = 0; nt < 4; ++nt) {
                half8 vh = *(const half8*)(lds + (nt * 2 + kcs) * 1024 + lane * 16);
                half8 vl = *(const half8*)(lds + 8192 + (nt * 2 + kcs) * 1024 + lane * 16);
                oacc[nt] = __builtin_amdgcn_mfma_f32_16x16x32_f16(ph, vh, oacc[nt], 0, 0, 0);
                oacc[nt] = __builtin_amdgcn_mfma_f32_16x16x32_f16(ph, vl, oacc[nt], 0, 0, 0);
                oacc[nt] = __builtin_amdgcn_mfma_f32_16x16x32_f16(pl, vh, oacc[nt], 0, 0, 0);
            }
        }
    }

    // ---- epilogue: stage O (hi|lo) in LDS, coalesced 16B stores ----
    __syncthreads();
    #pragma unroll
    for (int nt = 0; nt < 4; ++nt)
        #pragma unroll
        for (int r = 0; r < 4; ++r) {
            float vv = oacc[nt][r];
            half_t hh = (half_t)vv;
            int row = w * 16 + quad * 4 + r, col = nt * 16 + l15;
            *(half_t*)(lds + (row * 132 + col) * 2) = hh;
            *(half_t*)(lds + (row * 132 + 64 + col) * 2) = (half_t)(vv - (float)hh);
        }
    __syncthreads();
    #pragma unroll
    for (int ii = 0; ii < 4; ++ii) {
        int u = ii * 512 + t;
        int i = u >> 4, seg = (u >> 3) & 1, p8 = u & 7;
        half8 val = *(const half8*)(lds + (i * 132 + seg * 64 + p8 * 8) * 2);
        *(half8*)(att + ((size_t)img * 1024 + ic * 128 + i) * 1024 + seg * 512 + h * 64 + p8 * 8) = val;
    }
}

// ================= launch =================
extern "C" void kernel_launch(void* const* d_in, const int* in_sizes, int n_in,
                              void* d_out, int out_size, void* d_ws, size_t ws_size,
                              hipStream_t stream) {
    const float* x    = (const float*)d_in[0];
    const float* y    = (const float*)d_in[1];
    const float* qdw  = (const float*)d_in[2];
    const float* qg   = (const float*)d_in[3];
    const float* qbb  = (const float*)d_in[4];
    const float* qm   = (const float*)d_in[5];
    const float* qv   = (const float*)d_in[6];
    const float* qpw  = (const float*)d_in[7];
    const float* kvdw = (const float*)d_in[8];
    const float* kg   = (const float*)d_in[9];
    const float* kb_  = (const float*)d_in[10];
    const float* km   = (const float*)d_in[11];
    const float* kvv  = (const float*)d_in[12];
    const float* kvpw = (const float*)d_in[13];
    const float* outw = (const float*)d_in[14];
    const float* outb = (const float*)d_in[15];

    char* ws = (char*)d_ws;
    half_t* wq   = (half_t*)(ws);              //  512*512*2  = 524288
    half_t* wkv  = (half_t*)(ws + 524288);     // 1024*512*2  = 1048576
    half_t* wout = (half_t*)(ws + 1572864);    //  256*1024*2 = 524288
    float*  bq   = (float*) (ws + 2097152);
    float*  bkv  = (float*) (ws + 2099200);
    half_t* qpr  = (half_t*)(ws + 2103296);    // 16*8*1024*128*2 = 33554432
    half_t* kpr  = (half_t*)(ws + 35657728);   // 16*8*256*128*2  = 8388608
    half_t* vpr  = (half_t*)(ws + 44046336);   // 16*8*64*512*2   = 8388608
    half_t* qB   = (half_t*)(ws + 52434944);   // 16*1024*512*2   = 16777216
    half_t* kvB  = (half_t*)(ws + 69212160);   // 16*256*512*2    = 4194304
    half_t* attp = (half_t*)(ws + 52434944);   // aliases qB+kvB (dead by attn time): 33554432
    // total 85,989,376 B

    prep_dw_kernel<<<2048, 256, 0, stream>>>(
        x, y, qdw, kvdw, qg, qbb, qm, qv, qpw, kg, kb_, km, kvv, kvpw, outw,
        wq, wkv, wout, bq, bkv, qB, kvB);

    qkv_kernel<<<dim3(48, 1, 16), 256, 0, stream>>>(
        wq, wkv, qB, kvB, bq, bkv, qpr, kpr, vpr);

    attn_fused<<<dim3(8, 8, 16), 512, 0, stream>>>(qpr, kpr, vpr, attp);

    out_kernel<<<dim3(32, 1, 16), 256, 0, stream>>>(wout, attp, outb, (float*)d_out);
}

// Round 7
// 213.195 us; speedup vs baseline: 1.8601x; 1.0860x over previous
//
#include <hip/hip_runtime.h>

#define BN_EPS 1e-5f
#define ATT_SCALE 0.125f   // 64^-0.5

typedef _Float16 half_t;
typedef _Float16 half8 __attribute__((ext_vector_type(8)));
typedef _Float16 half4 __attribute__((ext_vector_type(4)));
typedef float f32x4 __attribute__((ext_vector_type(4)));

// async global->LDS, 16B per lane; LDS dest = wave-uniform base + lane*16
__device__ __forceinline__ void gll16(const void* g, void* l) {
    __builtin_amdgcn_global_load_lds((const __attribute__((address_space(1))) void*)g,
                                     (__attribute__((address_space(3))) void*)l, 16, 0, 0);
}

// ================= fused prep (BN-fold + weight split) + dw-conv pack =================
__device__ void prep_body(
    int o, int c,
    const float* qg, const float* qb, const float* qm, const float* qv, const float* qpw,
    const float* kg, const float* kbt, const float* km, const float* kvv, const float* kvpw,
    const float* outw,
    half_t* wq, half_t* wkv, half_t* wout, float* bq, float* bkv, float* red)
{
    if (o >= 1536) {   // out_w rows: no BN, just split
        int ro = o - 1536;
        #pragma unroll
        for (int ci = 0; ci < 2; ++ci) {
            int cc = ci * 256 + c;
            float wv = outw[(size_t)ro * 512 + cc];
            half_t hh = (half_t)wv;
            wout[(size_t)ro * 1024 + cc]       = hh;
            wout[(size_t)ro * 1024 + 512 + cc] = (half_t)(wv - (float)hh);
        }
        return;
    }
    const float *g, *b, *m, *v, *w; half_t* we; float* be;
    if (o < 512) {
        g = qg; b = qb; m = qm; v = qv;
        w = qpw + (size_t)o * 256; we = wq + (size_t)o * 512; be = bq + o;
    } else {
        int ro = o - 512;
        g = kg; b = kbt; m = km; v = kvv;
        w = kvpw + (size_t)ro * 256; we = wkv + (size_t)ro * 512; be = bkv + ro;
    }
    float s  = g[c] * rsqrtf(v[c] + BN_EPS);
    float tt = b[c] - m[c] * s;
    float wv = w[c];
    float wsv = wv * s;
    half_t hh = (half_t)wsv;
    we[c]       = hh;
    we[256 + c] = (half_t)(wsv - (float)hh);
    float partial = wv * tt;
    #pragma unroll
    for (int off = 32; off > 0; off >>= 1)
        partial += __shfl_down(partial, off, 64);
    if ((c & 63) == 0) red[c >> 6] = partial;
    __syncthreads();
    if (c == 0) *be = red[0] + red[1] + red[2] + red[3];
}

// dw conv with vectorized padded-LDS window reads.
// sin layout: ch*148 + row*36 + physcol; physcol = logical_col + 2 (logical -2..33).
__device__ void dw_body(
    int rp, int img, float* sin,
    const float* x, const float* y,
    const float* qdw, const float* kvdw,
    half_t* qB, half_t* kvB)
{
    const float* in = (img < 8) ? x + (size_t)img * 256 * 1024
                                : y + (size_t)(img - 8) * 256 * 1024;
    int t = threadIdx.x;
    int ch = t & 63, cg = t >> 6;
    int r0 = 2 * rp - 1;
    // zero pads (physical cols 0,1,34,35) once; staging only writes 2..33
    #pragma unroll
    for (int u = t; u < 1024; u += 256) {
        int c = u >> 4, row = (u >> 2) & 3, pi = u & 3;
        sin[c * 148 + row * 36 + (pi < 2 ? pi : 32 + pi)] = 0.f;
    }
    for (int cc = 0; cc < 4; ++cc) {
        __syncthreads();
        #pragma unroll
        for (int ii = 0; ii < 8; ++ii) {
            int u = ii * 256 + t;            // float4 unit
            int sch = u >> 5, row = (u >> 3) & 3, seg = u & 7;
            int gr = r0 + row;
            float4 v4 = {0.f, 0.f, 0.f, 0.f};
            if (gr >= 0 && gr < 32)
                v4 = *(const float4*)(in + (size_t)(cc * 64 + sch) * 1024 + gr * 32 + seg * 4);
            float* d = &sin[sch * 148 + row * 36 + 2 + seg * 4];  // 8B-aligned
            d[0] = v4.x; d[1] = v4.y; d[2] = v4.z; d[3] = v4.w;
        }
        __syncthreads();
        int gch = cc * 64 + ch;
        float wq9[9], wk9[9];
        #pragma unroll
        for (int i = 0; i < 9; ++i) { wq9[i] = qdw[gch * 9 + i]; wk9[i] = kvdw[gch * 9 + i]; }
        // load 4 rows x 12 floats (physical cg*8 .. cg*8+11 = logical cg*8-2 .. +9)
        float rowv[4][12];
        const float* base = &sin[ch * 148];
        #pragma unroll
        for (int rr = 0; rr < 4; ++rr) {
            *(float4*)&rowv[rr][0] = *(const float4*)(base + rr * 36 + cg * 8);
            *(float4*)&rowv[rr][4] = *(const float4*)(base + rr * 36 + cg * 8 + 4);
            *(float4*)&rowv[rr][8] = *(const float4*)(base + rr * 36 + cg * 8 + 8);
        }
        // q (stride 1): rows 2rp..2rp+1, cols cg*8..+8; tap e = c8+dc+1
        #pragma unroll
        for (int r = 0; r < 2; ++r) {
            #pragma unroll
            for (int c8 = 0; c8 < 8; ++c8) {
                float acc = 0.f;
                #pragma unroll
                for (int dr = 0; dr < 3; ++dr)
                    #pragma unroll
                    for (int dc = 0; dc < 3; ++dc)
                        acc += wq9[dr * 3 + dc] * rowv[r + dr][c8 + dc + 1];
                half_t hh = (half_t)acc;
                size_t p = (size_t)img * 1024 + (2 * rp + r) * 32 + cg * 8 + c8;
                qB[p * 512 + gch]       = hh;
                qB[p * 512 + 256 + gch] = (half_t)(acc - (float)hh);
            }
        }
        // kv (stride 2): row rp, cols cg*4..+4; tap e = 2*c4+dc+1
        #pragma unroll
        for (int c4 = 0; c4 < 4; ++c4) {
            float acc = 0.f;
            #pragma unroll
            for (int dr = 0; dr < 3; ++dr)
                #pragma unroll
                for (int dc = 0; dc < 3; ++dc)
                    acc += wk9[dr * 3 + dc] * rowv[dr][2 * c4 + dc + 1];
            half_t hh = (half_t)acc;
            size_t p = (size_t)img * 256 + rp * 16 + cg * 4 + c4;
            kvB[p * 512 + gch]       = hh;
            kvB[p * 512 + 256 + gch] = (half_t)(acc - (float)hh);
        }
    }
}

__global__ __launch_bounds__(256) void prep_dw_kernel(
    const float* __restrict__ x, const float* __restrict__ y,
    const float* __restrict__ qdw, const float* __restrict__ kvdw,
    const float* __restrict__ qg, const float* __restrict__ qb,
    const float* __restrict__ qm, const float* __restrict__ qv,
    const float* __restrict__ qpw,
    const float* __restrict__ kg, const float* __restrict__ kbt,
    const float* __restrict__ km, const float* __restrict__ kvv,
    const float* __restrict__ kvpw,
    const float* __restrict__ outw,
    half_t* __restrict__ wq, half_t* __restrict__ wkv, half_t* __restrict__ wout,
    float* __restrict__ bq, float* __restrict__ bkv,
    half_t* __restrict__ qB, half_t* __restrict__ kvB)
{
    __shared__ __align__(16) float smem[64 * 148];
    int bx = blockIdx.x;
    if (bx < 256)
        dw_body(bx & 15, bx >> 4, smem, x, y, qdw, kvdw, qB, kvB);
    else
        prep_body(bx - 256, threadIdx.x, qg, qb, qm, qv, qpw,
                  kg, kbt, km, kvv, kvpw, outw, wq, wkv, wout, bq, bkv, smem);
}

// ================= split-f16 MFMA GEMM worker (double-buffered, 1 barrier/chunk) ====
// KC=32. Per chunk: stage A_hi,A_lo,B_hi,B_lo for chunk k+1 after the barrier, compute k.
// A [M][2K] hi|lo, B [N][2K] hi|lo; C = sum_k A*B^T. Ab/Bb pre-offset by m0/n0 (+img).
// MODE 0 (QK): f16 out [(img*8+h)*NPX + n][128]: hi d0, lo 64+d0; (acc+bias[m])*scale
// MODE 1 (V):  f16 out [(img*8+h)*64 + d][512]: hi at m, lo 256+m; acc+bias[n]
//   (MODE 0/1: LDS-transposed epilogue -> coalesced 16B stores)
// MODE 2 (F32): fp32 out [img*256 + m][NPX] = acc + bias[m]  (direct)
template<int MT, int NT, int WGM, int WGN, int NTHR, int MODE>
__device__ __forceinline__ void gemm_worker(
    char* lds, const half_t* Ab, const half_t* Bb,
    void* outBuf, const float* bias,
    int K, int NPX, int img, int m0, int n0, float scale)
{
    constexpr int TM = WGM * MT * 16, TN = WGN * NT * 16;
    constexpr int BUF = (TM + TN) * 128;   // bytes per buffer (A hi/lo + B hi/lo)
    int t = threadIdx.x, w = t >> 6, lane = t & 63, quad = lane >> 4, l15 = lane & 15;
    int wm = w % WGM, wn = w / WGM;
    f32x4 acc[MT][NT] = {};
    const int NC = K / 32;

    auto stage = [&](int kh, int p) {   // kh = k offset in halfs
        char* Ah = lds + p * BUF;
        char* Al = Ah + TM * 64;
        char* Bh = Ah + TM * 128;
        char* Bl = Bh + TN * 64;
        #pragma unroll
        for (int ii = 0; ii < TM * 4 / NTHR; ++ii) {
            int u = ii * NTHR + t;
            int mt = u >> 6, q = (u >> 4) & 3, r = u & 15;
            const half_t* g = Ab + (size_t)(mt * 16 + r) * (2 * K) + kh + q * 8;
            gll16(g,     Ah + (u & ~63) * 16);
            gll16(g + K, Al + (u & ~63) * 16);
        }
        #pragma unroll
        for (int ii = 0; ii < TN * 4 / NTHR; ++ii) {
            int u = ii * NTHR + t;
            int nt = u >> 6, q = (u >> 4) & 3, r = u & 15;
            const half_t* g = Bb + (size_t)(nt * 16 + r) * (2 * K) + kh + q * 8;
            gll16(g,     Bh + (u & ~63) * 16);
            gll16(g + K, Bl + (u & ~63) * 16);
        }
    };

    stage(0, 0);
    for (int kc = 0; kc < NC; ++kc) {
        __syncthreads();                      // buf[kc&1] ready; buf[(kc+1)&1] free
        if (kc + 1 < NC) stage((kc + 1) * 32, (kc + 1) & 1);
        char* Ah = lds + (kc & 1) * BUF;
        char* Al = Ah + TM * 64;
        char* Bh = Ah + TM * 128;
        char* Bl = Bh + TN * 64;
        half8 afh[MT], afl[MT];
        #pragma unroll
        for (int mi = 0; mi < MT; ++mi) {
            afh[mi] = *(half8*)(Ah + (wm * MT + mi) * 1024 + lane * 16);
            afl[mi] = *(half8*)(Al + (wm * MT + mi) * 1024 + lane * 16);
        }
        #pragma unroll
        for (int ni = 0; ni < NT; ++ni) {
            half8 bh = *(half8*)(Bh + (wn * NT + ni) * 1024 + lane * 16);
            half8 bl = *(half8*)(Bl + (wn * NT + ni) * 1024 + lane * 16);
            #pragma unroll
            for (int mi = 0; mi < MT; ++mi) {
                acc[mi][ni] = __builtin_amdgcn_mfma_f32_16x16x32_f16(afh[mi], bh, acc[mi][ni], 0, 0, 0);
                acc[mi][ni] = __builtin_amdgcn_mfma_f32_16x16x32_f16(afh[mi], bl, acc[mi][ni], 0, 0, 0);
                acc[mi][ni] = __builtin_amdgcn_mfma_f32_16x16x32_f16(afl[mi], bh, acc[mi][ni], 0, 0, 0);
            }
        }
    }

    if (MODE == 2) {
        #pragma unroll
        for (int mi = 0; mi < MT; ++mi) {
            int mrow0 = m0 + wm * MT * 16 + mi * 16 + quad * 4;
            #pragma unroll
            for (int ni = 0; ni < NT; ++ni) {
                int col = n0 + wn * NT * 16 + ni * 16 + l15;
                f32x4 a = acc[mi][ni];
                float* op = (float*)outBuf + (size_t)img * 256 * NPX;
                #pragma unroll
                for (int r = 0; r < 4; ++r)
                    op[(size_t)(mrow0 + r) * NPX + col] = a[r] + bias[mrow0 + r];
            }
        }
    } else {
        // LDS-transposed epilogue: TM in 32-row quarters; tbuf [TN][40 floats]
        __syncthreads();
        float* tbuf = (float*)lds;
        constexpr int TP = 40;
        #pragma unroll
        for (int qtr = 0; qtr < TM / 32; ++qtr) {
            #pragma unroll
            for (int mi = 0; mi < MT; ++mi) {
                int rowblk = wm * MT * 16 + mi * 16;
                if (rowblk >= qtr * 32 && rowblk < qtr * 32 + 32) {
                    int mloc = rowblk - qtr * 32 + quad * 4;
                    #pragma unroll
                    for (int ni = 0; ni < NT; ++ni) {
                        int nloc = wn * NT * 16 + ni * 16 + l15;
                        #pragma unroll
                        for (int r = 0; r < 4; ++r) {
                            float vv = acc[mi][ni][r];
                            if (MODE == 0) vv = (vv + bias[m0 + rowblk + quad * 4 + r]) * scale;
                            else           vv = vv + bias[n0 + nloc];
                            tbuf[nloc * TP + mloc + r] = vv;
                        }
                    }
                }
            }
            __syncthreads();
            #pragma unroll
            for (int it = 0; it < (TN * 4) / NTHR; ++it) {
                int u = it * NTHR + t;
                int n = u >> 2, mg = u & 3;
                float vv[8];
                *(float4*)&vv[0] = *(const float4*)&tbuf[n * TP + mg * 8];
                *(float4*)&vv[4] = *(const float4*)&tbuf[n * TP + mg * 8 + 4];
                half8 hv, lv;
                #pragma unroll
                for (int j = 0; j < 8; ++j) {
                    half_t hh = (half_t)vv[j];
                    hv[j] = hh; lv[j] = (half_t)(vv[j] - (float)hh);
                }
                int mglob = m0 + qtr * 32 + mg * 8;
                if (MODE == 0) {
                    int h = mglob >> 6, d0 = mglob & 63;
                    half_t* op = (half_t*)outBuf + ((size_t)(img * 8 + h) * NPX + n0 + n) * 128 + d0;
                    *(half8*)op = hv;
                    *(half8*)(op + 64) = lv;
                } else {
                    int nn = n0 + n, h = nn >> 6, d = nn & 63;
                    half_t* op = (half_t*)outBuf + ((size_t)(img * 8 + h) * 64 + d) * 512 + mglob;
                    *(half8*)op = hv;
                    *(half8*)(op + 256) = lv;
                }
            }
            __syncthreads();
        }
    }
}

// ---- fused q/k/v projection: 48 128x128 tiles/img, 512 threads, dbuf 64KB ----
__global__ __launch_bounds__(512, 4) void qkv_kernel(
    const half_t* __restrict__ wq, const half_t* __restrict__ wkv,
    const half_t* __restrict__ qB, const half_t* __restrict__ kvB,
    const float* __restrict__ bq, const float* __restrict__ bkv,
    half_t* __restrict__ qpr, half_t* __restrict__ kpr, half_t* __restrict__ vpr)
{
    __shared__ __align__(16) char lds[65536];
    int tile = blockIdx.x, img = blockIdx.z;
    if (tile < 32) {        // q': (wq @ dwq + bq)*SCALE  M=512 N=1024 K=256
        int m0 = (tile >> 3) * 128, n0 = (tile & 7) * 128;
        gemm_worker<2, 4, 4, 2, 512, 0>(lds,
            wq + (size_t)m0 * 512,
            qB + (size_t)img * (1024 * 512) + (size_t)n0 * 512,
            qpr, bq, 256, 1024, img, m0, n0, ATT_SCALE);
    } else if (tile < 40) { // k': wkv[0:512] @ dwkv + bkv  M=512 N=256 K=256
        int tt = tile - 32;
        int m0 = (tt >> 1) * 128, n0 = (tt & 1) * 128;
        gemm_worker<2, 4, 4, 2, 512, 0>(lds,
            wkv + (size_t)m0 * 512,
            kvB + (size_t)img * (256 * 512) + (size_t)n0 * 512,
            kpr, bkv, 256, 256, img, m0, n0, 1.0f);
    } else {                // v': (wkv[512:] @ dwkv + bkv)^T  M=256(j) N=512(c) K=256
        int tt = tile - 40;
        int m0 = (tt >> 2) * 128, n0 = (tt & 3) * 128;
        gemm_worker<2, 4, 4, 2, 512, 1>(lds,
            kvB + (size_t)img * (256 * 512) + (size_t)m0 * 512,
            wkv + (size_t)(512 + n0) * 512,
            vpr, bkv + 512, 256, 512, img, m0, n0, 1.0f);
    }
}

// ---- out-proj: 64x128 tiles, 256 threads, dbuf 48KB, 32 tiles/img ----
__global__ __launch_bounds__(256, 3) void out_kernel(
    const half_t* __restrict__ wout, const half_t* __restrict__ attp,
    const float* __restrict__ outb, float* __restrict__ out)
{
    __shared__ __align__(16) char lds[49152];
    int tile = blockIdx.x, img = blockIdx.z;
    int m0 = (tile >> 3) * 64, n0 = (tile & 7) * 128;
    gemm_worker<2, 4, 2, 2, 256, 2>(lds,
        wout + (size_t)m0 * 1024,
        attp + (size_t)img * (1024 * 1024) + (size_t)n0 * 1024,
        out, outb, 512, 1024, img, m0, n0, 1.0f);
}

// ================= attention: 512 threads, 128 q/block, V double-buffered =========
// LDS: phase1 K_hi @0 (32K), K_lo @32768 (32K).
// phase2: V dbuf @0 and @16384 (each: hi 8K | lo 8K);
//         P @32768 + w*4096: hi 2K | lo 2K, stride 64 halfs, XOR-swizzled blocks.
// epilogue: O @0 (33792B). partner = img^8.
__global__ __launch_bounds__(512, 4) void attn_fused(
    const half_t* __restrict__ qb, const half_t* __restrict__ kb,
    const half_t* __restrict__ vb, half_t* __restrict__ att)
{
    __shared__ __align__(16) char lds[65536];
    int ic = blockIdx.x, h = blockIdx.y, img = blockIdx.z;
    int partner = img ^ 8;
    int t = threadIdx.x, w = t >> 6, lane = t & 63, quad = lane >> 4, l15 = lane & 15;
    const half_t* qp = qb + ((size_t)(img * 8 + h) * 1024 + ic * 128) * 128;
    const half_t* kp = kb + (size_t)(partner * 8 + h) * 256 * 128;
    const half_t* vp = vb + (size_t)(partner * 8 + h) * 64 * 512;

    // Q frags for this wave's 16 rows (i = w*16 + l15)
    half8 qh[2], ql[2];
    #pragma unroll
    for (int kcs = 0; kcs < 2; ++kcs) {
        qh[kcs] = *(const half8*)(qp + (size_t)(w * 16 + l15) * 128 + kcs * 32 + quad * 8);
        ql[kcs] = *(const half8*)(qp + (size_t)(w * 16 + l15) * 128 + 64 + kcs * 32 + quad * 8);
    }

    // stage K_hi + K_lo (one barrier)
    #pragma unroll
    for (int ii = 0; ii < 4; ++ii) {
        int u = ii * 512 + t;
        const half_t* g = kp + (size_t)((u >> 7) * 16 + (u & 15)) * 128
                             + ((u >> 6) & 1) * 32 + ((u >> 4) & 3) * 8;
        gll16(g,      lds + (u & ~63) * 16);
        gll16(g + 64, lds + 32768 + (u & ~63) * 16);
    }
    __syncthreads();

    // ---- phase 1: S[16 i][256 j] per wave, 96 MFMAs ----
    f32x4 sacc[16] = {};
    #pragma unroll
    for (int kcs = 0; kcs < 2; ++kcs)
        #pragma unroll
        for (int nt = 0; nt < 16; ++nt) {
            half8 bh = *(const half8*)(lds + (nt * 2 + kcs) * 1024 + lane * 16);
            half8 bl = *(const half8*)(lds + 32768 + (nt * 2 + kcs) * 1024 + lane * 16);
            sacc[nt] = __builtin_amdgcn_mfma_f32_16x16x32_f16(qh[kcs], bh, sacc[nt], 0, 0, 0);
            sacc[nt] = __builtin_amdgcn_mfma_f32_16x16x32_f16(qh[kcs], bl, sacc[nt], 0, 0, 0);
            sacc[nt] = __builtin_amdgcn_mfma_f32_16x16x32_f16(ql[kcs], bh, sacc[nt], 0, 0, 0);
        }

    // ---- softmax over j (row = quad*4 + r; cols = nt*16 + l15) ----
    #pragma unroll
    for (int r = 0; r < 4; ++r) {
        float mx = sacc[0][r];
        #pragma unroll
        for (int nt = 1; nt < 16; ++nt) mx = fmaxf(mx, sacc[nt][r]);
        #pragma unroll
        for (int off = 1; off < 16; off <<= 1) mx = fmaxf(mx, __shfl_xor(mx, off, 64));
        float sum = 0.f;
        #pragma unroll
        for (int nt = 0; nt < 16; ++nt) {
            float e = __expf(sacc[nt][r] - mx);
            sacc[nt][r] = e; sum += e;
        }
        #pragma unroll
        for (int off = 1; off < 16; off <<= 1) sum += __shfl_xor(sum, off, 64);
        float inv = 1.f / sum;
        #pragma unroll
        for (int nt = 0; nt < 16; ++nt) sacc[nt][r] *= inv;
    }
    __syncthreads();   // K LDS dead

    // stage V chunk 0 into buf0
    {
        int u = t;
        int nt = (u >> 7) & 3, kcs = (u >> 6) & 1, q = (u >> 4) & 3, r = u & 15;
        const half_t* g = vp + (size_t)(nt * 16 + r) * 512 + kcs * 32 + q * 8;
        gll16(g,       lds + (u & ~63) * 16);
        gll16(g + 256, lds + 8192 + (u & ~63) * 16);
    }

    // ---- phase 2: O[16 i][64 d] per wave, 1 barrier per jc ----
    char* Pw = lds + 32768 + w * 4096;    // hi 2K | lo 2K, swizzled
    f32x4 oacc[4] = {};
    for (int jc = 0; jc < 4; ++jc) {
        // write P chunk (wave-private, XOR-swizzled 16B blocks)
        #pragma unroll
        for (int n4 = 0; n4 < 4; ++n4)
            #pragma unroll
            for (int r = 0; r < 4; ++r) {
                float pv = sacc[jc * 4 + n4][r];
                half_t hh = (half_t)pv;
                int row = quad * 4 + r;
                int cb = (n4 * 16 + l15) * 2;
                int off = row * 128 + (cb ^ ((row & 7) << 4));
                *(half_t*)(Pw + off) = hh;
                *(half_t*)(Pw + 2048 + off) = (half_t)(pv - (float)hh);
            }
        __syncthreads();   // V[jc] ready; V[jc-1] consumers done
        if (jc < 3) {      // prefetch V[jc+1] into the other buffer
            int u = t;
            int nt = (u >> 7) & 3, kcs = (u >> 6) & 1, q = (u >> 4) & 3, r = u & 15;
            const half_t* g = vp + (size_t)(nt * 16 + r) * 512 + (jc + 1) * 64 + kcs * 32 + q * 8;
            char* nb = lds + ((jc + 1) & 1) * 16384;
            gll16(g,       nb + (u & ~63) * 16);
            gll16(g + 256, nb + 8192 + (u & ~63) * 16);
        }
        char* vbase = lds + (jc & 1) * 16384;
        #pragma unroll
        for (int kcs = 0; kcs < 2; ++kcs) {
            int pofs = (kcs * 64 + quad * 16) ^ ((l15 & 7) << 4);
            half8 ph = *(const half8*)(Pw + l15 * 128 + pofs);
            half8 pl = *(const half8*)(Pw + 2048 + l15 * 128 + pofs);
            #pragma unroll
            for (int nt = 0; nt < 4; ++nt) {
                half8 vh = *(const half8*)(vbase + (nt * 2 + kcs) * 1024 + lane * 16);
                half8 vl = *(const half8*)(vbase + 8192 + (nt * 2 + kcs) * 1024 + lane * 16);
                oacc[nt] = __builtin_amdgcn_mfma_f32_16x16x32_f16(ph, vh, oacc[nt], 0, 0, 0);
                oacc[nt] = __builtin_amdgcn_mfma_f32_16x16x32_f16(ph, vl, oacc[nt], 0, 0, 0);
                oacc[nt] = __builtin_amdgcn_mfma_f32_16x16x32_f16(pl, vh, oacc[nt], 0, 0, 0);
            }
        }
    }

    // ---- epilogue: stage O (hi|lo) in LDS, coalesced 16B stores ----
    __syncthreads();
    #pragma unroll
    for (int nt = 0; nt < 4; ++nt)
        #pragma unroll
        for (int r = 0; r < 4; ++r) {
            float vv = oacc[nt][r];
            half_t hh = (half_t)vv;
            int row = w * 16 + quad * 4 + r, col = nt * 16 + l15;
            *(half_t*)(lds + (row * 132 + col) * 2) = hh;
            *(half_t*)(lds + (row * 132 + 64 + col) * 2) = (half_t)(vv - (float)hh);
        }
    __syncthreads();
    #pragma unroll
    for (int ii = 0; ii < 4; ++ii) {
        int u = ii * 512 + t;
        int i = u >> 4, seg = (u >> 3) & 1, p8 = u & 7;
        half8 val = *(const half8*)(lds + (i * 132 + seg * 64 + p8 * 8) * 2);
        *(half8*)(att + ((size_t)img * 1024 + ic * 128 + i) * 1024 + seg * 512 + h * 64 + p8 * 8) = val;
    }
}

// ================= launch =================
extern "C" void kernel_launch(void* const* d_in, const int* in_sizes, int n_in,
                              void* d_out, int out_size, void* d_ws, size_t ws_size,
                              hipStream_t stream) {
    const float* x    = (const float*)d_in[0];
    const float* y    = (const float*)d_in[1];
    const float* qdw  = (const float*)d_in[2];
    const float* qg   = (const float*)d_in[3];
    const float* qbb  = (const float*)d_in[4];
    const float* qm   = (const float*)d_in[5];
    const float* qv   = (const float*)d_in[6];
    const float* qpw  = (const float*)d_in[7];
    const float* kvdw = (const float*)d_in[8];
    const float* kg   = (const float*)d_in[9];
    const float* kb_  = (const float*)d_in[10];
    const float* km   = (const float*)d_in[11];
    const float* kvv  = (const float*)d_in[12];
    const float* kvpw = (const float*)d_in[13];
    const float* outw = (const float*)d_in[14];
    const float* outb = (const float*)d_in[15];

    char* ws = (char*)d_ws;
    half_t* wq   = (half_t*)(ws);              //  512*512*2  = 524288
    half_t* wkv  = (half_t*)(ws + 524288);     // 1024*512*2  = 1048576
    half_t* wout = (half_t*)(ws + 1572864);    //  256*1024*2 = 524288
    float*  bq   = (float*) (ws + 2097152);
    float*  bkv  = (float*) (ws + 2099200);
    half_t* qpr  = (half_t*)(ws + 2103296);    // 16*8*1024*128*2 = 33554432
    half_t* kpr  = (half_t*)(ws + 35657728);   // 16*8*256*128*2  = 8388608
    half_t* vpr  = (half_t*)(ws + 44046336);   // 16*8*64*512*2   = 8388608
    half_t* qB   = (half_t*)(ws + 52434944);   // 16*1024*512*2   = 16777216
    half_t* kvB  = (half_t*)(ws + 69212160);   // 16*256*512*2    = 4194304
    half_t* attp = (half_t*)(ws + 52434944);   // aliases qB+kvB (dead by attn time): 33554432
    // total 85,989,376 B

    prep_dw_kernel<<<2048, 256, 0, stream>>>(
        x, y, qdw, kvdw, qg, qbb, qm, qv, qpw, kg, kb_, km, kvv, kvpw, outw,
        wq, wkv, wout, bq, bkv, qB, kvB);

    qkv_kernel<<<dim3(48, 1, 16), 512, 0, stream>>>(
        wq, wkv, qB, kvB, bq, bkv, qpr, kpr, vpr);

    attn_fused<<<dim3(8, 8, 16), 512, 0, stream>>>(qpr, kpr, vpr, attp);

    out_kernel<<<dim3(32, 1, 16), 256, 0, stream>>>(wout, attp, outb, (float*)d_out);
}

// Round 9
// 208.291 us; speedup vs baseline: 1.9039x; 1.0235x over previous
//
#include <hip/hip_runtime.h>

#define BN_EPS 1e-5f
#define ATT_SCALE 0.125f   // 64^-0.5

typedef _Float16 half_t;
typedef _Float16 half8 __attribute__((ext_vector_type(8)));
typedef _Float16 half4 __attribute__((ext_vector_type(4)));
typedef float f32x4 __attribute__((ext_vector_type(4)));

// async global->LDS, 16B per lane; LDS dest = wave-uniform base + lane*16
__device__ __forceinline__ void gll16(const void* g, void* l) {
    __builtin_amdgcn_global_load_lds((const __attribute__((address_space(1))) void*)g,
                                     (__attribute__((address_space(3))) void*)l, 16, 0, 0);
}

// ================= fused prep (BN-fold + weight split) + dw-conv pack =================
__device__ void prep_body(
    int o, int c,
    const float* qg, const float* qb, const float* qm, const float* qv, const float* qpw,
    const float* kg, const float* kbt, const float* km, const float* kvv, const float* kvpw,
    const float* outw,
    half_t* wq, half_t* wkv, half_t* wout, float* bq, float* bkv, float* red)
{
    if (o >= 1536) {   // out_w rows: no BN, just split
        int ro = o - 1536;
        #pragma unroll
        for (int ci = 0; ci < 2; ++ci) {
            int cc = ci * 256 + c;
            float wv = outw[(size_t)ro * 512 + cc];
            half_t hh = (half_t)wv;
            wout[(size_t)ro * 1024 + cc]       = hh;
            wout[(size_t)ro * 1024 + 512 + cc] = (half_t)(wv - (float)hh);
        }
        return;
    }
    const float *g, *b, *m, *v, *w; half_t* we; float* be;
    if (o < 512) {
        g = qg; b = qb; m = qm; v = qv;
        w = qpw + (size_t)o * 256; we = wq + (size_t)o * 512; be = bq + o;
    } else {
        int ro = o - 512;
        g = kg; b = kbt; m = km; v = kvv;
        w = kvpw + (size_t)ro * 256; we = wkv + (size_t)ro * 512; be = bkv + ro;
    }
    float s  = g[c] * rsqrtf(v[c] + BN_EPS);
    float tt = b[c] - m[c] * s;
    float wv = w[c];
    float wsv = wv * s;
    half_t hh = (half_t)wsv;
    we[c]       = hh;
    we[256 + c] = (half_t)(wsv - (float)hh);
    float partial = wv * tt;
    #pragma unroll
    for (int off = 32; off > 0; off >>= 1)
        partial += __shfl_down(partial, off, 64);
    if ((c & 63) == 0) red[c >> 6] = partial;
    __syncthreads();
    if (c == 0) *be = red[0] + red[1] + red[2] + red[3];
}

// dw conv with vectorized padded-LDS window reads.
// sin layout: ch*148 + row*36 + physcol; physcol = logical_col + 2 (logical -2..33).
__device__ void dw_body(
    int rp, int img, float* sin,
    const float* x, const float* y,
    const float* qdw, const float* kvdw,
    half_t* qB, half_t* kvB)
{
    const float* in = (img < 8) ? x + (size_t)img * 256 * 1024
                                : y + (size_t)(img - 8) * 256 * 1024;
    int t = threadIdx.x;
    int ch = t & 63, cg = t >> 6;
    int r0 = 2 * rp - 1;
    // zero pads (physical cols 0,1,34,35) once; staging only writes 2..33
    #pragma unroll
    for (int u = t; u < 1024; u += 256) {
        int c = u >> 4, row = (u >> 2) & 3, pi = u & 3;
        sin[c * 148 + row * 36 + (pi < 2 ? pi : 32 + pi)] = 0.f;
    }
    for (int cc = 0; cc < 4; ++cc) {
        __syncthreads();
        #pragma unroll
        for (int ii = 0; ii < 8; ++ii) {
            int u = ii * 256 + t;            // float4 unit
            int sch = u >> 5, row = (u >> 3) & 3, seg = u & 7;
            int gr = r0 + row;
            float4 v4 = {0.f, 0.f, 0.f, 0.f};
            if (gr >= 0 && gr < 32)
                v4 = *(const float4*)(in + (size_t)(cc * 64 + sch) * 1024 + gr * 32 + seg * 4);
            float* d = &sin[sch * 148 + row * 36 + 2 + seg * 4];  // 8B-aligned
            d[0] = v4.x; d[1] = v4.y; d[2] = v4.z; d[3] = v4.w;
        }
        __syncthreads();
        int gch = cc * 64 + ch;
        float wq9[9], wk9[9];
        #pragma unroll
        for (int i = 0; i < 9; ++i) { wq9[i] = qdw[gch * 9 + i]; wk9[i] = kvdw[gch * 9 + i]; }
        // load 4 rows x 12 floats (physical cg*8 .. cg*8+11 = logical cg*8-2 .. +9)
        float rowv[4][12];
        const float* base = &sin[ch * 148];
        #pragma unroll
        for (int rr = 0; rr < 4; ++rr) {
            *(float4*)&rowv[rr][0] = *(const float4*)(base + rr * 36 + cg * 8);
            *(float4*)&rowv[rr][4] = *(const float4*)(base + rr * 36 + cg * 8 + 4);
            *(float4*)&rowv[rr][8] = *(const float4*)(base + rr * 36 + cg * 8 + 8);
        }
        // q (stride 1): rows 2rp..2rp+1, cols cg*8..+8; tap e = c8+dc+1
        #pragma unroll
        for (int r = 0; r < 2; ++r) {
            #pragma unroll
            for (int c8 = 0; c8 < 8; ++c8) {
                float acc = 0.f;
                #pragma unroll
                for (int dr = 0; dr < 3; ++dr)
                    #pragma unroll
                    for (int dc = 0; dc < 3; ++dc)
                        acc += wq9[dr * 3 + dc] * rowv[r + dr][c8 + dc + 1];
                half_t hh = (half_t)acc;
                size_t p = (size_t)img * 1024 + (2 * rp + r) * 32 + cg * 8 + c8;
                qB[p * 512 + gch]       = hh;
                qB[p * 512 + 256 + gch] = (half_t)(acc - (float)hh);
            }
        }
        // kv (stride 2): row rp, cols cg*4..+4; tap e = 2*c4+dc+1
        #pragma unroll
        for (int c4 = 0; c4 < 4; ++c4) {
            float acc = 0.f;
            #pragma unroll
            for (int dr = 0; dr < 3; ++dr)
                #pragma unroll
                for (int dc = 0; dc < 3; ++dc)
                    acc += wk9[dr * 3 + dc] * rowv[dr][2 * c4 + dc + 1];
            half_t hh = (half_t)acc;
            size_t p = (size_t)img * 256 + rp * 16 + cg * 4 + c4;
            kvB[p * 512 + gch]       = hh;
            kvB[p * 512 + 256 + gch] = (half_t)(acc - (float)hh);
        }
    }
}

__global__ __launch_bounds__(256) void prep_dw_kernel(
    const float* __restrict__ x, const float* __restrict__ y,
    const float* __restrict__ qdw, const float* __restrict__ kvdw,
    const float* __restrict__ qg, const float* __restrict__ qb,
    const float* __restrict__ qm, const float* __restrict__ qv,
    const float* __restrict__ qpw,
    const float* __restrict__ kg, const float* __restrict__ kbt,
    const float* __restrict__ km, const float* __restrict__ kvv,
    const float* __restrict__ kvpw,
    const float* __restrict__ outw,
    half_t* __restrict__ wq, half_t* __restrict__ wkv, half_t* __restrict__ wout,
    float* __restrict__ bq, float* __restrict__ bkv,
    half_t* __restrict__ qB, half_t* __restrict__ kvB)
{
    __shared__ __align__(16) float smem[64 * 148];
    int bx = blockIdx.x;
    if (bx < 256)
        dw_body(bx & 15, bx >> 4, smem, x, y, qdw, kvdw, qB, kvB);
    else
        prep_body(bx - 256, threadIdx.x, qg, qb, qm, qv, qpw,
                  kg, kbt, km, kvv, kvpw, outw, wq, wkv, wout, bq, bkv, smem);
}

// ================= split-f16 MFMA GEMM worker (double-buffered, 1 barrier/chunk) ====
// KC=32. Per chunk: stage A_hi,A_lo,B_hi,B_lo for chunk k+1 after the barrier, compute k.
// A [M][2K] hi|lo, B [N][2K] hi|lo; C = sum_k A*B^T. Ab/Bb pre-offset by m0/n0 (+img).
// MODE 0 (QK): f16 out [(img*8+h)*NPX + n][128]: hi d0, lo 64+d0; (acc+bias[m])*scale
// MODE 1 (V):  f16 out [(img*8+h)*64 + d][512]: hi at m, lo 256+m; acc+bias[n]
//   (MODE 0/1: LDS-transposed epilogue -> coalesced 16B stores)
// MODE 2 (F32): fp32 out [img*256 + m][NPX] = acc + bias[m]  (direct)
template<int MT, int NT, int WGM, int WGN, int NTHR, int MODE>
__device__ __forceinline__ void gemm_worker(
    char* lds, const half_t* Ab, const half_t* Bb,
    void* outBuf, const float* bias,
    int K, int NPX, int img, int m0, int n0, float scale)
{
    constexpr int TM = WGM * MT * 16, TN = WGN * NT * 16;
    constexpr int BUF = (TM + TN) * 128;   // bytes per buffer (A hi/lo + B hi/lo)
    int t = threadIdx.x, w = t >> 6, lane = t & 63, quad = lane >> 4, l15 = lane & 15;
    int wm = w % WGM, wn = w / WGM;
    f32x4 acc[MT][NT] = {};
    const int NC = K / 32;

    auto stage = [&](int kh, int p) {   // kh = k offset in halfs
        char* Ah = lds + p * BUF;
        char* Al = Ah + TM * 64;
        char* Bh = Ah + TM * 128;
        char* Bl = Bh + TN * 64;
        #pragma unroll
        for (int ii = 0; ii < TM * 4 / NTHR; ++ii) {
            int u = ii * NTHR + t;
            int mt = u >> 6, q = (u >> 4) & 3, r = u & 15;
            const half_t* g = Ab + (size_t)(mt * 16 + r) * (2 * K) + kh + q * 8;
            gll16(g,     Ah + (u & ~63) * 16);
            gll16(g + K, Al + (u & ~63) * 16);
        }
        #pragma unroll
        for (int ii = 0; ii < TN * 4 / NTHR; ++ii) {
            int u = ii * NTHR + t;
            int nt = u >> 6, q = (u >> 4) & 3, r = u & 15;
            const half_t* g = Bb + (size_t)(nt * 16 + r) * (2 * K) + kh + q * 8;
            gll16(g,     Bh + (u & ~63) * 16);
            gll16(g + K, Bl + (u & ~63) * 16);
        }
    };

    stage(0, 0);
    for (int kc = 0; kc < NC; ++kc) {
        __syncthreads();                      // buf[kc&1] ready; buf[(kc+1)&1] free
        if (kc + 1 < NC) stage((kc + 1) * 32, (kc + 1) & 1);
        char* Ah = lds + (kc & 1) * BUF;
        char* Al = Ah + TM * 64;
        char* Bh = Ah + TM * 128;
        char* Bl = Bh + TN * 64;
        half8 afh[MT], afl[MT];
        #pragma unroll
        for (int mi = 0; mi < MT; ++mi) {
            afh[mi] = *(half8*)(Ah + (wm * MT + mi) * 1024 + lane * 16);
            afl[mi] = *(half8*)(Al + (wm * MT + mi) * 1024 + lane * 16);
        }
        #pragma unroll
        for (int ni = 0; ni < NT; ++ni) {
            half8 bh = *(half8*)(Bh + (wn * NT + ni) * 1024 + lane * 16);
            half8 bl = *(half8*)(Bl + (wn * NT + ni) * 1024 + lane * 16);
            #pragma unroll
            for (int mi = 0; mi < MT; ++mi) {
                acc[mi][ni] = __builtin_amdgcn_mfma_f32_16x16x32_f16(afh[mi], bh, acc[mi][ni], 0, 0, 0);
                acc[mi][ni] = __builtin_amdgcn_mfma_f32_16x16x32_f16(afh[mi], bl, acc[mi][ni], 0, 0, 0);
                acc[mi][ni] = __builtin_amdgcn_mfma_f32_16x16x32_f16(afl[mi], bh, acc[mi][ni], 0, 0, 0);
            }
        }
    }

    if (MODE == 2) {
        #pragma unroll
        for (int mi = 0; mi < MT; ++mi) {
            int mrow0 = m0 + wm * MT * 16 + mi * 16 + quad * 4;
            #pragma unroll
            for (int ni = 0; ni < NT; ++ni) {
                int col = n0 + wn * NT * 16 + ni * 16 + l15;
                f32x4 a = acc[mi][ni];
                float* op = (float*)outBuf + (size_t)img * 256 * NPX;
                #pragma unroll
                for (int r = 0; r < 4; ++r)
                    op[(size_t)(mrow0 + r) * NPX + col] = a[r] + bias[mrow0 + r];
            }
        }
    } else {
        // LDS-transposed epilogue: TM in 32-row quarters; tbuf [TN][40 floats]
        __syncthreads();
        float* tbuf = (float*)lds;
        constexpr int TP = 40;
        #pragma unroll
        for (int qtr = 0; qtr < TM / 32; ++qtr) {
            #pragma unroll
            for (int mi = 0; mi < MT; ++mi) {
                int rowblk = wm * MT * 16 + mi * 16;
                if (rowblk >= qtr * 32 && rowblk < qtr * 32 + 32) {
                    int mloc = rowblk - qtr * 32 + quad * 4;
                    #pragma unroll
                    for (int ni = 0; ni < NT; ++ni) {
                        int nloc = wn * NT * 16 + ni * 16 + l15;
                        #pragma unroll
                        for (int r = 0; r < 4; ++r) {
                            float vv = acc[mi][ni][r];
                            if (MODE == 0) vv = (vv + bias[m0 + rowblk + quad * 4 + r]) * scale;
                            else           vv = vv + bias[n0 + nloc];
                            tbuf[nloc * TP + mloc + r] = vv;
                        }
                    }
                }
            }
            __syncthreads();
            #pragma unroll
            for (int it = 0; it < (TN * 4) / NTHR; ++it) {
                int u = it * NTHR + t;
                int n = u >> 2, mg = u & 3;
                float vv[8];
                *(float4*)&vv[0] = *(const float4*)&tbuf[n * TP + mg * 8];
                *(float4*)&vv[4] = *(const float4*)&tbuf[n * TP + mg * 8 + 4];
                half8 hv, lv;
                #pragma unroll
                for (int j = 0; j < 8; ++j) {
                    half_t hh = (half_t)vv[j];
                    hv[j] = hh; lv[j] = (half_t)(vv[j] - (float)hh);
                }
                int mglob = m0 + qtr * 32 + mg * 8;
                if (MODE == 0) {
                    int h = mglob >> 6, d0 = mglob & 63;
                    half_t* op = (half_t*)outBuf + ((size_t)(img * 8 + h) * NPX + n0 + n) * 128 + d0;
                    *(half8*)op = hv;
                    *(half8*)(op + 64) = lv;
                } else {
                    int nn = n0 + n, h = nn >> 6, d = nn & 63;
                    half_t* op = (half_t*)outBuf + ((size_t)(img * 8 + h) * 64 + d) * 512 + mglob;
                    *(half8*)op = hv;
                    *(half8*)(op + 256) = lv;
                }
            }
            __syncthreads();
        }
    }
}

// ---- fused q/k/v projection: 48 128x128 tiles/img, 512 threads, dbuf 64KB ----
__global__ __launch_bounds__(512, 4) void qkv_kernel(
    const half_t* __restrict__ wq, const half_t* __restrict__ wkv,
    const half_t* __restrict__ qB, const half_t* __restrict__ kvB,
    const float* __restrict__ bq, const float* __restrict__ bkv,
    half_t* __restrict__ qpr, half_t* __restrict__ kpr, half_t* __restrict__ vpr)
{
    __shared__ __align__(16) char lds[65536];
    int tile = blockIdx.x, img = blockIdx.z;
    if (tile < 32) {        // q': (wq @ dwq + bq)*SCALE  M=512 N=1024 K=256
        int m0 = (tile >> 3) * 128, n0 = (tile & 7) * 128;
        gemm_worker<2, 4, 4, 2, 512, 0>(lds,
            wq + (size_t)m0 * 512,
            qB + (size_t)img * (1024 * 512) + (size_t)n0 * 512,
            qpr, bq, 256, 1024, img, m0, n0, ATT_SCALE);
    } else if (tile < 40) { // k': wkv[0:512] @ dwkv + bkv  M=512 N=256 K=256
        int tt = tile - 32;
        int m0 = (tt >> 1) * 128, n0 = (tt & 1) * 128;
        gemm_worker<2, 4, 4, 2, 512, 0>(lds,
            wkv + (size_t)m0 * 512,
            kvB + (size_t)img * (256 * 512) + (size_t)n0 * 512,
            kpr, bkv, 256, 256, img, m0, n0, 1.0f);
    } else {                // v': (wkv[512:] @ dwkv + bkv)^T  M=256(j) N=512(c) K=256
        int tt = tile - 40;
        int m0 = (tt >> 2) * 128, n0 = (tt & 3) * 128;
        gemm_worker<2, 4, 4, 2, 512, 1>(lds,
            kvB + (size_t)img * (256 * 512) + (size_t)m0 * 512,
            wkv + (size_t)(512 + n0) * 512,
            vpr, bkv + 512, 256, 512, img, m0, n0, 1.0f);
    }
}

// ---- out-proj: 64x128 tiles, 256 threads, dbuf 48KB, 32 tiles/img ----
__global__ __launch_bounds__(256, 3) void out_kernel(
    const half_t* __restrict__ wout, const half_t* __restrict__ attp,
    const float* __restrict__ outb, float* __restrict__ out)
{
    __shared__ __align__(16) char lds[49152];
    int tile = blockIdx.x, img = blockIdx.z;
    int m0 = (tile >> 3) * 64, n0 = (tile & 7) * 128;
    gemm_worker<2, 4, 2, 2, 256, 2>(lds,
        wout + (size_t)m0 * 1024,
        attp + (size_t)img * (1024 * 1024) + (size_t)n0 * 1024,
        out, outb, 512, 1024, img, m0, n0, 1.0f);
}

// ================= attention: 512 threads, 128 q/block =================
// Grid: x = h*16 + img (same (img,h) group + partner pair -> same XCD), y = ic.
// Deferred softmax normalization: P~ = exp(S - m) computed inside the jc loop
// (pipe mixing); O scaled by 1/l in the epilogue.
// LDS: phase1 K_hi @0 (32K), K_lo @32768 (32K).
// phase2: V @0 (hi 8K | lo 8K), P @16384 + w*4608 (hi 2304 | lo 2304, stride 72)
//         -> ends 16384 + 8*4608 = 53248 <= 65536.
// epilogue: O @0 (33792B). partner = img^8.
__global__ __launch_bounds__(512, 4) void attn_fused(
    const half_t* __restrict__ qb, const half_t* __restrict__ kb,
    const half_t* __restrict__ vb, half_t* __restrict__ att)
{
    __shared__ __align__(16) char lds[65536];
    int ic = blockIdx.y;
    int img = blockIdx.x & 15, h = blockIdx.x >> 4;
    int partner = img ^ 8;
    int t = threadIdx.x, w = t >> 6, lane = t & 63, quad = lane >> 4, l15 = lane & 15;
    const half_t* qp = qb + ((size_t)(img * 8 + h) * 1024 + ic * 128) * 128;
    const half_t* kp = kb + (size_t)(partner * 8 + h) * 256 * 128;
    const half_t* vp = vb + (size_t)(partner * 8 + h) * 64 * 512;

    // Q frags for this wave's 16 rows (i = w*16 + l15)
    half8 qh[2], ql[2];
    #pragma unroll
    for (int kcs = 0; kcs < 2; ++kcs) {
        qh[kcs] = *(const half8*)(qp + (size_t)(w * 16 + l15) * 128 + kcs * 32 + quad * 8);
        ql[kcs] = *(const half8*)(qp + (size_t)(w * 16 + l15) * 128 + 64 + kcs * 32 + quad * 8);
    }

    // stage K_hi + K_lo (one barrier)
    #pragma unroll
    for (int ii = 0; ii < 4; ++ii) {
        int u = ii * 512 + t;
        const half_t* g = kp + (size_t)((u >> 7) * 16 + (u & 15)) * 128
                             + ((u >> 6) & 1) * 32 + ((u >> 4) & 3) * 8;
        gll16(g,      lds + (u & ~63) * 16);
        gll16(g + 64, lds + 32768 + (u & ~63) * 16);
    }
    __syncthreads();

    // ---- phase 1: S[16 i][256 j] per wave, 96 MFMAs ----
    f32x4 sacc[16] = {};
    #pragma unroll
    for (int kcs = 0; kcs < 2; ++kcs)
        #pragma unroll
        for (int nt = 0; nt < 16; ++nt) {
            half8 bh = *(const half8*)(lds + (nt * 2 + kcs) * 1024 + lane * 16);
            half8 bl = *(const half8*)(lds + 32768 + (nt * 2 + kcs) * 1024 + lane * 16);
            sacc[nt] = __builtin_amdgcn_mfma_f32_16x16x32_f16(qh[kcs], bh, sacc[nt], 0, 0, 0);
            sacc[nt] = __builtin_amdgcn_mfma_f32_16x16x32_f16(qh[kcs], bl, sacc[nt], 0, 0, 0);
            sacc[nt] = __builtin_amdgcn_mfma_f32_16x16x32_f16(ql[kcs], bh, sacc[nt], 0, 0, 0);
        }

    // ---- row max only (row = quad*4 + r; cols = nt*16 + l15) ----
    float mrow[4];
    #pragma unroll
    for (int r = 0; r < 4; ++r) {
        float mx = sacc[0][r];
        #pragma unroll
        for (int nt = 1; nt < 16; ++nt) mx = fmaxf(mx, sacc[nt][r]);
        #pragma unroll
        for (int off = 1; off < 16; off <<= 1) mx = fmaxf(mx, __shfl_xor(mx, off, 64));
        mrow[r] = mx;
    }
    __syncthreads();   // K LDS dead before P/V overwrite

    // ---- phase 2: O~[16 i][64 d] per wave; exp/split interleaved per jc ----
    char* Pw = lds + 16384 + w * 4608;   // hi 2304 | lo 2304 per wave
    f32x4 oacc[4] = {};
    float lsum[4] = {0.f, 0.f, 0.f, 0.f};
    for (int jc = 0; jc < 4; ++jc) {
        #pragma unroll
        for (int n4 = 0; n4 < 4; ++n4)
            #pragma unroll
            for (int r = 0; r < 4; ++r) {
                float pv = __expf(sacc[jc * 4 + n4][r] - mrow[r]);
                lsum[r] += pv;
                half_t hh = (half_t)pv;
                int idx = ((quad * 4 + r) * 72 + n4 * 16 + l15) * 2;
                *(half_t*)(Pw + idx) = hh;
                *(half_t*)(Pw + 2304 + idx) = (half_t)(pv - (float)hh);
            }
        __syncthreads();   // previous V chunk consumed by all waves
        {
            const half_t* g = vp + (size_t)(((t >> 7) & 3) * 16 + (t & 15)) * 512
                                 + jc * 64 + ((t >> 6) & 1) * 32 + ((t >> 4) & 3) * 8;
            gll16(g,       lds + (t & ~63) * 16);
            gll16(g + 256, lds + 8192 + (t & ~63) * 16);
        }
        __syncthreads();   // V chunk ready; P published
        #pragma unroll
        for (int kcs = 0; kcs < 2; ++kcs) {
            half8 ph = *(const half8*)(Pw + (l15 * 72 + kcs * 32 + quad * 8) * 2);
            half8 pl = *(const half8*)(Pw + 2304 + (l15 * 72 + kcs * 32 + quad * 8) * 2);
            #pragma unroll
            for (int nt = 0; nt < 4; ++nt) {
                half8 vh = *(const half8*)(lds + (nt * 2 + kcs) * 1024 + lane * 16);
                half8 vl = *(const half8*)(lds + 8192 + (nt * 2 + kcs) * 1024 + lane * 16);
                oacc[nt] = __builtin_amdgcn_mfma_f32_16x16x32_f16(ph, vh, oacc[nt], 0, 0, 0);
                oacc[nt] = __builtin_amdgcn_mfma_f32_16x16x32_f16(ph, vl, oacc[nt], 0, 0, 0);
                oacc[nt] = __builtin_amdgcn_mfma_f32_16x16x32_f16(pl, vh, oacc[nt], 0, 0, 0);
            }
        }
    }

    // ---- normalize: reduce lsum over the 16 j-lanes, inv per row ----
    float inv[4];
    #pragma unroll
    for (int r = 0; r < 4; ++r) {
        float s = lsum[r];
        #pragma unroll
        for (int off = 1; off < 16; off <<= 1) s += __shfl_xor(s, off, 64);
        inv[r] = 1.f / s;
    }

    // ---- epilogue: stage O (hi|lo) in LDS, coalesced 16B stores ----
    __syncthreads();
    #pragma unroll
    for (int nt = 0; nt < 4; ++nt)
        #pragma unroll
        for (int r = 0; r < 4; ++r) {
            float vv = oacc[nt][r] * inv[r];
            half_t hh = (half_t)vv;
            int row = w * 16 + quad * 4 + r, col = nt * 16 + l15;
            *(half_t*)(lds + (row * 132 + col) * 2) = hh;
            *(half_t*)(lds + (row * 132 + 64 + col) * 2) = (half_t)(vv - (float)hh);
        }
    __syncthreads();
    #pragma unroll
    for (int ii = 0; ii < 4; ++ii) {
        int u = ii * 512 + t;
        int i = u >> 4, seg = (u >> 3) & 1, p8 = u & 7;
        half8 val = *(const half8*)(lds + (i * 132 + seg * 64 + p8 * 8) * 2);
        *(half8*)(att + ((size_t)img * 1024 + ic * 128 + i) * 1024 + seg * 512 + h * 64 + p8 * 8) = val;
    }
}

// ================= launch =================
extern "C" void kernel_launch(void* const* d_in, const int* in_sizes, int n_in,
                              void* d_out, int out_size, void* d_ws, size_t ws_size,
                              hipStream_t stream) {
    const float* x    = (const float*)d_in[0];
    const float* y    = (const float*)d_in[1];
    const float* qdw  = (const float*)d_in[2];
    const float* qg   = (const float*)d_in[3];
    const float* qbb  = (const float*)d_in[4];
    const float* qm   = (const float*)d_in[5];
    const float* qv   = (const float*)d_in[6];
    const float* qpw  = (const float*)d_in[7];
    const float* kvdw = (const float*)d_in[8];
    const float* kg   = (const float*)d_in[9];
    const float* kb_  = (const float*)d_in[10];
    const float* km   = (const float*)d_in[11];
    const float* kvv  = (const float*)d_in[12];
    const float* kvpw = (const float*)d_in[13];
    const float* outw = (const float*)d_in[14];
    const float* outb = (const float*)d_in[15];

    char* ws = (char*)d_ws;
    half_t* wq   = (half_t*)(ws);              //  512*512*2  = 524288
    half_t* wkv  = (half_t*)(ws + 524288);     // 1024*512*2  = 1048576
    half_t* wout = (half_t*)(ws + 1572864);    //  256*1024*2 = 524288
    float*  bq   = (float*) (ws + 2097152);
    float*  bkv  = (float*) (ws + 2099200);
    half_t* qpr  = (half_t*)(ws + 2103296);    // 16*8*1024*128*2 = 33554432
    half_t* kpr  = (half_t*)(ws + 35657728);   // 16*8*256*128*2  = 8388608
    half_t* vpr  = (half_t*)(ws + 44046336);   // 16*8*64*512*2   = 8388608
    half_t* qB   = (half_t*)(ws + 52434944);   // 16*1024*512*2   = 16777216
    half_t* kvB  = (half_t*)(ws + 69212160);   // 16*256*512*2    = 4194304
    half_t* attp = (half_t*)(ws + 52434944);   // aliases qB+kvB (dead by attn time): 33554432
    // total 85,989,376 B

    prep_dw_kernel<<<2048, 256, 0, stream>>>(
        x, y, qdw, kvdw, qg, qbb, qm, qv, qpw, kg, kb_, km, kvv, kvpw, outw,
        wq, wkv, wout, bq, bkv, qB, kvB);

    qkv_kernel<<<dim3(48, 1, 16), 512, 0, stream>>>(
        wq, wkv, qB, kvB, bq, bkv, qpr, kpr, vpr);

    attn_fused<<<dim3(128, 8, 1), 512, 0, stream>>>(qpr, kpr, vpr, attp);

    out_kernel<<<dim3(32, 1, 16), 256, 0, stream>>>(wout, attp, outb, (float*)d_out);
}